// Round 2
// baseline (817.692 us; speedup 1.0000x reference)
//
#include <hip/hip_runtime.h>

typedef unsigned short u16;
typedef unsigned int u32;
typedef __attribute__((ext_vector_type(8))) short short8_t;  // 8 bf16 (4 VGPRs)
typedef __attribute__((ext_vector_type(4))) float f32x4;

static constexpr int Bc = 4, Sc = 1024, Hc = 32, HKVc = 8, Dc = 128;
static constexpr int BS = Bc * Sc;     // 4096 rows
static constexpr int DIMc = 4096;

__device__ __forceinline__ u16 f2bf(float f) {
  u32 u = __float_as_uint(f);
  u32 r = (u + 0x7fffu + ((u >> 16) & 1u)) >> 16;  // RNE
  return (u16)r;
}
__device__ __forceinline__ float bf2f(u16 u) {
  return __uint_as_float(((u32)u) << 16);
}
__device__ __forceinline__ void gload_lds16(const void* g, void* l) {
  __builtin_amdgcn_global_load_lds((const __attribute__((address_space(1))) void*)g,
                                   (__attribute__((address_space(3))) void*)l, 16, 0, 0);
}

// ---------------- RoPE table: cos/sin for (s, i) ----------------
__global__ void rope_table_k(float* __restrict__ tbl) {
  int i = blockIdx.x * 256 + threadIdx.x;     // 1024*64
  int s = i >> 6, fi = i & 63;
  float freq = powf(10000.f, -(float)fi / 64.f);
  float ang = (float)s * freq;
  float sv, cv;
  sincosf(ang, &sv, &cv);
  tbl[2 * i] = cv;
  tbl[2 * i + 1] = sv;
}

// ---------------- fp32 -> bf16 convert (vectorized) ----------------
__global__ void f32_to_bf16_k(const float* __restrict__ in, u16* __restrict__ out, int n4) {
  int i = blockIdx.x * 256 + threadIdx.x;
  if (i >= n4) return;
  float4 v = *(const float4*)(in + (size_t)i * 4);
  uint2 pk;
  pk.x = (u32)f2bf(v.x) | ((u32)f2bf(v.y) << 16);
  pk.y = (u32)f2bf(v.z) | ((u32)f2bf(v.w) << 16);
  *(uint2*)(out + (size_t)i * 4) = pk;
}

// ---------------- W (K,N) fp32 -> WT (N,K) bf16, tiled transpose ----------------
__global__ __launch_bounds__(256) void transpose_w_k(const float* __restrict__ W, u16* __restrict__ WT,
                                                     int Kdim, int Ndim) {
  __shared__ float tile[64 * 65];
  const int t = threadIdx.x;
  const int n0 = blockIdx.x * 64, k0 = blockIdx.y * 64;
  #pragma unroll
  for (int p = 0; p < 4; ++p) {
    int idx = p * 256 + t;           // 1024 float4 chunks
    int r = idx >> 4, c = (idx & 15) * 4;
    float4 v = *(const float4*)(W + (size_t)(k0 + r) * Ndim + n0 + c);
    tile[r * 65 + c + 0] = v.x;
    tile[r * 65 + c + 1] = v.y;
    tile[r * 65 + c + 2] = v.z;
    tile[r * 65 + c + 3] = v.w;
  }
  __syncthreads();
  #pragma unroll
  for (int p = 0; p < 2; ++p) {
    int idx = p * 256 + t;           // 512 chunks of 8 bf16
    int n = idx >> 3, c = (idx & 7) * 8;
    alignas(16) u16 o[8];
    #pragma unroll
    for (int i = 0; i < 8; ++i) o[i] = f2bf(tile[(c + i) * 65 + n]);
    *(uint4*)(WT + (size_t)(n0 + n) * Kdim + k0 + c) = *(const uint4*)o;
  }
}

// ---------------- GEMM: C[M,N] = A[M,K] @ BT[N,K]^T (bf16 in, bf16/f32 out) ----------------
template <int OUT_F32>
__global__ __launch_bounds__(256) void gemm_bt(const u16* __restrict__ A, const u16* __restrict__ BT,
                                               void* __restrict__ Cv, int M, int N, int K) {
  __shared__ u16 As[128 * 32];
  __shared__ u16 Bs[128 * 32];
  const int t = threadIdx.x, l = t & 63, w = t >> 6;
  const int bm = blockIdx.y, bn = blockIdx.x;
  const int wr = (w >> 1) * 64, wc = (w & 1) * 64;
  const int ln15 = l & 15, khB = (l >> 4) * 8;
  f32x4 acc[4][4];
  #pragma unroll
  for (int i = 0; i < 4; ++i)
    #pragma unroll
    for (int j = 0; j < 4; ++j) acc[i][j] = f32x4{0.f, 0.f, 0.f, 0.f};
  const int srow = l >> 2, scol = (l & 3) * 8;
  const u16* Ab = A + (size_t)bm * 128 * K;
  const u16* Bb = BT + (size_t)bn * 128 * K;
  for (int k0 = 0; k0 < K; k0 += 32) {
    __syncthreads();
    #pragma unroll
    for (int i = 0; i < 2; ++i) {
      int chunk = w * 2 + i;                 // 8 x 1KB chunks per tile
      int r = chunk * 16 + srow;
      gload_lds16(Ab + (size_t)r * K + k0 + scol, (char*)As + chunk * 1024);
      gload_lds16(Bb + (size_t)r * K + k0 + scol, (char*)Bs + chunk * 1024);
    }
    __syncthreads();
    short8_t af[4], bf[4];
    #pragma unroll
    for (int i = 0; i < 4; ++i) af[i] = *(const short8_t*)&As[(wr + i * 16 + ln15) * 32 + khB];
    #pragma unroll
    for (int j = 0; j < 4; ++j) bf[j] = *(const short8_t*)&Bs[(wc + j * 16 + ln15) * 32 + khB];
    #pragma unroll
    for (int i = 0; i < 4; ++i)
      #pragma unroll
      for (int j = 0; j < 4; ++j)
        acc[i][j] = __builtin_amdgcn_mfma_f32_16x16x32_bf16(af[i], bf[j], acc[i][j], 0, 0, 0);
  }
  const int rbase = bm * 128 + wr + (l >> 4) * 4;
  const int cbase = bn * 128 + wc + ln15;
  #pragma unroll
  for (int i = 0; i < 4; ++i)
    #pragma unroll
    for (int j = 0; j < 4; ++j)
      #pragma unroll
      for (int e = 0; e < 4; ++e) {
        size_t idx = (size_t)(rbase + i * 16 + e) * N + cbase + j * 16;
        if (OUT_F32) ((float*)Cv)[idx] = acc[i][j][e];
        else         ((u16*)Cv)[idx]  = f2bf(acc[i][j][e]);
      }
}

// ---------------- RoPE apply + layout change: [b][s][h][d] -> [b][h][s][d] ----------------
__global__ void rope_apply_k(const u16* __restrict__ In, u16* __restrict__ Out,
                             const float* __restrict__ tbl, int nh, int lognh, float scale) {
  int idx = blockIdx.x * 256 + threadIdx.x;        // one (b,s,h,pair)
  int fi = idx & 63;
  int hs = idx >> 6;
  int h = hs & (nh - 1);
  int rest = hs >> lognh;
  int s = rest & (Sc - 1);
  int b = rest >> 10;
  u32 v = *(const u32*)(In + (size_t)idx * 2);
  float xr = bf2f((u16)(v & 0xffffu));
  float xi = bf2f((u16)(v >> 16));
  float cv = tbl[2 * (s * 64 + fi)];
  float sv = tbl[2 * (s * 64 + fi) + 1];
  float orr = (xr * cv - xi * sv) * scale;
  float oii = (xr * sv + xi * cv) * scale;
  u32 o = (u32)f2bf(orr) | ((u32)f2bf(oii) << 16);
  size_t oidx = ((size_t)(b * nh + h) * Sc + s) * 64 + fi;
  *(u32*)(Out + oidx * 2) = o;
}

// ---------------- V: [b][s][hkv][d] -> VT: [b][hkv][d][s] (tiled transpose) ----------------
__global__ __launch_bounds__(256) void transpose_v_k(const u16* __restrict__ V, u16* __restrict__ VT) {
  __shared__ u16 tile[64 * 136];    // 64 s x 128 d, stride padded to 136
  const int t = threadIdx.x;
  const int s0 = blockIdx.x * 64;
  const int hkv = blockIdx.y, b = blockIdx.z;
  #pragma unroll
  for (int p = 0; p < 4; ++p) {
    int idx = p * 256 + t;             // 1024 chunks of 8 bf16
    int r = idx >> 4, c = (idx & 15) * 8;
    uint4 v = *(const uint4*)(V + (size_t)(b * Sc + s0 + r) * (HKVc * Dc) + hkv * Dc + c);
    *(uint4*)&tile[r * 136 + c] = v;
  }
  __syncthreads();
  #pragma unroll
  for (int p = 0; p < 4; ++p) {
    int idx = p * 256 + t;             // 1024 chunks of 8 bf16 (128 d rows x 8 s-chunks)
    int d = idx >> 3, sc = (idx & 7) * 8;
    alignas(16) u16 o[8];
    #pragma unroll
    for (int i = 0; i < 8; ++i) o[i] = tile[(sc + i) * 136 + d];
    *(uint4*)(VT + ((size_t)(b * HKVc + hkv) * Dc + d) * Sc + s0 + sc) = *(const uint4*)o;
  }
}

// ---------------- Flash attention (causal, GQA) ----------------
// Q: [b][h][s][d] (pre-scaled by 1/sqrt(128)); K: [b][hkv][s][d]; VT: [b][hkv][d][s]
// out AO: [b][s][h*128+d] bf16
__global__ __launch_bounds__(256) void attn_k(const u16* __restrict__ Q, const u16* __restrict__ Kr,
                                              const u16* __restrict__ Vt, u16* __restrict__ AO) {
  __shared__ u16 Ks[64 * 128];       // XOR-swizzled rows (16B-chunk granularity)
  __shared__ u16 Vs[128 * 72];       // [d][kv], stride 72
  __shared__ u16 Ps[4 * 16 * 72];    // per-wave P, stride 72
  const int t = threadIdx.x, l = t & 63, w = t >> 6;
  const int qb = blockIdx.x, h = blockIdx.y, b = blockIdx.z;
  const int hkv = h >> 2;
  const int ln15 = l & 15, lh = l >> 4;

  short8_t qf[4];
  {
    int q = qb * 64 + w * 16 + ln15;
    const u16* qp = Q + ((size_t)(b * Hc + h) * Sc + q) * Dc + lh * 8;
    #pragma unroll
    for (int ks = 0; ks < 4; ++ks) qf[ks] = *(const short8_t*)(qp + ks * 32);
  }
  f32x4 oacc[8];
  #pragma unroll
  for (int i = 0; i < 8; ++i) oacc[i] = f32x4{0.f, 0.f, 0.f, 0.f};
  float mrun[4], lrun[4];
  #pragma unroll
  for (int j = 0; j < 4; ++j) { mrun[j] = -1e30f; lrun[j] = 0.f; }

  const u16* Kg0 = Kr + (size_t)(b * HKVc + hkv) * Sc * Dc;
  const u16* Vg0 = Vt + (size_t)(b * HKVc + hkv) * Dc * Sc;

  for (int kvb = 0; kvb <= qb; ++kvb) {
    __syncthreads();
    {
      const u16* Kg = Kg0 + (size_t)kvb * 64 * Dc;
      #pragma unroll
      for (int p = 0; p < 4; ++p) {
        int idx = p * 256 + t;             // 1024 chunks: 64 rows x 16 chunks
        int sr = idx >> 4;
        int c = idx & 15;
        uint4 v = *(const uint4*)(Kg + sr * Dc + c * 8);
        *(uint4*)((char*)Ks + sr * 256 + ((c ^ (sr & 7)) << 4)) = v;   // XOR-swizzle
      }
      const u16* Vg = Vg0 + kvb * 64;
      #pragma unroll
      for (int p = 0; p < 4; ++p) {
        int idx = p * 256 + t;
        int d = idx >> 3, c = idx & 7;
        uint4 v = *(const uint4*)(Vg + (size_t)d * Sc + c * 8);
        *(uint4*)((char*)Vs + d * 144 + (c << 4)) = v;
      }
    }
    __syncthreads();

    // QK^T: wave computes 16 q rows x 64 kv cols
    f32x4 sf[4];
    #pragma unroll
    for (int fc = 0; fc < 4; ++fc) {
      sf[fc] = f32x4{0.f, 0.f, 0.f, 0.f};
      int kvr = fc * 16 + ln15;
      #pragma unroll
      for (int ks = 0; ks < 4; ++ks) {
        int chunk = ks * 4 + lh;
        short8_t kf = *(const short8_t*)((const char*)Ks + kvr * 256 + ((chunk ^ (kvr & 7)) << 4));
        sf[fc] = __builtin_amdgcn_mfma_f32_16x16x32_bf16(qf[ks], kf, sf[fc], 0, 0, 0);
      }
    }
    if (kvb == qb) {   // diagonal tile: mask kv > q
      #pragma unroll
      for (int fc = 0; fc < 4; ++fc)
        #pragma unroll
        for (int j = 0; j < 4; ++j) {
          int kvloc = fc * 16 + ln15;
          int qloc = w * 16 + lh * 4 + j;
          if (kvloc > qloc) sf[fc][j] = -1e30f;
        }
    }
    // online softmax
    float mt[4];
    #pragma unroll
    for (int j = 0; j < 4; ++j) {
      float v = fmaxf(fmaxf(sf[0][j], sf[1][j]), fmaxf(sf[2][j], sf[3][j]));
      v = fmaxf(v, __shfl_xor(v, 1));
      v = fmaxf(v, __shfl_xor(v, 2));
      v = fmaxf(v, __shfl_xor(v, 4));
      v = fmaxf(v, __shfl_xor(v, 8));
      mt[j] = v;
    }
    float alpha[4];
    #pragma unroll
    for (int j = 0; j < 4; ++j) {
      float mnew = fmaxf(mrun[j], mt[j]);
      alpha[j] = __expf(mrun[j] - mnew);
      mrun[j] = mnew;
    }
    float rs[4] = {0.f, 0.f, 0.f, 0.f};
    #pragma unroll
    for (int fc = 0; fc < 4; ++fc)
      #pragma unroll
      for (int j = 0; j < 4; ++j) {
        float p = __expf(sf[fc][j] - mrun[j]);
        sf[fc][j] = p;
        rs[j] += p;
      }
    #pragma unroll
    for (int j = 0; j < 4; ++j) {
      float v = rs[j];
      v += __shfl_xor(v, 1);
      v += __shfl_xor(v, 2);
      v += __shfl_xor(v, 4);
      v += __shfl_xor(v, 8);
      lrun[j] = lrun[j] * alpha[j] + v;
    }
    #pragma unroll
    for (int i = 0; i < 8; ++i)
      #pragma unroll
      for (int j = 0; j < 4; ++j) oacc[i][j] *= alpha[j];

    // P -> LDS (bf16), per-wave region; wave-local so only lgkmcnt needed
    u16* Pw = Ps + w * 16 * 72;
    #pragma unroll
    for (int fc = 0; fc < 4; ++fc)
      #pragma unroll
      for (int j = 0; j < 4; ++j)
        Pw[(lh * 4 + j) * 72 + fc * 16 + ln15] = f2bf(sf[fc][j]);
    asm volatile("s_waitcnt lgkmcnt(0)" ::: "memory");

    short8_t pf[2];
    #pragma unroll
    for (int ks = 0; ks < 2; ++ks)
      pf[ks] = *(const short8_t*)((const char*)Pw + ln15 * 144 + ks * 64 + lh * 16);
    #pragma unroll
    for (int fd = 0; fd < 8; ++fd) {
      int dcol = fd * 16 + ln15;
      #pragma unroll
      for (int ks = 0; ks < 2; ++ks) {
        short8_t vf = *(const short8_t*)((const char*)Vs + dcol * 144 + ks * 64 + lh * 16);
        oacc[fd] = __builtin_amdgcn_mfma_f32_16x16x32_bf16(pf[ks], vf, oacc[fd], 0, 0, 0);
      }
    }
  }
  // epilogue: O /= l, write [b][s][h*128+d]
  #pragma unroll
  for (int j = 0; j < 4; ++j) {
    float r = 1.f / lrun[j];
    int q = qb * 64 + w * 16 + lh * 4 + j;
    u16* op = AO + (size_t)(b * Sc + q) * DIMc + h * Dc + ln15;
    #pragma unroll
    for (int fd = 0; fd < 8; ++fd) op[fd * 16] = f2bf(oacc[fd][j] * r);
  }
}

extern "C" void kernel_launch(void* const* d_in, const int* in_sizes, int n_in,
                              void* d_out, int out_size, void* d_ws, size_t ws_size,
                              hipStream_t stream) {
  const float* x  = (const float*)d_in[0];
  const float* wq = (const float*)d_in[1];
  const float* wk = (const float*)d_in[2];
  const float* wv = (const float*)d_in[3];
  const float* wo = (const float*)d_in[4];
  float* out = (float*)d_out;

  char* ws = (char*)d_ws;
  size_t off = 0;
  auto alloc = [&](size_t bytes) -> char* {
    char* p = ws + off;
    off += (bytes + 255) & ~(size_t)255;
    return p;
  };
  // total needed ~145 MB
  float* tbl  = (float*)alloc((size_t)Sc * 64 * 2 * 4);
  u16* xb   = (u16*)alloc((size_t)BS * DIMc * 2);      // x bf16; later reused as Qr
  u16* wA   = (u16*)alloc((size_t)4096 * 4096 * 2);    // wqT, later woT
  u16* wkT  = (u16*)alloc((size_t)1024 * 4096 * 2);
  u16* wvT  = (u16*)alloc((size_t)1024 * 4096 * 2);
  u16* Qb   = (u16*)alloc((size_t)BS * 4096 * 2);      // Q proj; later reused as AO
  u16* Kb   = (u16*)alloc((size_t)BS * 1024 * 2);
  u16* Vb   = (u16*)alloc((size_t)BS * 1024 * 2);
  u16* Krp  = (u16*)alloc((size_t)BS * 1024 * 2);
  u16* Vtp  = (u16*)alloc((size_t)BS * 1024 * 2);
  u16* Qr = xb;   // alias: xb dead after V GEMM
  u16* AO = Qb;   // alias: Qb dead after rope(Q)

  rope_table_k<<<(Sc * 64) / 256, 256, 0, stream>>>(tbl);
  f32_to_bf16_k<<<(BS * DIMc / 4) / 256, 256, 0, stream>>>(x, xb, BS * DIMc / 4);

  transpose_w_k<<<dim3(64, 64), 256, 0, stream>>>(wq, wA, 4096, 4096);
  gemm_bt<0><<<dim3(32, 32), 256, 0, stream>>>(xb, wA, Qb, 4096, 4096, 4096);
  transpose_w_k<<<dim3(16, 64), 256, 0, stream>>>(wk, wkT, 4096, 1024);
  gemm_bt<0><<<dim3(8, 32), 256, 0, stream>>>(xb, wkT, Kb, 4096, 1024, 4096);
  transpose_w_k<<<dim3(16, 64), 256, 0, stream>>>(wv, wvT, 4096, 1024);
  gemm_bt<0><<<dim3(8, 32), 256, 0, stream>>>(xb, wvT, Vb, 4096, 1024, 4096);

  rope_apply_k<<<(Bc * Sc * Hc * 64) / 256, 256, 0, stream>>>(Qb, Qr, tbl, Hc, 5, 0.08838834764831845f);
  rope_apply_k<<<(Bc * Sc * HKVc * 64) / 256, 256, 0, stream>>>(Kb, Krp, tbl, HKVc, 3, 1.0f);
  transpose_v_k<<<dim3(16, HKVc, Bc), 256, 0, stream>>>(Vb, Vtp);

  attn_k<<<dim3(16, Hc, Bc), 256, 0, stream>>>(Qr, Krp, Vtp, AO);

  transpose_w_k<<<dim3(64, 64), 256, 0, stream>>>(wo, wA, 4096, 4096);
  gemm_bt<1><<<dim3(32, 32), 256, 0, stream>>>(AO, wA, out, 4096, 4096, 4096);
}

// Round 4
// 674.420 us; speedup vs baseline: 1.2124x; 1.2124x over previous
//
#include <hip/hip_runtime.h>

typedef unsigned short u16;
typedef unsigned int u32;
typedef __attribute__((ext_vector_type(8))) short short8_t;  // 8 bf16 (4 VGPRs)
typedef __attribute__((ext_vector_type(4))) float f32x4;

static constexpr int Bc = 4, Sc = 1024, Hc = 32, HKVc = 8, Dc = 128;
static constexpr int BS = Bc * Sc;     // 4096 rows
static constexpr int DIMc = 4096;

__device__ __forceinline__ u16 f2bf(float f) {
  u32 u = __float_as_uint(f);
  u32 r = (u + 0x7fffu + ((u >> 16) & 1u)) >> 16;  // RNE
  return (u16)r;
}
__device__ __forceinline__ float bf2f(u16 u) {
  return __uint_as_float(((u32)u) << 16);
}
__device__ __forceinline__ void gload_lds16(const void* g, void* l) {
  __builtin_amdgcn_global_load_lds((const __attribute__((address_space(1))) void*)g,
                                   (__attribute__((address_space(3))) void*)l, 16, 0, 0);
}

#define SBAR __builtin_amdgcn_sched_barrier(0)
#define PBARRIER do { SBAR; __builtin_amdgcn_s_barrier(); SBAR; } while (0)

// ---------------- RoPE table: cos/sin for (s, i) ----------------
__global__ void rope_table_k(float* __restrict__ tbl) {
  int i = blockIdx.x * 256 + threadIdx.x;     // 1024*64
  int s = i >> 6, fi = i & 63;
  float freq = powf(10000.f, -(float)fi / 64.f);
  float ang = (float)s * freq;
  float sv, cv;
  sincosf(ang, &sv, &cv);
  tbl[2 * i] = cv;
  tbl[2 * i + 1] = sv;
}

// ---------------- fp32 -> bf16 convert (vectorized) ----------------
__global__ void f32_to_bf16_k(const float* __restrict__ in, u16* __restrict__ out, int n4) {
  int i = blockIdx.x * 256 + threadIdx.x;
  if (i >= n4) return;
  float4 v = *(const float4*)(in + (size_t)i * 4);
  uint2 pk;
  pk.x = (u32)f2bf(v.x) | ((u32)f2bf(v.y) << 16);
  pk.y = (u32)f2bf(v.z) | ((u32)f2bf(v.w) << 16);
  *(uint2*)(out + (size_t)i * 4) = pk;
}

// ---------------- W (K,N) fp32 -> WT (N,K) bf16, tiled transpose ----------------
__global__ __launch_bounds__(256) void transpose_w_k(const float* __restrict__ W, u16* __restrict__ WT,
                                                     int Kdim, int Ndim) {
  __shared__ float tile[64 * 65];
  const int t = threadIdx.x;
  const int n0 = blockIdx.x * 64, k0 = blockIdx.y * 64;
  #pragma unroll
  for (int p = 0; p < 4; ++p) {
    int idx = p * 256 + t;           // 1024 float4 chunks
    int r = idx >> 4, c = (idx & 15) * 4;
    float4 v = *(const float4*)(W + (size_t)(k0 + r) * Ndim + n0 + c);
    tile[r * 65 + c + 0] = v.x;
    tile[r * 65 + c + 1] = v.y;
    tile[r * 65 + c + 2] = v.z;
    tile[r * 65 + c + 3] = v.w;
  }
  __syncthreads();
  #pragma unroll
  for (int p = 0; p < 2; ++p) {
    int idx = p * 256 + t;           // 512 chunks of 8 bf16
    int n = idx >> 3, c = (idx & 7) * 8;
    alignas(16) u16 o[8];
    #pragma unroll
    for (int i = 0; i < 8; ++i) o[i] = f2bf(tile[(c + i) * 65 + n]);
    *(uint4*)(WT + (size_t)(n0 + n) * Kdim + k0 + c) = *(const uint4*)o;
  }
}

// ---------------- 128^2-tile GEMM (kept for K/V projections) ----------------
template <int OUT_F32>
__global__ __launch_bounds__(256) void gemm_bt(const u16* __restrict__ A, const u16* __restrict__ BT,
                                               void* __restrict__ Cv, int M, int N, int K) {
  __shared__ u16 As[128 * 32];
  __shared__ u16 Bs[128 * 32];
  const int t = threadIdx.x, l = t & 63, w = t >> 6;
  const int bm = blockIdx.y, bn = blockIdx.x;
  const int wr = (w >> 1) * 64, wc = (w & 1) * 64;
  const int ln15 = l & 15, khB = (l >> 4) * 8;
  f32x4 acc[4][4];
  #pragma unroll
  for (int i = 0; i < 4; ++i)
    #pragma unroll
    for (int j = 0; j < 4; ++j) acc[i][j] = f32x4{0.f, 0.f, 0.f, 0.f};
  const int srow = l >> 2, scol = (l & 3) * 8;
  const u16* Ab = A + (size_t)bm * 128 * K;
  const u16* Bb = BT + (size_t)bn * 128 * K;
  for (int k0 = 0; k0 < K; k0 += 32) {
    __syncthreads();
    #pragma unroll
    for (int i = 0; i < 2; ++i) {
      int chunk = w * 2 + i;                 // 8 x 1KB chunks per tile
      int r = chunk * 16 + srow;
      gload_lds16(Ab + (size_t)r * K + k0 + scol, (char*)As + chunk * 1024);
      gload_lds16(Bb + (size_t)r * K + k0 + scol, (char*)Bs + chunk * 1024);
    }
    __syncthreads();
    short8_t af[4], bf[4];
    #pragma unroll
    for (int i = 0; i < 4; ++i) af[i] = *(const short8_t*)&As[(wr + i * 16 + ln15) * 32 + khB];
    #pragma unroll
    for (int j = 0; j < 4; ++j) bf[j] = *(const short8_t*)&Bs[(wc + j * 16 + ln15) * 32 + khB];
    #pragma unroll
    for (int i = 0; i < 4; ++i)
      #pragma unroll
      for (int j = 0; j < 4; ++j)
        acc[i][j] = __builtin_amdgcn_mfma_f32_16x16x32_bf16(af[i], bf[j], acc[i][j], 0, 0, 0);
  }
  const int rbase = bm * 128 + wr + (l >> 4) * 4;
  const int cbase = bn * 128 + wc + ln15;
  #pragma unroll
  for (int i = 0; i < 4; ++i)
    #pragma unroll
    for (int j = 0; j < 4; ++j)
      #pragma unroll
      for (int e = 0; e < 4; ++e) {
        size_t idx = (size_t)(rbase + i * 16 + e) * N + cbase + j * 16;
        if (OUT_F32) ((float*)Cv)[idx] = acc[i][j][e];
        else         ((u16*)Cv)[idx]  = f2bf(acc[i][j][e]);
      }
}

// ---------------- 256^2-tile 8-phase GEMM (big projections) ----------------
// C[M,N] = A[M,K] @ BT[N,K]^T. BK=64, 8 waves (2x4 over a 128x128 C-quadrant
// per phase), 2x64KB LDS double buffer, XOR-swizzle (chunk16 ^= row&7) applied
// as pre-swizzled global source + swizzled ds_read (rule 21). Counted vmcnt is
// always placed BEFORE a barrier; dependent ds_reads come after that barrier.
#define MFMAQ(QI)                                                                        \
  do {                                                                                   \
    __builtin_amdgcn_s_setprio(1);                                                       \
    _Pragma("unroll") for (int mf = 0; mf < 4; ++mf)                                     \
      _Pragma("unroll") for (int nf = 0; nf < 2; ++nf)                                   \
        _Pragma("unroll") for (int kk = 0; kk < 2; ++kk)                                 \
          acc[QI][mf][nf] = __builtin_amdgcn_mfma_f32_16x16x32_bf16(                     \
              af[mf][kk], bf[nf][kk], acc[QI][mf][nf], 0, 0, 0);                         \
    __builtin_amdgcn_s_setprio(0);                                                       \
  } while (0)

#define WAITVM(N) asm volatile("s_waitcnt vmcnt(" #N ")" ::: "memory")

template <int OUT_F32>
__global__ __launch_bounds__(512, 2) void gemm256(const u16* __restrict__ A, const u16* __restrict__ BT,
                                                  void* __restrict__ Cv, int M, int N, int K) {
  extern __shared__ char smem[];   // 131072 B: [buf:2][A|B][half:2][128 rows][8 chunk16]
  const int t = threadIdx.x, l = t & 63, w = t >> 6;
  const int ln15 = l & 15, lh = l >> 4;
  const int NT = K >> 6;

  // XCD-bijective swizzle (grid = 256 blocks, multiple of 8)
  int id = blockIdx.x;
  int nwg = gridDim.x;
  int swz = ((nwg & 7) == 0) ? ((id & 7) * (nwg >> 3) + (id >> 3)) : id;
  const int nbn = N >> 8;
  const int bm = swz / nbn, bn = swz % nbn;

  const u16* Ag = A + (size_t)bm * 256 * K;
  const u16* Bg = BT + (size_t)bn * 256 * K;

  f32x4 acc[4][4][2];
  #pragma unroll
  for (int q = 0; q < 4; ++q)
    #pragma unroll
    for (int mf = 0; mf < 4; ++mf)
      #pragma unroll
      for (int nf = 0; nf < 2; ++nf) acc[q][mf][nf] = f32x4{0.f, 0.f, 0.f, 0.f};
  short8_t af[4][2], bf[2][2];

  // ---- staging: one call = one 16KB half-tile (128 rows x 64 K), 2 gload_lds/wave ----
  const int srow = (l >> 3);                 // 0..7 within wave's 8-row strip
  const int sck  = (l & 7) ^ srow;           // pre-swizzled global 16B-chunk
  auto stageA = [&](char* bufbase, int h, int tt) {
    char* lb = bufbase + h * 16384 + w * 1024;
    const u16* g = Ag + (size_t)(h * 128 + w * 8 + srow) * K + tt * 64 + (sck << 3);
    gload_lds16(g, lb);
    gload_lds16(g + (size_t)64 * K, lb + 8192);
  };
  auto stageB = [&](char* bufbase, int h, int tt) {
    char* lb = bufbase + 32768 + h * 16384 + w * 1024;
    const u16* g = Bg + (size_t)(h * 128 + w * 8 + srow) * K + tt * 64 + (sck << 3);
    gload_lds16(g, lb);
    gload_lds16(g + (size_t)64 * K, lb + 8192);
  };
  // ---- fragment loads (swizzled ds_read_b128) ----
  const int arow = (w >> 2) * 64 + ln15;     // within A half (2 wave-row groups)
  const int brow = (w & 3) * 32 + ln15;      // within B half (4 wave-col groups)
  const int rsw = ln15 & 7;
  auto LDA = [&](const char* cb, int qm) {
    #pragma unroll
    for (int mf = 0; mf < 4; ++mf)
      #pragma unroll
      for (int kk = 0; kk < 2; ++kk)
        af[mf][kk] = *(const short8_t*)(cb + qm * 16384 + (arow + mf * 16) * 128 +
                                        (((kk * 4 + lh) ^ rsw) << 4));
  };
  auto LDB = [&](const char* cb, int qn) {
    #pragma unroll
    for (int nf = 0; nf < 2; ++nf)
      #pragma unroll
      for (int kk = 0; kk < 2; ++kk)
        bf[nf][kk] = *(const short8_t*)(cb + 32768 + qn * 16384 + (brow + nf * 16) * 128 +
                                        (((kk * 4 + lh) ^ rsw) << 4));
  };

  // ---- prologue: 6 half-tiles in flight; retire tile-0's first 3 before reading ----
  {
    char* b0 = smem;
    char* b1 = smem + 65536;
    stageB(b0, 0, 0);   // S1 B0(0)
    stageA(b0, 1, 0);   // S2 A1(0)
    stageA(b0, 0, 0);   // S3 A0(0)
    stageB(b0, 1, 0);   // S4 B1(0)
    stageB(b1, 0, 1);   // S5 B0(1)
    stageA(b1, 1, 1);   // S6 A1(1)
  }
  WAITVM(6);     // S1..S3 retired (A0(0), B0(0) in LDS for ALL waves after barrier)
  PBARRIER;

  // ---- main loop: tiles 0..NT-2 ----
  for (int T = 0; T < NT - 1; ++T) {
    char* cb = smem + (T & 1) * 65536;
    char* nb = smem + ((T & 1) ^ 1) * 65536;
    // phase 1: quadrant (0,0)
    LDA(cb, 0); LDB(cb, 0);
    stageA(nb, 0, T + 1);               // A0(T+1)
    PBARRIER;
    MFMAQ(0);
    PBARRIER;
    // phase 2: quadrant (1,0) — reuse B frags
    LDA(cb, 1);
    stageB(nb, 1, T + 1);               // B1(T+1)
    PBARRIER;
    MFMAQ(1);
    WAITVM(8);                          // retire through B1(T) for p3's read
    PBARRIER;
    // phase 3: quadrant (1,1) — reuse A frags
    LDB(cb, 1);
    if (T + 2 < NT) stageB(cb, 0, T + 2);   // B0(T+2) into current buf (freed after p1)
    PBARRIER;
    MFMAQ(2);
    PBARRIER;
    // phase 4: quadrant (0,1) — reuse B frags
    LDA(cb, 0);
    if (T + 2 < NT) stageA(cb, 1, T + 2);   // A1(T+2) (freed after p2)
    PBARRIER;
    MFMAQ(3);
    if (T + 2 < NT) { WAITVM(6); }      // retire through A0(T+1) for next p1
    else            { WAITVM(2); }      // last main iter staged only 2 half-tiles
    PBARRIER;
  }
  // ---- peeled final tile (no staging) ----
  {
    char* cb = smem + ((NT - 1) & 1) * 65536;
    LDA(cb, 0); LDB(cb, 0);
    PBARRIER; MFMAQ(0); PBARRIER;
    LDA(cb, 1);
    PBARRIER; MFMAQ(1);
    WAITVM(0);                          // retire B1(NT-1) for p3
    PBARRIER;
    LDB(cb, 1);
    PBARRIER; MFMAQ(2); PBARRIER;
    LDA(cb, 0);
    PBARRIER; MFMAQ(3);
  }

  // ---- epilogue ----
  const int rw = (w >> 2) * 64, cw = (w & 3) * 32;
  #pragma unroll
  for (int qi = 0; qi < 4; ++qi) {
    const int qm = (qi == 1 || qi == 2) ? 1 : 0;
    const int qn = (qi >= 2) ? 1 : 0;
    #pragma unroll
    for (int mf = 0; mf < 4; ++mf)
      #pragma unroll
      for (int nf = 0; nf < 2; ++nf)
        #pragma unroll
        for (int e = 0; e < 4; ++e) {
          int row = bm * 256 + qm * 128 + rw + mf * 16 + lh * 4 + e;
          int col = bn * 256 + qn * 128 + cw + nf * 16 + ln15;
          size_t idx = (size_t)row * N + col;
          if (OUT_F32) ((float*)Cv)[idx] = acc[qi][mf][nf][e];
          else         ((u16*)Cv)[idx]  = f2bf(acc[qi][mf][nf][e]);
        }
  }
}

// ---------------- RoPE apply + layout change: [b][s][h][d] -> [b][h][s][d] ----------------
__global__ void rope_apply_k(const u16* __restrict__ In, u16* __restrict__ Out,
                             const float* __restrict__ tbl, int nh, int lognh, float scale) {
  int idx = blockIdx.x * 256 + threadIdx.x;        // one (b,s,h,pair)
  int fi = idx & 63;
  int hs = idx >> 6;
  int h = hs & (nh - 1);
  int rest = hs >> lognh;
  int s = rest & (Sc - 1);
  int b = rest >> 10;
  u32 v = *(const u32*)(In + (size_t)idx * 2);
  float xr = bf2f((u16)(v & 0xffffu));
  float xi = bf2f((u16)(v >> 16));
  float cv = tbl[2 * (s * 64 + fi)];
  float sv = tbl[2 * (s * 64 + fi) + 1];
  float orr = (xr * cv - xi * sv) * scale;
  float oii = (xr * sv + xi * cv) * scale;
  u32 o = (u32)f2bf(orr) | ((u32)f2bf(oii) << 16);
  size_t oidx = ((size_t)(b * nh + h) * Sc + s) * 64 + fi;
  *(u32*)(Out + oidx * 2) = o;
}

// ---------------- V: [b][s][hkv][d] -> VT: [b][hkv][d][s] (tiled transpose) ----------------
__global__ __launch_bounds__(256) void transpose_v_k(const u16* __restrict__ V, u16* __restrict__ VT) {
  __shared__ u16 tile[64 * 136];    // 64 s x 128 d, stride padded to 136
  const int t = threadIdx.x;
  const int s0 = blockIdx.x * 64;
  const int hkv = blockIdx.y, b = blockIdx.z;
  #pragma unroll
  for (int p = 0; p < 4; ++p) {
    int idx = p * 256 + t;             // 1024 chunks of 8 bf16
    int r = idx >> 4, c = (idx & 15) * 8;
    uint4 v = *(const uint4*)(V + (size_t)(b * Sc + s0 + r) * (HKVc * Dc) + hkv * Dc + c);
    *(uint4*)&tile[r * 136 + c] = v;
  }
  __syncthreads();
  #pragma unroll
  for (int p = 0; p < 4; ++p) {
    int idx = p * 256 + t;             // 1024 chunks of 8 bf16 (128 d rows x 8 s-chunks)
    int d = idx >> 3, sc = (idx & 7) * 8;
    alignas(16) u16 o[8];
    #pragma unroll
    for (int i = 0; i < 8; ++i) o[i] = tile[(sc + i) * 136 + d];
    *(uint4*)(VT + ((size_t)(b * HKVc + hkv) * Dc + d) * Sc + s0 + sc) = *(const uint4*)o;
  }
}

// ---------------- Flash attention (causal, GQA) ----------------
// Q: [b][h][s][d] (pre-scaled by 1/sqrt(128)); K: [b][hkv][s][d]; VT: [b][hkv][d][s]
// out AO: [b][s][h*128+d] bf16
__global__ __launch_bounds__(256) void attn_k(const u16* __restrict__ Q, const u16* __restrict__ Kr,
                                              const u16* __restrict__ Vt, u16* __restrict__ AO) {
  __shared__ u16 Ks[64 * 128];       // XOR-swizzled rows (16B-chunk granularity)
  __shared__ u16 Vs[128 * 72];       // [d][kv], stride 72
  __shared__ u16 Ps[4 * 16 * 72];    // per-wave P, stride 72
  const int t = threadIdx.x, l = t & 63, w = t >> 6;
  const int qb = blockIdx.x, h = blockIdx.y, b = blockIdx.z;
  const int hkv = h >> 2;
  const int ln15 = l & 15, lh = l >> 4;

  short8_t qf[4];
  {
    int q = qb * 64 + w * 16 + ln15;
    const u16* qp = Q + ((size_t)(b * Hc + h) * Sc + q) * Dc + lh * 8;
    #pragma unroll
    for (int ks = 0; ks < 4; ++ks) qf[ks] = *(const short8_t*)(qp + ks * 32);
  }
  f32x4 oacc[8];
  #pragma unroll
  for (int i = 0; i < 8; ++i) oacc[i] = f32x4{0.f, 0.f, 0.f, 0.f};
  float mrun[4], lrun[4];
  #pragma unroll
  for (int j = 0; j < 4; ++j) { mrun[j] = -1e30f; lrun[j] = 0.f; }

  const u16* Kg0 = Kr + (size_t)(b * HKVc + hkv) * Sc * Dc;
  const u16* Vg0 = Vt + (size_t)(b * HKVc + hkv) * Dc * Sc;

  for (int kvb = 0; kvb <= qb; ++kvb) {
    __syncthreads();
    {
      const u16* Kg = Kg0 + (size_t)kvb * 64 * Dc;
      #pragma unroll
      for (int p = 0; p < 4; ++p) {
        int idx = p * 256 + t;             // 1024 chunks: 64 rows x 16 chunks
        int sr = idx >> 4;
        int c = idx & 15;
        uint4 v = *(const uint4*)(Kg + sr * Dc + c * 8);
        *(uint4*)((char*)Ks + sr * 256 + ((c ^ (sr & 7)) << 4)) = v;   // XOR-swizzle
      }
      const u16* Vg = Vg0 + kvb * 64;
      #pragma unroll
      for (int p = 0; p < 4; ++p) {
        int idx = p * 256 + t;
        int d = idx >> 3, c = idx & 7;
        uint4 v = *(const uint4*)(Vg + (size_t)d * Sc + c * 8);
        *(uint4*)((char*)Vs + d * 144 + (c << 4)) = v;
      }
    }
    __syncthreads();

    // QK^T: wave computes 16 q rows x 64 kv cols
    f32x4 sf[4];
    #pragma unroll
    for (int fc = 0; fc < 4; ++fc) {
      sf[fc] = f32x4{0.f, 0.f, 0.f, 0.f};
      int kvr = fc * 16 + ln15;
      #pragma unroll
      for (int ks = 0; ks < 4; ++ks) {
        int chunk = ks * 4 + lh;
        short8_t kf = *(const short8_t*)((const char*)Ks + kvr * 256 + ((chunk ^ (kvr & 7)) << 4));
        sf[fc] = __builtin_amdgcn_mfma_f32_16x16x32_bf16(qf[ks], kf, sf[fc], 0, 0, 0);
      }
    }
    if (kvb == qb) {   // diagonal tile: mask kv > q
      #pragma unroll
      for (int fc = 0; fc < 4; ++fc)
        #pragma unroll
        for (int j = 0; j < 4; ++j) {
          int kvloc = fc * 16 + ln15;
          int qloc = w * 16 + lh * 4 + j;
          if (kvloc > qloc) sf[fc][j] = -1e30f;
        }
    }
    // online softmax
    float mt[4];
    #pragma unroll
    for (int j = 0; j < 4; ++j) {
      float v = fmaxf(fmaxf(sf[0][j], sf[1][j]), fmaxf(sf[2][j], sf[3][j]));
      v = fmaxf(v, __shfl_xor(v, 1));
      v = fmaxf(v, __shfl_xor(v, 2));
      v = fmaxf(v, __shfl_xor(v, 4));
      v = fmaxf(v, __shfl_xor(v, 8));
      mt[j] = v;
    }
    float alpha[4];
    #pragma unroll
    for (int j = 0; j < 4; ++j) {
      float mnew = fmaxf(mrun[j], mt[j]);
      alpha[j] = __expf(mrun[j] - mnew);
      mrun[j] = mnew;
    }
    float rs[4] = {0.f, 0.f, 0.f, 0.f};
    #pragma unroll
    for (int fc = 0; fc < 4; ++fc)
      #pragma unroll
      for (int j = 0; j < 4; ++j) {
        float p = __expf(sf[fc][j] - mrun[j]);
        sf[fc][j] = p;
        rs[j] += p;
      }
    #pragma unroll
    for (int j = 0; j < 4; ++j) {
      float v = rs[j];
      v += __shfl_xor(v, 1);
      v += __shfl_xor(v, 2);
      v += __shfl_xor(v, 4);
      v += __shfl_xor(v, 8);
      lrun[j] = lrun[j] * alpha[j] + v;
    }
    #pragma unroll
    for (int i = 0; i < 8; ++i)
      #pragma unroll
      for (int j = 0; j < 4; ++j) oacc[i][j] *= alpha[j];

    // P -> LDS (bf16), per-wave region; wave-local so only lgkmcnt needed
    u16* Pw = Ps + w * 16 * 72;
    #pragma unroll
    for (int fc = 0; fc < 4; ++fc)
      #pragma unroll
      for (int j = 0; j < 4; ++j)
        Pw[(lh * 4 + j) * 72 + fc * 16 + ln15] = f2bf(sf[fc][j]);
    asm volatile("s_waitcnt lgkmcnt(0)" ::: "memory");

    short8_t pf[2];
    #pragma unroll
    for (int ks = 0; ks < 2; ++ks)
      pf[ks] = *(const short8_t*)((const char*)Pw + ln15 * 144 + ks * 64 + lh * 16);
    #pragma unroll
    for (int fd = 0; fd < 8; ++fd) {
      int dcol = fd * 16 + ln15;
      #pragma unroll
      for (int ks = 0; ks < 2; ++ks) {
        short8_t vf = *(const short8_t*)((const char*)Vs + dcol * 144 + ks * 64 + lh * 16);
        oacc[fd] = __builtin_amdgcn_mfma_f32_16x16x32_bf16(pf[ks], vf, oacc[fd], 0, 0, 0);
      }
    }
  }
  // epilogue: O /= l, write [b][s][h*128+d]
  #pragma unroll
  for (int j = 0; j < 4; ++j) {
    float r = 1.f / lrun[j];
    int q = qb * 64 + w * 16 + lh * 4 + j;
    u16* op = AO + (size_t)(b * Sc + q) * DIMc + h * Dc + ln15;
    #pragma unroll
    for (int fd = 0; fd < 8; ++fd) op[fd * 16] = f2bf(oacc[fd][j] * r);
  }
}

extern "C" void kernel_launch(void* const* d_in, const int* in_sizes, int n_in,
                              void* d_out, int out_size, void* d_ws, size_t ws_size,
                              hipStream_t stream) {
  const float* x  = (const float*)d_in[0];
  const float* wq = (const float*)d_in[1];
  const float* wk = (const float*)d_in[2];
  const float* wv = (const float*)d_in[3];
  const float* wo = (const float*)d_in[4];
  float* out = (float*)d_out;

  char* ws = (char*)d_ws;
  size_t off = 0;
  auto alloc = [&](size_t bytes) -> char* {
    char* p = ws + off;
    off += (bytes + 255) & ~(size_t)255;
    return p;
  };
  // total needed ~145 MB
  float* tbl  = (float*)alloc((size_t)Sc * 64 * 2 * 4);
  u16* xb   = (u16*)alloc((size_t)BS * DIMc * 2);      // x bf16; later reused as Qr
  u16* wA   = (u16*)alloc((size_t)4096 * 4096 * 2);    // wqT, later woT
  u16* wkT  = (u16*)alloc((size_t)1024 * 4096 * 2);
  u16* wvT  = (u16*)alloc((size_t)1024 * 4096 * 2);
  u16* Qb   = (u16*)alloc((size_t)BS * 4096 * 2);      // Q proj; later reused as AO
  u16* Kb   = (u16*)alloc((size_t)BS * 1024 * 2);
  u16* Vb   = (u16*)alloc((size_t)BS * 1024 * 2);
  u16* Krp  = (u16*)alloc((size_t)BS * 1024 * 2);
  u16* Vtp  = (u16*)alloc((size_t)BS * 1024 * 2);
  u16* Qr = xb;   // alias: xb dead after V GEMM
  u16* AO = Qb;   // alias: Qb dead after rope(Q)

  rope_table_k<<<(Sc * 64) / 256, 256, 0, stream>>>(tbl);
  f32_to_bf16_k<<<(BS * DIMc / 4) / 256, 256, 0, stream>>>(x, xb, BS * DIMc / 4);

  transpose_w_k<<<dim3(64, 64), 256, 0, stream>>>(wq, wA, 4096, 4096);
  gemm256<0><<<256, 512, 131072, stream>>>(xb, wA, Qb, 4096, 4096, 4096);
  transpose_w_k<<<dim3(16, 64), 256, 0, stream>>>(wk, wkT, 4096, 1024);
  gemm_bt<0><<<dim3(8, 32), 256, 0, stream>>>(xb, wkT, Kb, 4096, 1024, 4096);
  transpose_w_k<<<dim3(16, 64), 256, 0, stream>>>(wv, wvT, 4096, 1024);
  gemm_bt<0><<<dim3(8, 32), 256, 0, stream>>>(xb, wvT, Vb, 4096, 1024, 4096);

  rope_apply_k<<<(Bc * Sc * Hc * 64) / 256, 256, 0, stream>>>(Qb, Qr, tbl, Hc, 5, 0.08838834764831845f);
  rope_apply_k<<<(Bc * Sc * HKVc * 64) / 256, 256, 0, stream>>>(Kb, Krp, tbl, HKVc, 3, 1.0f);
  transpose_v_k<<<dim3(16, HKVc, Bc), 256, 0, stream>>>(Vb, Vtp);

  attn_k<<<dim3(16, Hc, Bc), 256, 0, stream>>>(Qr, Krp, Vtp, AO);

  transpose_w_k<<<dim3(64, 64), 256, 0, stream>>>(wo, wA, 4096, 4096);
  gemm256<1><<<256, 512, 131072, stream>>>(AO, wA, out, 4096, 4096, 4096);
}

// Round 5
// 640.106 us; speedup vs baseline: 1.2774x; 1.0536x over previous
//
#include <hip/hip_runtime.h>

typedef unsigned short u16;
typedef unsigned int u32;
typedef __attribute__((ext_vector_type(8))) short short8_t;  // 8 bf16 (4 VGPRs)
typedef __attribute__((ext_vector_type(4))) float f32x4;

static constexpr int Bc = 4, Sc = 1024, Hc = 32, HKVc = 8, Dc = 128;
static constexpr int BS = Bc * Sc;     // 4096 rows
static constexpr int DIMc = 4096;

__device__ __forceinline__ u16 f2bf(float f) {
  u32 u = __float_as_uint(f);
  u32 r = (u + 0x7fffu + ((u >> 16) & 1u)) >> 16;  // RNE
  return (u16)r;
}
__device__ __forceinline__ float bf2f(u16 u) {
  return __uint_as_float(((u32)u) << 16);
}
__device__ __forceinline__ void gload_lds16(const void* g, void* l) {
  __builtin_amdgcn_global_load_lds((const __attribute__((address_space(1))) void*)g,
                                   (__attribute__((address_space(3))) void*)l, 16, 0, 0);
}

#define SBAR __builtin_amdgcn_sched_barrier(0)
#define PBARRIER do { SBAR; __builtin_amdgcn_s_barrier(); SBAR; } while (0)
#define WAITVM(N) asm volatile("s_waitcnt vmcnt(" #N ")" ::: "memory")

// ---------------- RoPE table: cos/sin for (s, i) ----------------
__global__ void rope_table_k(float* __restrict__ tbl) {
  int i = blockIdx.x * 256 + threadIdx.x;     // 1024*64
  int s = i >> 6, fi = i & 63;
  float freq = powf(10000.f, -(float)fi / 64.f);
  float ang = (float)s * freq;
  float sv, cv;
  sincosf(ang, &sv, &cv);
  tbl[2 * i] = cv;
  tbl[2 * i + 1] = sv;
}

// ---------------- fp32 -> bf16 convert (vectorized) ----------------
__global__ void f32_to_bf16_k(const float* __restrict__ in, u16* __restrict__ out, int n4) {
  int i = blockIdx.x * 256 + threadIdx.x;
  if (i >= n4) return;
  float4 v = *(const float4*)(in + (size_t)i * 4);
  uint2 pk;
  pk.x = (u32)f2bf(v.x) | ((u32)f2bf(v.y) << 16);
  pk.y = (u32)f2bf(v.z) | ((u32)f2bf(v.w) << 16);
  *(uint2*)(out + (size_t)i * 4) = pk;
}

// ---------------- W (K,N) fp32 -> WT (N,K) bf16, tiled transpose ----------------
__global__ __launch_bounds__(256) void transpose_w_k(const float* __restrict__ W, u16* __restrict__ WT,
                                                     int Kdim, int Ndim) {
  __shared__ float tile[64 * 65];
  const int t = threadIdx.x;
  const int n0 = blockIdx.x * 64, k0 = blockIdx.y * 64;
  #pragma unroll
  for (int p = 0; p < 4; ++p) {
    int idx = p * 256 + t;           // 1024 float4 chunks
    int r = idx >> 4, c = (idx & 15) * 4;
    float4 v = *(const float4*)(W + (size_t)(k0 + r) * Ndim + n0 + c);
    tile[r * 65 + c + 0] = v.x;
    tile[r * 65 + c + 1] = v.y;
    tile[r * 65 + c + 2] = v.z;
    tile[r * 65 + c + 3] = v.w;
  }
  __syncthreads();
  #pragma unroll
  for (int p = 0; p < 2; ++p) {
    int idx = p * 256 + t;           // 512 chunks of 8 bf16
    int n = idx >> 3, c = (idx & 7) * 8;
    alignas(16) u16 o[8];
    #pragma unroll
    for (int i = 0; i < 8; ++i) o[i] = f2bf(tile[(c + i) * 65 + n]);
    *(uint4*)(WT + (size_t)(n0 + n) * Kdim + k0 + c) = *(const uint4*)o;
  }
}

// ---------------- 128^2-tile GEMM (kept for K/V projections) ----------------
template <int OUT_F32>
__global__ __launch_bounds__(256) void gemm_bt(const u16* __restrict__ A, const u16* __restrict__ BT,
                                               void* __restrict__ Cv, int M, int N, int K) {
  __shared__ u16 As[128 * 32];
  __shared__ u16 Bs[128 * 32];
  const int t = threadIdx.x, l = t & 63, w = t >> 6;
  const int bm = blockIdx.y, bn = blockIdx.x;
  const int wr = (w >> 1) * 64, wc = (w & 1) * 64;
  const int ln15 = l & 15, khB = (l >> 4) * 8;
  f32x4 acc[4][4];
  #pragma unroll
  for (int i = 0; i < 4; ++i)
    #pragma unroll
    for (int j = 0; j < 4; ++j) acc[i][j] = f32x4{0.f, 0.f, 0.f, 0.f};
  const int srow = l >> 2, scol = (l & 3) * 8;
  const u16* Ab = A + (size_t)bm * 128 * K;
  const u16* Bb = BT + (size_t)bn * 128 * K;
  for (int k0 = 0; k0 < K; k0 += 32) {
    __syncthreads();
    #pragma unroll
    for (int i = 0; i < 2; ++i) {
      int chunk = w * 2 + i;                 // 8 x 1KB chunks per tile
      int r = chunk * 16 + srow;
      gload_lds16(Ab + (size_t)r * K + k0 + scol, (char*)As + chunk * 1024);
      gload_lds16(Bb + (size_t)r * K + k0 + scol, (char*)Bs + chunk * 1024);
    }
    __syncthreads();
    short8_t af[4], bf[4];
    #pragma unroll
    for (int i = 0; i < 4; ++i) af[i] = *(const short8_t*)&As[(wr + i * 16 + ln15) * 32 + khB];
    #pragma unroll
    for (int j = 0; j < 4; ++j) bf[j] = *(const short8_t*)&Bs[(wc + j * 16 + ln15) * 32 + khB];
    #pragma unroll
    for (int i = 0; i < 4; ++i)
      #pragma unroll
      for (int j = 0; j < 4; ++j)
        acc[i][j] = __builtin_amdgcn_mfma_f32_16x16x32_bf16(af[i], bf[j], acc[i][j], 0, 0, 0);
  }
  const int rbase = bm * 128 + wr + (l >> 4) * 4;
  const int cbase = bn * 128 + wc + ln15;
  #pragma unroll
  for (int i = 0; i < 4; ++i)
    #pragma unroll
    for (int j = 0; j < 4; ++j)
      #pragma unroll
      for (int e = 0; e < 4; ++e) {
        size_t idx = (size_t)(rbase + i * 16 + e) * N + cbase + j * 16;
        if (OUT_F32) ((float*)Cv)[idx] = acc[i][j][e];
        else         ((u16*)Cv)[idx]  = f2bf(acc[i][j][e]);
      }
}

// ---------------- 256^2-tile 8-phase GEMM (big projections) ----------------
#define MFMAQ(QI)                                                                        \
  do {                                                                                   \
    __builtin_amdgcn_s_setprio(1);                                                       \
    _Pragma("unroll") for (int mf = 0; mf < 4; ++mf)                                     \
      _Pragma("unroll") for (int nf = 0; nf < 2; ++nf)                                   \
        _Pragma("unroll") for (int kk = 0; kk < 2; ++kk)                                 \
          acc[QI][mf][nf] = __builtin_amdgcn_mfma_f32_16x16x32_bf16(                     \
              af[mf][kk], bf[nf][kk], acc[QI][mf][nf], 0, 0, 0);                         \
    __builtin_amdgcn_s_setprio(0);                                                       \
  } while (0)

template <int OUT_F32>
__global__ __launch_bounds__(512, 2) void gemm256(const u16* __restrict__ A, const u16* __restrict__ BT,
                                                  void* __restrict__ Cv, int M, int N, int K) {
  extern __shared__ char smem[];   // 131072 B
  const int t = threadIdx.x, l = t & 63, w = t >> 6;
  const int ln15 = l & 15, lh = l >> 4;
  const int NT = K >> 6;

  int id = blockIdx.x;
  int nwg = gridDim.x;
  int swz = ((nwg & 7) == 0) ? ((id & 7) * (nwg >> 3) + (id >> 3)) : id;
  const int nbn = N >> 8;
  const int bm = swz / nbn, bn = swz % nbn;

  const u16* Ag = A + (size_t)bm * 256 * K;
  const u16* Bg = BT + (size_t)bn * 256 * K;

  f32x4 acc[4][4][2];
  #pragma unroll
  for (int q = 0; q < 4; ++q)
    #pragma unroll
    for (int mf = 0; mf < 4; ++mf)
      #pragma unroll
      for (int nf = 0; nf < 2; ++nf) acc[q][mf][nf] = f32x4{0.f, 0.f, 0.f, 0.f};
  short8_t af[4][2], bf[2][2];

  const int srow = (l >> 3);
  const int sck  = (l & 7) ^ srow;
  auto stageA = [&](char* bufbase, int h, int tt) {
    char* lb = bufbase + h * 16384 + w * 1024;
    const u16* g = Ag + (size_t)(h * 128 + w * 8 + srow) * K + tt * 64 + (sck << 3);
    gload_lds16(g, lb);
    gload_lds16(g + (size_t)64 * K, lb + 8192);
  };
  auto stageB = [&](char* bufbase, int h, int tt) {
    char* lb = bufbase + 32768 + h * 16384 + w * 1024;
    const u16* g = Bg + (size_t)(h * 128 + w * 8 + srow) * K + tt * 64 + (sck << 3);
    gload_lds16(g, lb);
    gload_lds16(g + (size_t)64 * K, lb + 8192);
  };
  const int arow = (w >> 2) * 64 + ln15;
  const int brow = (w & 3) * 32 + ln15;
  const int rsw = ln15 & 7;
  auto LDA = [&](const char* cb, int qm) {
    #pragma unroll
    for (int mf = 0; mf < 4; ++mf)
      #pragma unroll
      for (int kk = 0; kk < 2; ++kk)
        af[mf][kk] = *(const short8_t*)(cb + qm * 16384 + (arow + mf * 16) * 128 +
                                        (((kk * 4 + lh) ^ rsw) << 4));
  };
  auto LDB = [&](const char* cb, int qn) {
    #pragma unroll
    for (int nf = 0; nf < 2; ++nf)
      #pragma unroll
      for (int kk = 0; kk < 2; ++kk)
        bf[nf][kk] = *(const short8_t*)(cb + 32768 + qn * 16384 + (brow + nf * 16) * 128 +
                                        (((kk * 4 + lh) ^ rsw) << 4));
  };

  {
    char* b0 = smem;
    char* b1 = smem + 65536;
    stageB(b0, 0, 0);   // S1 B0(0)
    stageA(b0, 1, 0);   // S2 A1(0)
    stageA(b0, 0, 0);   // S3 A0(0)
    stageB(b0, 1, 0);   // S4 B1(0)
    stageB(b1, 0, 1);   // S5 B0(1)
    stageA(b1, 1, 1);   // S6 A1(1)
  }
  WAITVM(6);
  PBARRIER;

  for (int T = 0; T < NT - 1; ++T) {
    char* cb = smem + (T & 1) * 65536;
    char* nb = smem + ((T & 1) ^ 1) * 65536;
    LDA(cb, 0); LDB(cb, 0);
    stageA(nb, 0, T + 1);
    PBARRIER;
    MFMAQ(0);
    PBARRIER;
    LDA(cb, 1);
    stageB(nb, 1, T + 1);
    PBARRIER;
    MFMAQ(1);
    WAITVM(8);
    PBARRIER;
    LDB(cb, 1);
    if (T + 2 < NT) stageB(cb, 0, T + 2);
    PBARRIER;
    MFMAQ(2);
    PBARRIER;
    LDA(cb, 0);
    if (T + 2 < NT) stageA(cb, 1, T + 2);
    PBARRIER;
    MFMAQ(3);
    if (T + 2 < NT) { WAITVM(6); }
    else            { WAITVM(2); }
    PBARRIER;
  }
  {
    char* cb = smem + ((NT - 1) & 1) * 65536;
    LDA(cb, 0); LDB(cb, 0);
    PBARRIER; MFMAQ(0); PBARRIER;
    LDA(cb, 1);
    PBARRIER; MFMAQ(1);
    WAITVM(0);
    PBARRIER;
    LDB(cb, 1);
    PBARRIER; MFMAQ(2); PBARRIER;
    LDA(cb, 0);
    PBARRIER; MFMAQ(3);
  }

  const int rw = (w >> 2) * 64, cw = (w & 3) * 32;
  #pragma unroll
  for (int qi = 0; qi < 4; ++qi) {
    const int qm = (qi == 1 || qi == 2) ? 1 : 0;
    const int qn = (qi >= 2) ? 1 : 0;
    #pragma unroll
    for (int mf = 0; mf < 4; ++mf)
      #pragma unroll
      for (int nf = 0; nf < 2; ++nf)
        #pragma unroll
        for (int e = 0; e < 4; ++e) {
          int row = bm * 256 + qm * 128 + rw + mf * 16 + lh * 4 + e;
          int col = bn * 256 + qn * 128 + cw + nf * 16 + ln15;
          size_t idx = (size_t)row * N + col;
          if (OUT_F32) ((float*)Cv)[idx] = acc[qi][mf][nf][e];
          else         ((u16*)Cv)[idx]  = f2bf(acc[qi][mf][nf][e]);
        }
  }
}

// ---------------- RoPE apply + layout change: [b][s][h][d] -> [b][h][s][d] ----------------
__global__ void rope_apply_k(const u16* __restrict__ In, u16* __restrict__ Out,
                             const float* __restrict__ tbl, int nh, int lognh, float scale) {
  int idx = blockIdx.x * 256 + threadIdx.x;        // one (b,s,h,pair)
  int fi = idx & 63;
  int hs = idx >> 6;
  int h = hs & (nh - 1);
  int rest = hs >> lognh;
  int s = rest & (Sc - 1);
  int b = rest >> 10;
  u32 v = *(const u32*)(In + (size_t)idx * 2);
  float xr = bf2f((u16)(v & 0xffffu));
  float xi = bf2f((u16)(v >> 16));
  float cv = tbl[2 * (s * 64 + fi)];
  float sv = tbl[2 * (s * 64 + fi) + 1];
  float orr = (xr * cv - xi * sv) * scale;
  float oii = (xr * sv + xi * cv) * scale;
  u32 o = (u32)f2bf(orr) | ((u32)f2bf(oii) << 16);
  size_t oidx = ((size_t)(b * nh + h) * Sc + s) * 64 + fi;
  *(u32*)(Out + oidx * 2) = o;
}

// ---------------- V: [b][s][hkv][d] -> VT: [b][hkv][d][s] (tiled transpose) ----------------
__global__ __launch_bounds__(256) void transpose_v_k(const u16* __restrict__ V, u16* __restrict__ VT) {
  __shared__ u16 tile[64 * 136];    // 64 s x 128 d, stride padded to 136
  const int t = threadIdx.x;
  const int s0 = blockIdx.x * 64;
  const int hkv = blockIdx.y, b = blockIdx.z;
  #pragma unroll
  for (int p = 0; p < 4; ++p) {
    int idx = p * 256 + t;             // 1024 chunks of 8 bf16
    int r = idx >> 4, c = (idx & 15) * 8;
    uint4 v = *(const uint4*)(V + (size_t)(b * Sc + s0 + r) * (HKVc * Dc) + hkv * Dc + c);
    *(uint4*)&tile[r * 136 + c] = v;
  }
  __syncthreads();
  #pragma unroll
  for (int p = 0; p < 4; ++p) {
    int idx = p * 256 + t;             // 1024 chunks of 8 bf16 (128 d rows x 8 s-chunks)
    int d = idx >> 3, sc = (idx & 7) * 8;
    alignas(16) u16 o[8];
    #pragma unroll
    for (int i = 0; i < 8; ++i) o[i] = tile[(sc + i) * 136 + d];
    *(uint4*)(VT + ((size_t)(b * HKVc + hkv) * Dc + d) * Sc + s0 + sc) = *(const uint4*)o;
  }
}

// ---------------- Flash attention (causal, GQA), 8-wave QBLK=128, dbuf K/V ----------------
// Q: [b][h][s][d] (pre-scaled); K: [b][hkv][s][d]; VT: [b][hkv][d][s]
// LDS map: Ks[2][64][128]swz @0 (16K ea) | Vs[2][128][64]swz @32768 (16K ea)
//          Ps[8][16][64]swz @65536 (2K/wave). Total 81920 B -> exactly 2 blocks/CU.
__global__ __launch_bounds__(512, 4) void attn_k(const u16* __restrict__ Q, const u16* __restrict__ Kr,
                                                 const u16* __restrict__ Vt, u16* __restrict__ AO) {
  extern __shared__ char smem[];
  const int t = threadIdx.x, l = t & 63, w = t >> 6;
  const int qb = blockIdx.x, h = blockIdx.y, b = blockIdx.z;
  const int hkv = h >> 2;
  const int ln15 = l & 15, lh = l >> 4;
  const int NT = 2 * qb + 2;

  const u16* Kg0 = Kr + (size_t)(b * HKVc + hkv) * Sc * Dc;
  const u16* Vg0 = Vt + (size_t)(b * HKVc + hkv) * Dc * Sc;

  // staging: pre-swizzled global chunk -> linear LDS (rule 21); 4 loads/wave/tile
  auto stageK = [&](int buf, int tt) {
    char* base = smem + buf * 16384 + w * 2048;
    #pragma unroll
    for (int i = 0; i < 2; ++i) {
      int row = w * 8 + i * 4 + (l >> 4);
      int c = l & 15;
      gload_lds16(Kg0 + (size_t)(tt * 64 + row) * Dc + ((c ^ (row & 7)) << 3), base + i * 1024);
    }
  };
  auto stageV = [&](int buf, int tt) {
    char* base = smem + 32768 + buf * 16384 + w * 2048;
    #pragma unroll
    for (int i = 0; i < 2; ++i) {
      int d = w * 16 + i * 8 + (l >> 3);
      int c = l & 7;
      gload_lds16(Vg0 + (size_t)d * Sc + tt * 64 + ((c ^ (d & 7)) << 3), base + i * 1024);
    }
  };

  // Q fragments (16 q rows per wave)
  short8_t qf[4];
  {
    int q = qb * 128 + w * 16 + ln15;
    const u16* qp = Q + ((size_t)(b * Hc + h) * Sc + q) * Dc + lh * 8;
    #pragma unroll
    for (int ks = 0; ks < 4; ++ks) qf[ks] = *(const short8_t*)(qp + ks * 32);
  }
  SBAR;   // keep qf loads issued before staging (vmcnt ordering)

  f32x4 oacc[8];
  #pragma unroll
  for (int i = 0; i < 8; ++i) oacc[i] = f32x4{0.f, 0.f, 0.f, 0.f};
  float mrun[4], lrun[4];
  #pragma unroll
  for (int j = 0; j < 4; ++j) { mrun[j] = -1e30f; lrun[j] = 0.f; }

  // prologue: two tiles in flight
  stageK(0, 0); stageV(0, 0);
  stageK(1, 1); stageV(1, 1);

  u16* Pw = (u16*)(smem + 65536 + w * 2048);
  const int qmaxw = qb * 128 + w * 16 + 15;

  for (int T = 0; T < NT; ++T) {
    if (T < NT - 1) { WAITVM(4); } else { WAITVM(0); }
    PBARRIER;
    const char* Kb = smem + (T & 1) * 16384;
    const char* Vb = smem + 32768 + (T & 1) * 16384;

    if (T * 64 <= qmaxw) {     // wave has unmasked rows in this tile
      // QK^T: 16 q rows x 64 kv
      f32x4 sf[4];
      #pragma unroll
      for (int fc = 0; fc < 4; ++fc) {
        sf[fc] = f32x4{0.f, 0.f, 0.f, 0.f};
        int kvr = fc * 16 + ln15;
        #pragma unroll
        for (int ks = 0; ks < 4; ++ks) {
          int chunk = ks * 4 + lh;
          short8_t kf = *(const short8_t*)(Kb + kvr * 256 + ((chunk ^ (kvr & 7)) << 4));
          sf[fc] = __builtin_amdgcn_mfma_f32_16x16x32_bf16(qf[ks], kf, sf[fc], 0, 0, 0);
        }
      }
      if (T * 64 + 63 > qb * 128 + w * 16) {   // diagonal-overlapping tile: mask kv > q
        #pragma unroll
        for (int fc = 0; fc < 4; ++fc)
          #pragma unroll
          for (int j = 0; j < 4; ++j) {
            int kvg = T * 64 + fc * 16 + ln15;
            int qg = qb * 128 + w * 16 + lh * 4 + j;
            if (kvg > qg) sf[fc][j] = -1e30f;
          }
      }
      // online softmax
      float mt[4];
      #pragma unroll
      for (int j = 0; j < 4; ++j) {
        float v = fmaxf(fmaxf(sf[0][j], sf[1][j]), fmaxf(sf[2][j], sf[3][j]));
        v = fmaxf(v, __shfl_xor(v, 1));
        v = fmaxf(v, __shfl_xor(v, 2));
        v = fmaxf(v, __shfl_xor(v, 4));
        v = fmaxf(v, __shfl_xor(v, 8));
        mt[j] = v;
      }
      float alpha[4];
      #pragma unroll
      for (int j = 0; j < 4; ++j) {
        float mnew = fmaxf(mrun[j], mt[j]);
        alpha[j] = __expf(mrun[j] - mnew);
        mrun[j] = mnew;
      }
      float rs[4] = {0.f, 0.f, 0.f, 0.f};
      #pragma unroll
      for (int fc = 0; fc < 4; ++fc)
        #pragma unroll
        for (int j = 0; j < 4; ++j) {
          float p = __expf(sf[fc][j] - mrun[j]);
          sf[fc][j] = p;
          rs[j] += p;
        }
      #pragma unroll
      for (int j = 0; j < 4; ++j) {
        float v = rs[j];
        v += __shfl_xor(v, 1);
        v += __shfl_xor(v, 2);
        v += __shfl_xor(v, 4);
        v += __shfl_xor(v, 8);
        lrun[j] = lrun[j] * alpha[j] + v;
      }
      #pragma unroll
      for (int i = 0; i < 8; ++i)
        #pragma unroll
        for (int j = 0; j < 4; ++j) oacc[i][j] *= alpha[j];

      // P -> LDS (bf16, XOR-swizzled rows of 128B), wave-local
      #pragma unroll
      for (int fc = 0; fc < 4; ++fc)
        #pragma unroll
        for (int j = 0; j < 4; ++j) {
          int qrow = lh * 4 + j;
          int chunk = (fc * 2 + (ln15 >> 3)) ^ (qrow & 7);
          ((u16*)((char*)Pw + qrow * 128 + chunk * 16))[ln15 & 7] = f2bf(sf[fc][j]);
        }
      asm volatile("s_waitcnt lgkmcnt(0)" ::: "memory");
      SBAR;

      short8_t pf[2];
      #pragma unroll
      for (int ks = 0; ks < 2; ++ks) {
        int chunk = ks * 4 + lh;
        pf[ks] = *(const short8_t*)((const char*)Pw + ln15 * 128 + ((chunk ^ (ln15 & 7)) << 4));
      }
      #pragma unroll
      for (int fd = 0; fd < 8; ++fd) {
        int dcol = fd * 16 + ln15;
        #pragma unroll
        for (int ks = 0; ks < 2; ++ks) {
          int chunk = ks * 4 + lh;
          short8_t vf = *(const short8_t*)(Vb + dcol * 128 + ((chunk ^ (dcol & 7)) << 4));
          oacc[fd] = __builtin_amdgcn_mfma_f32_16x16x32_bf16(pf[ks], vf, oacc[fd], 0, 0, 0);
        }
      }
    }
    PBARRIER;                        // all waves done reading buf (T&1)
    if (T + 2 < NT) { stageK(T & 1, T + 2); stageV(T & 1, T + 2); }  // fly during tile T+1
  }

  // epilogue: O /= l, write [b][s][h*128+d]
  #pragma unroll
  for (int j = 0; j < 4; ++j) {
    float r = 1.f / lrun[j];
    int q = qb * 128 + w * 16 + lh * 4 + j;
    u16* op = AO + (size_t)(b * Sc + q) * DIMc + h * Dc + ln15;
    #pragma unroll
    for (int fd = 0; fd < 8; ++fd) op[fd * 16] = f2bf(oacc[fd][j] * r);
  }
}

extern "C" void kernel_launch(void* const* d_in, const int* in_sizes, int n_in,
                              void* d_out, int out_size, void* d_ws, size_t ws_size,
                              hipStream_t stream) {
  const float* x  = (const float*)d_in[0];
  const float* wq = (const float*)d_in[1];
  const float* wk = (const float*)d_in[2];
  const float* wv = (const float*)d_in[3];
  const float* wo = (const float*)d_in[4];
  float* out = (float*)d_out;

  char* ws = (char*)d_ws;
  size_t off = 0;
  auto alloc = [&](size_t bytes) -> char* {
    char* p = ws + off;
    off += (bytes + 255) & ~(size_t)255;
    return p;
  };
  float* tbl  = (float*)alloc((size_t)Sc * 64 * 2 * 4);
  u16* xb   = (u16*)alloc((size_t)BS * DIMc * 2);      // x bf16; later reused as Qr
  u16* wA   = (u16*)alloc((size_t)4096 * 4096 * 2);    // wqT, later woT
  u16* wkT  = (u16*)alloc((size_t)1024 * 4096 * 2);
  u16* wvT  = (u16*)alloc((size_t)1024 * 4096 * 2);
  u16* Qb   = (u16*)alloc((size_t)BS * 4096 * 2);      // Q proj; later reused as AO
  u16* Kb   = (u16*)alloc((size_t)BS * 1024 * 2);
  u16* Vb   = (u16*)alloc((size_t)BS * 1024 * 2);
  u16* Krp  = (u16*)alloc((size_t)BS * 1024 * 2);
  u16* Vtp  = (u16*)alloc((size_t)BS * 1024 * 2);
  u16* Qr = xb;   // alias: xb dead after V GEMM
  u16* AO = Qb;   // alias: Qb dead after rope(Q)

  rope_table_k<<<(Sc * 64) / 256, 256, 0, stream>>>(tbl);
  f32_to_bf16_k<<<(BS * DIMc / 4) / 256, 256, 0, stream>>>(x, xb, BS * DIMc / 4);

  transpose_w_k<<<dim3(64, 64), 256, 0, stream>>>(wq, wA, 4096, 4096);
  gemm256<0><<<256, 512, 131072, stream>>>(xb, wA, Qb, 4096, 4096, 4096);
  transpose_w_k<<<dim3(16, 64), 256, 0, stream>>>(wk, wkT, 4096, 1024);
  gemm_bt<0><<<dim3(8, 32), 256, 0, stream>>>(xb, wkT, Kb, 4096, 1024, 4096);
  transpose_w_k<<<dim3(16, 64), 256, 0, stream>>>(wv, wvT, 4096, 1024);
  gemm_bt<0><<<dim3(8, 32), 256, 0, stream>>>(xb, wvT, Vb, 4096, 1024, 4096);

  rope_apply_k<<<(Bc * Sc * Hc * 64) / 256, 256, 0, stream>>>(Qb, Qr, tbl, Hc, 5, 0.08838834764831845f);
  rope_apply_k<<<(Bc * Sc * HKVc * 64) / 256, 256, 0, stream>>>(Kb, Krp, tbl, HKVc, 3, 1.0f);
  transpose_v_k<<<dim3(16, HKVc, Bc), 256, 0, stream>>>(Vb, Vtp);

  attn_k<<<dim3(8, Hc, Bc), 512, 81920, stream>>>(Qr, Krp, Vtp, AO);

  transpose_w_k<<<dim3(64, 64), 256, 0, stream>>>(wo, wA, 4096, 4096);
  gemm256<1><<<256, 512, 131072, stream>>>(AO, wA, out, 4096, 4096, 4096);
}

// Round 6
// 602.341 us; speedup vs baseline: 1.3575x; 1.0627x over previous
//
#include <hip/hip_runtime.h>

typedef unsigned short u16;
typedef unsigned int u32;
typedef __attribute__((ext_vector_type(8))) short short8_t;  // 8 bf16 (4 VGPRs)
typedef __attribute__((ext_vector_type(4))) float f32x4;

static constexpr int Bc = 4, Sc = 1024, Hc = 32, HKVc = 8, Dc = 128;
static constexpr int BS = Bc * Sc;     // 4096 rows
static constexpr int DIMc = 4096;

__device__ __forceinline__ u16 f2bf(float f) {
  u32 u = __float_as_uint(f);
  u32 r = (u + 0x7fffu + ((u >> 16) & 1u)) >> 16;  // RNE
  return (u16)r;
}
__device__ __forceinline__ float bf2f(u16 u) {
  return __uint_as_float(((u32)u) << 16);
}
__device__ __forceinline__ void gload_lds16(const void* g, void* l) {
  __builtin_amdgcn_global_load_lds((const __attribute__((address_space(1))) void*)g,
                                   (__attribute__((address_space(3))) void*)l, 16, 0, 0);
}

#define SBAR __builtin_amdgcn_sched_barrier(0)
#define PBARRIER do { SBAR; __builtin_amdgcn_s_barrier(); SBAR; } while (0)
#define WAITVM(N) asm volatile("s_waitcnt vmcnt(" #N ")" ::: "memory")

// ---------------- RoPE table: cos/sin for (s, i) ----------------
__global__ void rope_table_k(float* __restrict__ tbl) {
  int i = blockIdx.x * 256 + threadIdx.x;     // 1024*64
  int s = i >> 6, fi = i & 63;
  float freq = powf(10000.f, -(float)fi / 64.f);
  float ang = (float)s * freq;
  float sv, cv;
  sincosf(ang, &sv, &cv);
  tbl[2 * i] = cv;
  tbl[2 * i + 1] = sv;
}

// ---------------- fp32 -> bf16 convert (vectorized) ----------------
__global__ void f32_to_bf16_k(const float* __restrict__ in, u16* __restrict__ out, int n4) {
  int i = blockIdx.x * 256 + threadIdx.x;
  if (i >= n4) return;
  float4 v = *(const float4*)(in + (size_t)i * 4);
  uint2 pk;
  pk.x = (u32)f2bf(v.x) | ((u32)f2bf(v.y) << 16);
  pk.y = (u32)f2bf(v.z) | ((u32)f2bf(v.w) << 16);
  *(uint2*)(out + (size_t)i * 4) = pk;
}

// ---------------- W (K,N) fp32 -> WT (N,K) bf16, tiled transpose ----------------
__global__ __launch_bounds__(256) void transpose_w_k(const float* __restrict__ W, u16* __restrict__ WT,
                                                     int Kdim, int Ndim) {
  __shared__ float tile[64 * 65];
  const int t = threadIdx.x;
  const int n0 = blockIdx.x * 64, k0 = blockIdx.y * 64;
  #pragma unroll
  for (int p = 0; p < 4; ++p) {
    int idx = p * 256 + t;           // 1024 float4 chunks
    int r = idx >> 4, c = (idx & 15) * 4;
    float4 v = *(const float4*)(W + (size_t)(k0 + r) * Ndim + n0 + c);
    tile[r * 65 + c + 0] = v.x;
    tile[r * 65 + c + 1] = v.y;
    tile[r * 65 + c + 2] = v.z;
    tile[r * 65 + c + 3] = v.w;
  }
  __syncthreads();
  #pragma unroll
  for (int p = 0; p < 2; ++p) {
    int idx = p * 256 + t;           // 512 chunks of 8 bf16
    int n = idx >> 3, c = (idx & 7) * 8;
    alignas(16) u16 o[8];
    #pragma unroll
    for (int i = 0; i < 8; ++i) o[i] = f2bf(tile[(c + i) * 65 + n]);
    *(uint4*)(WT + (size_t)(n0 + n) * Kdim + k0 + c) = *(const uint4*)o;
  }
}

// ---------------- 128^2-tile GEMM (kept for K/V projections) ----------------
template <int OUT_F32>
__global__ __launch_bounds__(256) void gemm_bt(const u16* __restrict__ A, const u16* __restrict__ BT,
                                               void* __restrict__ Cv, int M, int N, int K) {
  __shared__ u16 As[128 * 32];
  __shared__ u16 Bs[128 * 32];
  const int t = threadIdx.x, l = t & 63, w = t >> 6;
  const int bm = blockIdx.y, bn = blockIdx.x;
  const int wr = (w >> 1) * 64, wc = (w & 1) * 64;
  const int ln15 = l & 15, khB = (l >> 4) * 8;
  f32x4 acc[4][4];
  #pragma unroll
  for (int i = 0; i < 4; ++i)
    #pragma unroll
    for (int j = 0; j < 4; ++j) acc[i][j] = f32x4{0.f, 0.f, 0.f, 0.f};
  const int srow = l >> 2, scol = (l & 3) * 8;
  const u16* Ab = A + (size_t)bm * 128 * K;
  const u16* Bb = BT + (size_t)bn * 128 * K;
  for (int k0 = 0; k0 < K; k0 += 32) {
    __syncthreads();
    #pragma unroll
    for (int i = 0; i < 2; ++i) {
      int chunk = w * 2 + i;                 // 8 x 1KB chunks per tile
      int r = chunk * 16 + srow;
      gload_lds16(Ab + (size_t)r * K + k0 + scol, (char*)As + chunk * 1024);
      gload_lds16(Bb + (size_t)r * K + k0 + scol, (char*)Bs + chunk * 1024);
    }
    __syncthreads();
    short8_t af[4], bf[4];
    #pragma unroll
    for (int i = 0; i < 4; ++i) af[i] = *(const short8_t*)&As[(wr + i * 16 + ln15) * 32 + khB];
    #pragma unroll
    for (int j = 0; j < 4; ++j) bf[j] = *(const short8_t*)&Bs[(wc + j * 16 + ln15) * 32 + khB];
    #pragma unroll
    for (int i = 0; i < 4; ++i)
      #pragma unroll
      for (int j = 0; j < 4; ++j)
        acc[i][j] = __builtin_amdgcn_mfma_f32_16x16x32_bf16(af[i], bf[j], acc[i][j], 0, 0, 0);
  }
  const int rbase = bm * 128 + wr + (l >> 4) * 4;
  const int cbase = bn * 128 + wc + ln15;
  #pragma unroll
  for (int i = 0; i < 4; ++i)
    #pragma unroll
    for (int j = 0; j < 4; ++j)
      #pragma unroll
      for (int e = 0; e < 4; ++e) {
        size_t idx = (size_t)(rbase + i * 16 + e) * N + cbase + j * 16;
        if (OUT_F32) ((float*)Cv)[idx] = acc[i][j][e];
        else         ((u16*)Cv)[idx]  = f2bf(acc[i][j][e]);
      }
}

// ---------------- 256^2-tile 8-phase GEMM (big projections) ----------------
#define MFMAQ(QI)                                                                        \
  do {                                                                                   \
    __builtin_amdgcn_s_setprio(1);                                                       \
    _Pragma("unroll") for (int mf = 0; mf < 4; ++mf)                                     \
      _Pragma("unroll") for (int nf = 0; nf < 2; ++nf)                                   \
        _Pragma("unroll") for (int kk = 0; kk < 2; ++kk)                                 \
          acc[QI][mf][nf] = __builtin_amdgcn_mfma_f32_16x16x32_bf16(                     \
              af[mf][kk], bf[nf][kk], acc[QI][mf][nf], 0, 0, 0);                         \
    __builtin_amdgcn_s_setprio(0);                                                       \
  } while (0)

template <int OUT_F32>
__global__ __launch_bounds__(512, 2) void gemm256(const u16* __restrict__ A, const u16* __restrict__ BT,
                                                  void* __restrict__ Cv, int M, int N, int K) {
  extern __shared__ char smem[];   // 131072 B
  const int t = threadIdx.x, l = t & 63, w = t >> 6;
  const int ln15 = l & 15, lh = l >> 4;
  const int NT = K >> 6;

  int id = blockIdx.x;
  int nwg = gridDim.x;
  int swz = ((nwg & 7) == 0) ? ((id & 7) * (nwg >> 3) + (id >> 3)) : id;
  const int nbn = N >> 8;
  const int bm = swz / nbn, bn = swz % nbn;

  const u16* Ag = A + (size_t)bm * 256 * K;
  const u16* Bg = BT + (size_t)bn * 256 * K;

  f32x4 acc[4][4][2];
  #pragma unroll
  for (int q = 0; q < 4; ++q)
    #pragma unroll
    for (int mf = 0; mf < 4; ++mf)
      #pragma unroll
      for (int nf = 0; nf < 2; ++nf) acc[q][mf][nf] = f32x4{0.f, 0.f, 0.f, 0.f};
  short8_t af[4][2], bf[2][2];

  const int srow = (l >> 3);
  const int sck  = (l & 7) ^ srow;
  auto stageA = [&](char* bufbase, int h, int tt) {
    char* lb = bufbase + h * 16384 + w * 1024;
    const u16* g = Ag + (size_t)(h * 128 + w * 8 + srow) * K + tt * 64 + (sck << 3);
    gload_lds16(g, lb);
    gload_lds16(g + (size_t)64 * K, lb + 8192);
  };
  auto stageB = [&](char* bufbase, int h, int tt) {
    char* lb = bufbase + 32768 + h * 16384 + w * 1024;
    const u16* g = Bg + (size_t)(h * 128 + w * 8 + srow) * K + tt * 64 + (sck << 3);
    gload_lds16(g, lb);
    gload_lds16(g + (size_t)64 * K, lb + 8192);
  };
  const int arow = (w >> 2) * 64 + ln15;
  const int brow = (w & 3) * 32 + ln15;
  const int rsw = ln15 & 7;
  auto LDA = [&](const char* cb, int qm) {
    #pragma unroll
    for (int mf = 0; mf < 4; ++mf)
      #pragma unroll
      for (int kk = 0; kk < 2; ++kk)
        af[mf][kk] = *(const short8_t*)(cb + qm * 16384 + (arow + mf * 16) * 128 +
                                        (((kk * 4 + lh) ^ rsw) << 4));
  };
  auto LDB = [&](const char* cb, int qn) {
    #pragma unroll
    for (int nf = 0; nf < 2; ++nf)
      #pragma unroll
      for (int kk = 0; kk < 2; ++kk)
        bf[nf][kk] = *(const short8_t*)(cb + 32768 + qn * 16384 + (brow + nf * 16) * 128 +
                                        (((kk * 4 + lh) ^ rsw) << 4));
  };

  {
    char* b0 = smem;
    char* b1 = smem + 65536;
    stageB(b0, 0, 0);   // S1 B0(0)
    stageA(b0, 1, 0);   // S2 A1(0)
    stageA(b0, 0, 0);   // S3 A0(0)
    stageB(b0, 1, 0);   // S4 B1(0)
    stageB(b1, 0, 1);   // S5 B0(1)
    stageA(b1, 1, 1);   // S6 A1(1)
  }
  WAITVM(6);
  PBARRIER;

  for (int T = 0; T < NT - 1; ++T) {
    char* cb = smem + (T & 1) * 65536;
    char* nb = smem + ((T & 1) ^ 1) * 65536;
    LDA(cb, 0); LDB(cb, 0);
    stageA(nb, 0, T + 1);
    PBARRIER;
    MFMAQ(0);
    PBARRIER;
    LDA(cb, 1);
    stageB(nb, 1, T + 1);
    PBARRIER;
    MFMAQ(1);
    WAITVM(8);
    PBARRIER;
    LDB(cb, 1);
    if (T + 2 < NT) stageB(cb, 0, T + 2);
    PBARRIER;
    MFMAQ(2);
    PBARRIER;
    LDA(cb, 0);
    if (T + 2 < NT) stageA(cb, 1, T + 2);
    PBARRIER;
    MFMAQ(3);
    if (T + 2 < NT) { WAITVM(6); }
    else            { WAITVM(2); }
    PBARRIER;
  }
  {
    char* cb = smem + ((NT - 1) & 1) * 65536;
    LDA(cb, 0); LDB(cb, 0);
    PBARRIER; MFMAQ(0); PBARRIER;
    LDA(cb, 1);
    PBARRIER; MFMAQ(1);
    WAITVM(0);
    PBARRIER;
    LDB(cb, 1);
    PBARRIER; MFMAQ(2); PBARRIER;
    LDA(cb, 0);
    PBARRIER; MFMAQ(3);
  }

  const int rw = (w >> 2) * 64, cw = (w & 3) * 32;
  #pragma unroll
  for (int qi = 0; qi < 4; ++qi) {
    const int qm = (qi == 1 || qi == 2) ? 1 : 0;
    const int qn = (qi >= 2) ? 1 : 0;
    #pragma unroll
    for (int mf = 0; mf < 4; ++mf)
      #pragma unroll
      for (int nf = 0; nf < 2; ++nf)
        #pragma unroll
        for (int e = 0; e < 4; ++e) {
          int row = bm * 256 + qm * 128 + rw + mf * 16 + lh * 4 + e;
          int col = bn * 256 + qn * 128 + cw + nf * 16 + ln15;
          size_t idx = (size_t)row * N + col;
          if (OUT_F32) ((float*)Cv)[idx] = acc[qi][mf][nf][e];
          else         ((u16*)Cv)[idx]  = f2bf(acc[qi][mf][nf][e]);
        }
  }
}

// ---------------- RoPE apply + layout change: [b][s][h][d] -> [b][h][s][d] ----------------
__global__ void rope_apply_k(const u16* __restrict__ In, u16* __restrict__ Out,
                             const float* __restrict__ tbl, int nh, int lognh, float scale) {
  int idx = blockIdx.x * 256 + threadIdx.x;        // one (b,s,h,pair)
  int fi = idx & 63;
  int hs = idx >> 6;
  int h = hs & (nh - 1);
  int rest = hs >> lognh;
  int s = rest & (Sc - 1);
  int b = rest >> 10;
  u32 v = *(const u32*)(In + (size_t)idx * 2);
  float xr = bf2f((u16)(v & 0xffffu));
  float xi = bf2f((u16)(v >> 16));
  float cv = tbl[2 * (s * 64 + fi)];
  float sv = tbl[2 * (s * 64 + fi) + 1];
  float orr = (xr * cv - xi * sv) * scale;
  float oii = (xr * sv + xi * cv) * scale;
  u32 o = (u32)f2bf(orr) | ((u32)f2bf(oii) << 16);
  size_t oidx = ((size_t)(b * nh + h) * Sc + s) * 64 + fi;
  *(u32*)(Out + oidx * 2) = o;
}

// ---------------- V: [b][s][hkv][d] -> VT: [b][hkv][d][sigma(s)] ----------------
// Column permutation sigma (within each 32-col block): position p = lh*8 + b2*4 + j
// holds V row kv = b2*16 + lh*4 + j. This makes the attn PV A-fragment a pure
// per-lane repack of the swapped-QK^T output (no cross-lane exchange).
__global__ __launch_bounds__(256) void transpose_v_k(const u16* __restrict__ V, u16* __restrict__ VT) {
  __shared__ u16 tile[64 * 136];    // 64 s x 128 d, stride padded to 136
  const int t = threadIdx.x;
  const int s0 = blockIdx.x * 64;
  const int hkv = blockIdx.y, b = blockIdx.z;
  #pragma unroll
  for (int p = 0; p < 4; ++p) {
    int idx = p * 256 + t;             // 1024 chunks of 8 bf16
    int r = idx >> 4, c = (idx & 15) * 8;
    uint4 v = *(const uint4*)(V + (size_t)(b * Sc + s0 + r) * (HKVc * Dc) + hkv * Dc + c);
    *(uint4*)&tile[r * 136 + c] = v;
  }
  __syncthreads();
  #pragma unroll
  for (int p = 0; p < 4; ++p) {
    int idx = p * 256 + t;             // 128 d rows x 8 s-chunks of 8
    int d = idx >> 3, sc = (idx & 7) * 8;
    size_t rowbase = ((size_t)(b * HKVc + hkv) * Dc + d) * Sc + s0;
    #pragma unroll
    for (int h2 = 0; h2 < 2; ++h2) {
      int sl = sc + h2 * 4;            // 4 consecutive source kv (same b2,lh bits)
      int pp = (sl & 32) + ((sl >> 2) & 3) * 8 + ((sl >> 4) & 1) * 4;
      alignas(8) u16 o4[4];
      #pragma unroll
      for (int j = 0; j < 4; ++j) o4[j] = tile[(sl + j) * 136 + d];
      *(uint2*)(VT + rowbase + pp) = *(const uint2*)o4;
    }
  }
}

// ---------------- Flash attention (causal, GQA), swapped-QK^T, P in registers ----------------
// Q: [b][h][s][d] (pre-scaled); K: [b][hkv][s][d]; VT: [b][hkv][d][sigma(s)]
// LDS: K dbuf 2x16K @0 | V dbuf 2x16K @32768. Total 65536 -> 2 blocks/CU.
// S^T = mfma(kf, qf): lane holds q = ln15, kv = fc*16 + lh*4 + j.
// PV A-frag pa[ks] = bf16(concat(sf[2ks], sf[2ks+1])) thanks to sigma-permuted V.
__global__ __launch_bounds__(512, 4) void attn_k(const u16* __restrict__ Q, const u16* __restrict__ Kr,
                                                 const u16* __restrict__ Vt, u16* __restrict__ AO) {
  extern __shared__ char smem[];
  const int t = threadIdx.x, l = t & 63, w = t >> 6;
  const int qb = (int)gridDim.x - 1 - (int)blockIdx.x;   // big causal tiles dispatched first
  const int h = blockIdx.y, b = blockIdx.z;
  const int hkv = h >> 2;
  const int ln15 = l & 15, lh = l >> 4;
  const int NT = 2 * qb + 2;

  const u16* Kg0 = Kr + (size_t)(b * HKVc + hkv) * Sc * Dc;
  const u16* Vg0 = Vt + (size_t)(b * HKVc + hkv) * Dc * Sc;

  auto stageK = [&](int buf, int tt) {
    char* base = smem + buf * 16384 + w * 2048;
    #pragma unroll
    for (int i = 0; i < 2; ++i) {
      int row = w * 8 + i * 4 + (l >> 4);
      int c = l & 15;
      gload_lds16(Kg0 + (size_t)(tt * 64 + row) * Dc + ((c ^ (row & 7)) << 3), base + i * 1024);
    }
  };
  auto stageV = [&](int buf, int tt) {
    char* base = smem + 32768 + buf * 16384 + w * 2048;
    #pragma unroll
    for (int i = 0; i < 2; ++i) {
      int d = w * 16 + i * 8 + (l >> 3);
      int c = l & 7;
      gload_lds16(Vg0 + (size_t)d * Sc + tt * 64 + ((c ^ (d & 7)) << 3), base + i * 1024);
    }
  };

  // Q fragments (16 q rows per wave; q = w*16 + ln15 within the 128-row block)
  short8_t qf[4];
  {
    int q = qb * 128 + w * 16 + ln15;
    const u16* qp = Q + ((size_t)(b * Hc + h) * Sc + q) * Dc + lh * 8;
    #pragma unroll
    for (int ks = 0; ks < 4; ++ks) qf[ks] = *(const short8_t*)(qp + ks * 32);
  }
  SBAR;   // qf loads issued before staging (vmcnt ordering)

  f32x4 oacc[8];
  #pragma unroll
  for (int i = 0; i < 8; ++i) oacc[i] = f32x4{0.f, 0.f, 0.f, 0.f};
  float mrun = -1e30f, lrun = 0.f;

  stageK(0, 0); stageV(0, 0);
  stageK(1, 1); stageV(1, 1);

  const int qmaxw = qb * 128 + w * 16 + 15;
  const int qlane = qb * 128 + w * 16 + ln15;

  for (int T = 0; T < NT; ++T) {
    if (T < NT - 1) { WAITVM(4); } else { WAITVM(0); }
    PBARRIER;
    const char* Kb = smem + (T & 1) * 16384;
    const char* Vb = smem + 32768 + (T & 1) * 16384;

    if (T * 64 <= qmaxw) {     // wave has unmasked rows in this tile
      // S^T = K·Q^T: lane q=ln15; rows kv = fc*16 + lh*4 + j
      f32x4 sf[4];
      #pragma unroll
      for (int fc = 0; fc < 4; ++fc) {
        sf[fc] = f32x4{0.f, 0.f, 0.f, 0.f};
        int kvr = fc * 16 + ln15;     // A-operand row (gathered across lanes)
        #pragma unroll
        for (int ks = 0; ks < 4; ++ks) {
          int chunk = ks * 4 + lh;
          short8_t kf = *(const short8_t*)(Kb + kvr * 256 + ((chunk ^ (kvr & 7)) << 4));
          sf[fc] = __builtin_amdgcn_mfma_f32_16x16x32_bf16(kf, qf[ks], sf[fc], 0, 0, 0);
        }
      }
      if (T * 64 + 63 > qb * 128 + w * 16) {   // diagonal-overlapping: mask kv > q
        #pragma unroll
        for (int fc = 0; fc < 4; ++fc)
          #pragma unroll
          for (int j = 0; j < 4; ++j) {
            int kvg = T * 64 + fc * 16 + lh * 4 + j;
            if (kvg > qlane) sf[fc][j] = -1e30f;
          }
      }
      // online softmax: full row of q=ln15 lives in 16 regs x 4 lh-groups
      float mx = sf[0][0];
      #pragma unroll
      for (int fc = 0; fc < 4; ++fc)
        #pragma unroll
        for (int j = 0; j < 4; ++j) mx = fmaxf(mx, sf[fc][j]);
      mx = fmaxf(mx, __shfl_xor(mx, 16));
      mx = fmaxf(mx, __shfl_xor(mx, 32));
      float mnew = fmaxf(mrun, mx);
      float alpha = __expf(mrun - mnew);
      mrun = mnew;
      float rs = 0.f;
      #pragma unroll
      for (int fc = 0; fc < 4; ++fc)
        #pragma unroll
        for (int j = 0; j < 4; ++j) {
          float p = __expf(sf[fc][j] - mnew);
          sf[fc][j] = p;
          rs += p;
        }
      rs += __shfl_xor(rs, 16);
      rs += __shfl_xor(rs, 32);
      lrun = lrun * alpha + rs;
      // rescale oacc rows (row q-local = lh*4 + j; alpha lives on lane ln15 = q-local)
      float arow[4];
      #pragma unroll
      for (int j = 0; j < 4; ++j) arow[j] = __shfl(alpha, (l & 48) | (lh * 4 + j));
      #pragma unroll
      for (int fd = 0; fd < 8; ++fd)
        #pragma unroll
        for (int j = 0; j < 4; ++j) oacc[fd][j] *= arow[j];
      // pack P for PV: pa[ks][b2*4+j] = sf[2ks+b2][j]  (sigma-permuted V makes this exact)
      short8_t pa[2];
      #pragma unroll
      for (int ks = 0; ks < 2; ++ks)
        #pragma unroll
        for (int b2 = 0; b2 < 2; ++b2)
          #pragma unroll
          for (int j = 0; j < 4; ++j) pa[ks][b2 * 4 + j] = (short)f2bf(sf[ks * 2 + b2][j]);
      // PV: O[q][d] += P·V
      #pragma unroll
      for (int fd = 0; fd < 8; ++fd) {
        int dcol = fd * 16 + ln15;
        #pragma unroll
        for (int ks = 0; ks < 2; ++ks) {
          int chunk = ks * 4 + lh;
          short8_t vf = *(const short8_t*)(Vb + dcol * 128 + ((chunk ^ (dcol & 7)) << 4));
          oacc[fd] = __builtin_amdgcn_mfma_f32_16x16x32_bf16(pa[ks], vf, oacc[fd], 0, 0, 0);
        }
      }
    }
    PBARRIER;                        // all waves done reading buf (T&1)
    if (T + 2 < NT) { stageK(T & 1, T + 2); stageV(T & 1, T + 2); }
  }

  // epilogue: O /= l (lrun lives on lane ln15 = q-local), write [b][s][h*128+d]
  float linv[4];
  #pragma unroll
  for (int j = 0; j < 4; ++j) linv[j] = 1.f / __shfl(lrun, (l & 48) | (lh * 4 + j));
  #pragma unroll
  for (int j = 0; j < 4; ++j) {
    int q = qb * 128 + w * 16 + lh * 4 + j;
    u16* op = AO + (size_t)(b * Sc + q) * DIMc + h * Dc + ln15;
    #pragma unroll
    for (int fd = 0; fd < 8; ++fd) op[fd * 16] = f2bf(oacc[fd][j] * linv[j]);
  }
}

extern "C" void kernel_launch(void* const* d_in, const int* in_sizes, int n_in,
                              void* d_out, int out_size, void* d_ws, size_t ws_size,
                              hipStream_t stream) {
  const float* x  = (const float*)d_in[0];
  const float* wq = (const float*)d_in[1];
  const float* wk = (const float*)d_in[2];
  const float* wv = (const float*)d_in[3];
  const float* wo = (const float*)d_in[4];
  float* out = (float*)d_out;

  char* ws = (char*)d_ws;
  size_t off = 0;
  auto alloc = [&](size_t bytes) -> char* {
    char* p = ws + off;
    off += (bytes + 255) & ~(size_t)255;
    return p;
  };
  float* tbl  = (float*)alloc((size_t)Sc * 64 * 2 * 4);
  u16* xb   = (u16*)alloc((size_t)BS * DIMc * 2);      // x bf16; later reused as Qr
  u16* wA   = (u16*)alloc((size_t)4096 * 4096 * 2);    // wqT, later woT
  u16* wkT  = (u16*)alloc((size_t)1024 * 4096 * 2);
  u16* wvT  = (u16*)alloc((size_t)1024 * 4096 * 2);
  u16* Qb   = (u16*)alloc((size_t)BS * 4096 * 2);      // Q proj; later reused as AO
  u16* Kb   = (u16*)alloc((size_t)BS * 1024 * 2);
  u16* Vb   = (u16*)alloc((size_t)BS * 1024 * 2);
  u16* Krp  = (u16*)alloc((size_t)BS * 1024 * 2);
  u16* Vtp  = (u16*)alloc((size_t)BS * 1024 * 2);
  u16* Qr = xb;   // alias: xb dead after V GEMM
  u16* AO = Qb;   // alias: Qb dead after rope(Q)

  rope_table_k<<<(Sc * 64) / 256, 256, 0, stream>>>(tbl);
  f32_to_bf16_k<<<(BS * DIMc / 4) / 256, 256, 0, stream>>>(x, xb, BS * DIMc / 4);

  transpose_w_k<<<dim3(64, 64), 256, 0, stream>>>(wq, wA, 4096, 4096);
  gemm256<0><<<256, 512, 131072, stream>>>(xb, wA, Qb, 4096, 4096, 4096);
  transpose_w_k<<<dim3(16, 64), 256, 0, stream>>>(wk, wkT, 4096, 1024);
  gemm_bt<0><<<dim3(8, 32), 256, 0, stream>>>(xb, wkT, Kb, 4096, 1024, 4096);
  transpose_w_k<<<dim3(16, 64), 256, 0, stream>>>(wv, wvT, 4096, 1024);
  gemm_bt<0><<<dim3(8, 32), 256, 0, stream>>>(xb, wvT, Vb, 4096, 1024, 4096);

  rope_apply_k<<<(Bc * Sc * Hc * 64) / 256, 256, 0, stream>>>(Qb, Qr, tbl, Hc, 5, 0.08838834764831845f);
  rope_apply_k<<<(Bc * Sc * HKVc * 64) / 256, 256, 0, stream>>>(Kb, Krp, tbl, HKVc, 3, 1.0f);
  transpose_v_k<<<dim3(16, HKVc, Bc), 256, 0, stream>>>(Vb, Vtp);

  attn_k<<<dim3(8, Hc, Bc), 512, 65536, stream>>>(Qr, Krp, Vtp, AO);

  transpose_w_k<<<dim3(64, 64), 256, 0, stream>>>(wo, wA, 4096, 4096);
  gemm256<1><<<256, 512, 131072, stream>>>(AO, wA, out, 4096, 4096, 4096);
}

// Round 7
// 593.933 us; speedup vs baseline: 1.3767x; 1.0142x over previous
//
#include <hip/hip_runtime.h>

typedef unsigned short u16;
typedef unsigned int u32;
typedef __attribute__((ext_vector_type(8))) short short8_t;  // 8 bf16 (4 VGPRs)
typedef __attribute__((ext_vector_type(4))) float f32x4;

static constexpr int Bc = 4, Sc = 1024, Hc = 32, HKVc = 8, Dc = 128;
static constexpr int BS = Bc * Sc;     // 4096 rows
static constexpr int DIMc = 4096;

__device__ __forceinline__ u16 f2bf(float f) {
  u32 u = __float_as_uint(f);
  u32 r = (u + 0x7fffu + ((u >> 16) & 1u)) >> 16;  // RNE
  return (u16)r;
}
__device__ __forceinline__ float bf2f(u16 u) {
  return __uint_as_float(((u32)u) << 16);
}
__device__ __forceinline__ void gload_lds16(const void* g, void* l) {
  __builtin_amdgcn_global_load_lds((const __attribute__((address_space(1))) void*)g,
                                   (__attribute__((address_space(3))) void*)l, 16, 0, 0);
}

#define SBAR __builtin_amdgcn_sched_barrier(0)
#define PBARRIER do { SBAR; __builtin_amdgcn_s_barrier(); SBAR; } while (0)
#define WAITVM(N) asm volatile("s_waitcnt vmcnt(" #N ")" ::: "memory")

// ---------------- RoPE table: cos/sin for (s, i) ----------------
__global__ void rope_table_k(float* __restrict__ tbl) {
  int i = blockIdx.x * 256 + threadIdx.x;     // 1024*64
  int s = i >> 6, fi = i & 63;
  float freq = powf(10000.f, -(float)fi / 64.f);
  float ang = (float)s * freq;
  float sv, cv;
  sincosf(ang, &sv, &cv);
  tbl[2 * i] = cv;
  tbl[2 * i + 1] = sv;
}

// ---------------- fp32 -> bf16 convert (vectorized) ----------------
__global__ void f32_to_bf16_k(const float* __restrict__ in, u16* __restrict__ out, int n4) {
  int i = blockIdx.x * 256 + threadIdx.x;
  if (i >= n4) return;
  float4 v = *(const float4*)(in + (size_t)i * 4);
  uint2 pk;
  pk.x = (u32)f2bf(v.x) | ((u32)f2bf(v.y) << 16);
  pk.y = (u32)f2bf(v.z) | ((u32)f2bf(v.w) << 16);
  *(uint2*)(out + (size_t)i * 4) = pk;
}

// ---------------- W (K,N) fp32 -> WT (N,K) bf16, tiled transpose ----------------
__global__ __launch_bounds__(256) void transpose_w_k(const float* __restrict__ W, u16* __restrict__ WT,
                                                     int Kdim, int Ndim) {
  __shared__ float tile[64 * 65];
  const int t = threadIdx.x;
  const int n0 = blockIdx.x * 64, k0 = blockIdx.y * 64;
  #pragma unroll
  for (int p = 0; p < 4; ++p) {
    int idx = p * 256 + t;           // 1024 float4 chunks
    int r = idx >> 4, c = (idx & 15) * 4;
    float4 v = *(const float4*)(W + (size_t)(k0 + r) * Ndim + n0 + c);
    tile[r * 65 + c + 0] = v.x;
    tile[r * 65 + c + 1] = v.y;
    tile[r * 65 + c + 2] = v.z;
    tile[r * 65 + c + 3] = v.w;
  }
  __syncthreads();
  #pragma unroll
  for (int p = 0; p < 2; ++p) {
    int idx = p * 256 + t;           // 512 chunks of 8 bf16
    int n = idx >> 3, c = (idx & 7) * 8;
    alignas(16) u16 o[8];
    #pragma unroll
    for (int i = 0; i < 8; ++i) o[i] = f2bf(tile[(c + i) * 65 + n]);
    *(uint4*)(WT + (size_t)(n0 + n) * Kdim + k0 + c) = *(const uint4*)o;
  }
}

// ---------------- 128^2-tile GEMM (kept for K/V projections) ----------------
template <int OUT_F32>
__global__ __launch_bounds__(256) void gemm_bt(const u16* __restrict__ A, const u16* __restrict__ BT,
                                               void* __restrict__ Cv, int M, int N, int K) {
  __shared__ u16 As[128 * 32];
  __shared__ u16 Bs[128 * 32];
  const int t = threadIdx.x, l = t & 63, w = t >> 6;
  const int bm = blockIdx.y, bn = blockIdx.x;
  const int wr = (w >> 1) * 64, wc = (w & 1) * 64;
  const int ln15 = l & 15, khB = (l >> 4) * 8;
  f32x4 acc[4][4];
  #pragma unroll
  for (int i = 0; i < 4; ++i)
    #pragma unroll
    for (int j = 0; j < 4; ++j) acc[i][j] = f32x4{0.f, 0.f, 0.f, 0.f};
  const int srow = l >> 2, scol = (l & 3) * 8;
  const u16* Ab = A + (size_t)bm * 128 * K;
  const u16* Bb = BT + (size_t)bn * 128 * K;
  for (int k0 = 0; k0 < K; k0 += 32) {
    __syncthreads();
    #pragma unroll
    for (int i = 0; i < 2; ++i) {
      int chunk = w * 2 + i;                 // 8 x 1KB chunks per tile
      int r = chunk * 16 + srow;
      gload_lds16(Ab + (size_t)r * K + k0 + scol, (char*)As + chunk * 1024);
      gload_lds16(Bb + (size_t)r * K + k0 + scol, (char*)Bs + chunk * 1024);
    }
    __syncthreads();
    short8_t af[4], bf[4];
    #pragma unroll
    for (int i = 0; i < 4; ++i) af[i] = *(const short8_t*)&As[(wr + i * 16 + ln15) * 32 + khB];
    #pragma unroll
    for (int j = 0; j < 4; ++j) bf[j] = *(const short8_t*)&Bs[(wc + j * 16 + ln15) * 32 + khB];
    #pragma unroll
    for (int i = 0; i < 4; ++i)
      #pragma unroll
      for (int j = 0; j < 4; ++j)
        acc[i][j] = __builtin_amdgcn_mfma_f32_16x16x32_bf16(af[i], bf[j], acc[i][j], 0, 0, 0);
  }
  const int rbase = bm * 128 + wr + (l >> 4) * 4;
  const int cbase = bn * 128 + wc + ln15;
  #pragma unroll
  for (int i = 0; i < 4; ++i)
    #pragma unroll
    for (int j = 0; j < 4; ++j)
      #pragma unroll
      for (int e = 0; e < 4; ++e) {
        size_t idx = (size_t)(rbase + i * 16 + e) * N + cbase + j * 16;
        if (OUT_F32) ((float*)Cv)[idx] = acc[i][j][e];
        else         ((u16*)Cv)[idx]  = f2bf(acc[i][j][e]);
      }
}

// ---------------- 256^2-tile GEMM, A-resident 4-phase schedule ----------------
// MODE 0: bf16 C row-major; MODE 1: f32 C row-major;
// MODE 2: bf16 + fused RoPE + relayout to Q[b][h][s][d] (scale folded).
// Per tile: p1 reads A0+B0 (12 ds_read_b128), p2 reads A1 (8), p3 reads B1 (4),
// p4 reads none (A0 kept in regs from p1). 24 reads/tile vs 32 before.
// Staging: all 4 halves of tile T+1 into nb, one per phase (order A0,B0,A1,B1).
// Derived waits: vmcnt(4) at end of p1/p2/p4 (last tile: 2/0/none).
#define MFMAQ(QI, AF)                                                                    \
  do {                                                                                   \
    __builtin_amdgcn_s_setprio(1);                                                       \
    _Pragma("unroll") for (int mf = 0; mf < 4; ++mf)                                     \
      _Pragma("unroll") for (int nf = 0; nf < 2; ++nf)                                   \
        _Pragma("unroll") for (int kk = 0; kk < 2; ++kk)                                 \
          acc[QI][mf][nf] = __builtin_amdgcn_mfma_f32_16x16x32_bf16(                     \
              AF[mf][kk], bf[nf][kk], acc[QI][mf][nf], 0, 0, 0);                         \
    __builtin_amdgcn_s_setprio(0);                                                       \
  } while (0)

template <int MODE>
__global__ __launch_bounds__(512, 2) void gemm256(const u16* __restrict__ A, const u16* __restrict__ BT,
                                                  void* __restrict__ Cv, const float* __restrict__ tbl,
                                                  int M, int N, int K) {
  extern __shared__ char smem[];   // 131072 B
  const int t = threadIdx.x, l = t & 63, w = t >> 6;
  const int ln15 = l & 15, lh = l >> 4;
  const int NT = K >> 6;

  int id = blockIdx.x;
  int nwg = gridDim.x;
  int swz = ((nwg & 7) == 0) ? ((id & 7) * (nwg >> 3) + (id >> 3)) : id;
  const int nbn = N >> 8;
  const int bm = swz / nbn, bn = swz % nbn;

  const u16* Ag = A + (size_t)bm * 256 * K;
  const u16* Bg = BT + (size_t)bn * 256 * K;

  f32x4 acc[4][4][2];
  #pragma unroll
  for (int q = 0; q < 4; ++q)
    #pragma unroll
    for (int mf = 0; mf < 4; ++mf)
      #pragma unroll
      for (int nf = 0; nf < 2; ++nf) acc[q][mf][nf] = f32x4{0.f, 0.f, 0.f, 0.f};
  short8_t af0[4][2], af1[4][2], bf[2][2];

  const int srow = (l >> 3);
  const int sck  = (l & 7) ^ srow;
  auto stageA = [&](char* bufbase, int h, int tt) {
    char* lb = bufbase + h * 16384 + w * 1024;
    const u16* g = Ag + (size_t)(h * 128 + w * 8 + srow) * K + tt * 64 + (sck << 3);
    gload_lds16(g, lb);
    gload_lds16(g + (size_t)64 * K, lb + 8192);
  };
  auto stageB = [&](char* bufbase, int h, int tt) {
    char* lb = bufbase + 32768 + h * 16384 + w * 1024;
    const u16* g = Bg + (size_t)(h * 128 + w * 8 + srow) * K + tt * 64 + (sck << 3);
    gload_lds16(g, lb);
    gload_lds16(g + (size_t)64 * K, lb + 8192);
  };
  const int arow = (w >> 2) * 64 + ln15;
  const int brow = (w & 3) * 32 + ln15;
  const int rsw = ln15 & 7;
  auto LDA = [&](const char* cb, int qm, short8_t (&dst)[4][2]) {
    #pragma unroll
    for (int mf = 0; mf < 4; ++mf)
      #pragma unroll
      for (int kk = 0; kk < 2; ++kk)
        dst[mf][kk] = *(const short8_t*)(cb + qm * 16384 + (arow + mf * 16) * 128 +
                                         (((kk * 4 + lh) ^ rsw) << 4));
  };
  auto LDB = [&](const char* cb, int qn) {
    #pragma unroll
    for (int nf = 0; nf < 2; ++nf)
      #pragma unroll
      for (int kk = 0; kk < 2; ++kk)
        bf[nf][kk] = *(const short8_t*)(cb + 32768 + qn * 16384 + (brow + nf * 16) * 128 +
                                        (((kk * 4 + lh) ^ rsw) << 4));
  };

  // ---- prologue: stage tile 0 (issue order A0,B0,A1,B1), retire A0+B0 ----
  stageA(smem, 0, 0);
  stageB(smem, 0, 0);
  stageA(smem, 1, 0);
  stageB(smem, 1, 0);
  WAITVM(4);
  PBARRIER;

  for (int T = 0; T < NT; ++T) {
    char* cb = smem + (T & 1) * 65536;
    char* nb = smem + ((T & 1) ^ 1) * 65536;
    const bool st = (T + 1 < NT);
    // ---- p1: Q00 (reads A0,B0) ----
    LDA(cb, 0, af0); LDB(cb, 0);
    if (st) stageA(nb, 0, T + 1);
    PBARRIER;
    MFMAQ(0, af0);
    if (st) { WAITVM(4); } else { WAITVM(2); }   // retire A1(T)
    PBARRIER;
    // ---- p2: Q10 (reads A1; B0 in regs) ----
    LDA(cb, 1, af1);
    if (st) stageB(nb, 0, T + 1);
    PBARRIER;
    MFMAQ(1, af1);
    if (st) { WAITVM(4); } else { WAITVM(0); }   // retire B1(T)
    PBARRIER;
    // ---- p3: Q11 (reads B1; A1 in regs) ----
    LDB(cb, 1);
    if (st) stageA(nb, 1, T + 1);
    PBARRIER;
    MFMAQ(2, af1);
    PBARRIER;
    // ---- p4: Q01 (no reads; A0 from p1, B1 from p3) ----
    if (st) stageB(nb, 1, T + 1);
    PBARRIER;
    MFMAQ(3, af0);
    if (st) { WAITVM(4); }                       // retire A0,B0(T+1)
    PBARRIER;
  }

  // ---- epilogue ----
  const int rw = (w >> 2) * 64, cw = (w & 3) * 32;
  #pragma unroll
  for (int qi = 0; qi < 4; ++qi) {
    const int qm = (qi == 1 || qi == 2) ? 1 : 0;
    const int qn = (qi >= 2) ? 1 : 0;
    #pragma unroll
    for (int mf = 0; mf < 4; ++mf)
      #pragma unroll
      for (int nf = 0; nf < 2; ++nf)
        #pragma unroll
        for (int e = 0; e < 4; ++e) {
          int row = bm * 256 + qm * 128 + rw + mf * 16 + lh * 4 + e;
          int col = bn * 256 + qn * 128 + cw + nf * 16 + ln15;
          float v = acc[qi][mf][nf][e];
          if (MODE == 2) {
            float pv = __shfl_xor(v, 1);        // partner holds col^1 (same row)
            int d = col & 127, hh = col >> 7;
            int s = row & (Sc - 1), bb = row >> 10;
            float2 cs = *(const float2*)(tbl + (size_t)(s * 64 + (d >> 1)) * 2);
            float o = (d & 1) ? (v * cs.x + pv * cs.y) : (v * cs.x - pv * cs.y);
            o *= 0.08838834764831845f;
            ((u16*)Cv)[(((size_t)(bb * Hc + hh) * Sc + s) << 7) + d] = f2bf(o);
          } else {
            size_t idx = (size_t)row * N + col;
            if (MODE == 1) ((float*)Cv)[idx] = v;
            else           ((u16*)Cv)[idx]  = f2bf(v);
          }
        }
  }
}

// ---------------- RoPE apply + layout change: [b][s][h][d] -> [b][h][s][d] (K only) ----------------
__global__ void rope_apply_k(const u16* __restrict__ In, u16* __restrict__ Out,
                             const float* __restrict__ tbl, int nh, int lognh, float scale) {
  int idx = blockIdx.x * 256 + threadIdx.x;        // one (b,s,h,pair)
  int fi = idx & 63;
  int hs = idx >> 6;
  int h = hs & (nh - 1);
  int rest = hs >> lognh;
  int s = rest & (Sc - 1);
  int b = rest >> 10;
  u32 v = *(const u32*)(In + (size_t)idx * 2);
  float xr = bf2f((u16)(v & 0xffffu));
  float xi = bf2f((u16)(v >> 16));
  float cv = tbl[2 * (s * 64 + fi)];
  float sv = tbl[2 * (s * 64 + fi) + 1];
  float orr = (xr * cv - xi * sv) * scale;
  float oii = (xr * sv + xi * cv) * scale;
  u32 o = (u32)f2bf(orr) | ((u32)f2bf(oii) << 16);
  size_t oidx = ((size_t)(b * nh + h) * Sc + s) * 64 + fi;
  *(u32*)(Out + oidx * 2) = o;
}

// ---------------- V: [b][s][hkv][d] -> VT: [b][hkv][d][sigma(s)] ----------------
__global__ __launch_bounds__(256) void transpose_v_k(const u16* __restrict__ V, u16* __restrict__ VT) {
  __shared__ u16 tile[64 * 136];    // 64 s x 128 d, stride padded to 136
  const int t = threadIdx.x;
  const int s0 = blockIdx.x * 64;
  const int hkv = blockIdx.y, b = blockIdx.z;
  #pragma unroll
  for (int p = 0; p < 4; ++p) {
    int idx = p * 256 + t;             // 1024 chunks of 8 bf16
    int r = idx >> 4, c = (idx & 15) * 8;
    uint4 v = *(const uint4*)(V + (size_t)(b * Sc + s0 + r) * (HKVc * Dc) + hkv * Dc + c);
    *(uint4*)&tile[r * 136 + c] = v;
  }
  __syncthreads();
  #pragma unroll
  for (int p = 0; p < 4; ++p) {
    int idx = p * 256 + t;             // 128 d rows x 8 s-chunks of 8
    int d = idx >> 3, sc = (idx & 7) * 8;
    size_t rowbase = ((size_t)(b * HKVc + hkv) * Dc + d) * Sc + s0;
    #pragma unroll
    for (int h2 = 0; h2 < 2; ++h2) {
      int sl = sc + h2 * 4;            // 4 consecutive source kv (same b2,lh bits)
      int pp = (sl & 32) + ((sl >> 2) & 3) * 8 + ((sl >> 4) & 1) * 4;
      alignas(8) u16 o4[4];
      #pragma unroll
      for (int j = 0; j < 4; ++j) o4[j] = tile[(sl + j) * 136 + d];
      *(uint2*)(VT + rowbase + pp) = *(const uint2*)o4;
    }
  }
}

// ---------------- Flash attention (causal, GQA), swapped-QK^T, P in registers ----------------
__global__ __launch_bounds__(512, 4) void attn_k(const u16* __restrict__ Q, const u16* __restrict__ Kr,
                                                 const u16* __restrict__ Vt, u16* __restrict__ AO) {
  extern __shared__ char smem[];
  const int t = threadIdx.x, l = t & 63, w = t >> 6;
  const int qb = (int)gridDim.x - 1 - (int)blockIdx.x;   // big causal tiles dispatched first
  const int h = blockIdx.y, b = blockIdx.z;
  const int hkv = h >> 2;
  const int ln15 = l & 15, lh = l >> 4;
  const int NT = 2 * qb + 2;

  const u16* Kg0 = Kr + (size_t)(b * HKVc + hkv) * Sc * Dc;
  const u16* Vg0 = Vt + (size_t)(b * HKVc + hkv) * Dc * Sc;

  auto stageK = [&](int buf, int tt) {
    char* base = smem + buf * 16384 + w * 2048;
    #pragma unroll
    for (int i = 0; i < 2; ++i) {
      int row = w * 8 + i * 4 + (l >> 4);
      int c = l & 15;
      gload_lds16(Kg0 + (size_t)(tt * 64 + row) * Dc + ((c ^ (row & 7)) << 3), base + i * 1024);
    }
  };
  auto stageV = [&](int buf, int tt) {
    char* base = smem + 32768 + buf * 16384 + w * 2048;
    #pragma unroll
    for (int i = 0; i < 2; ++i) {
      int d = w * 16 + i * 8 + (l >> 3);
      int c = l & 7;
      gload_lds16(Vg0 + (size_t)d * Sc + tt * 64 + ((c ^ (d & 7)) << 3), base + i * 1024);
    }
  };

  short8_t qf[4];
  {
    int q = qb * 128 + w * 16 + ln15;
    const u16* qp = Q + ((size_t)(b * Hc + h) * Sc + q) * Dc + lh * 8;
    #pragma unroll
    for (int ks = 0; ks < 4; ++ks) qf[ks] = *(const short8_t*)(qp + ks * 32);
  }
  SBAR;   // qf loads issued before staging (vmcnt ordering)

  f32x4 oacc[8];
  #pragma unroll
  for (int i = 0; i < 8; ++i) oacc[i] = f32x4{0.f, 0.f, 0.f, 0.f};
  float mrun = -1e30f, lrun = 0.f;

  stageK(0, 0); stageV(0, 0);
  stageK(1, 1); stageV(1, 1);

  const int qmaxw = qb * 128 + w * 16 + 15;
  const int qlane = qb * 128 + w * 16 + ln15;

  for (int T = 0; T < NT; ++T) {
    if (T < NT - 1) { WAITVM(4); } else { WAITVM(0); }
    PBARRIER;
    const char* Kb = smem + (T & 1) * 16384;
    const char* Vb = smem + 32768 + (T & 1) * 16384;

    if (T * 64 <= qmaxw) {
      f32x4 sf[4];
      #pragma unroll
      for (int fc = 0; fc < 4; ++fc) {
        sf[fc] = f32x4{0.f, 0.f, 0.f, 0.f};
        int kvr = fc * 16 + ln15;
        #pragma unroll
        for (int ks = 0; ks < 4; ++ks) {
          int chunk = ks * 4 + lh;
          short8_t kf = *(const short8_t*)(Kb + kvr * 256 + ((chunk ^ (kvr & 7)) << 4));
          sf[fc] = __builtin_amdgcn_mfma_f32_16x16x32_bf16(kf, qf[ks], sf[fc], 0, 0, 0);
        }
      }
      if (T * 64 + 63 > qb * 128 + w * 16) {
        #pragma unroll
        for (int fc = 0; fc < 4; ++fc)
          #pragma unroll
          for (int j = 0; j < 4; ++j) {
            int kvg = T * 64 + fc * 16 + lh * 4 + j;
            if (kvg > qlane) sf[fc][j] = -1e30f;
          }
      }
      float mx = sf[0][0];
      #pragma unroll
      for (int fc = 0; fc < 4; ++fc)
        #pragma unroll
        for (int j = 0; j < 4; ++j) mx = fmaxf(mx, sf[fc][j]);
      mx = fmaxf(mx, __shfl_xor(mx, 16));
      mx = fmaxf(mx, __shfl_xor(mx, 32));
      float mnew = fmaxf(mrun, mx);
      float alpha = __expf(mrun - mnew);
      mrun = mnew;
      float rs = 0.f;
      #pragma unroll
      for (int fc = 0; fc < 4; ++fc)
        #pragma unroll
        for (int j = 0; j < 4; ++j) {
          float p = __expf(sf[fc][j] - mnew);
          sf[fc][j] = p;
          rs += p;
        }
      rs += __shfl_xor(rs, 16);
      rs += __shfl_xor(rs, 32);
      lrun = lrun * alpha + rs;
      float arow[4];
      #pragma unroll
      for (int j = 0; j < 4; ++j) arow[j] = __shfl(alpha, (l & 48) | (lh * 4 + j));
      #pragma unroll
      for (int fd = 0; fd < 8; ++fd)
        #pragma unroll
        for (int j = 0; j < 4; ++j) oacc[fd][j] *= arow[j];
      short8_t pa[2];
      #pragma unroll
      for (int ks = 0; ks < 2; ++ks)
        #pragma unroll
        for (int b2 = 0; b2 < 2; ++b2)
          #pragma unroll
          for (int j = 0; j < 4; ++j) pa[ks][b2 * 4 + j] = (short)f2bf(sf[ks * 2 + b2][j]);
      #pragma unroll
      for (int fd = 0; fd < 8; ++fd) {
        int dcol = fd * 16 + ln15;
        #pragma unroll
        for (int ks = 0; ks < 2; ++ks) {
          int chunk = ks * 4 + lh;
          short8_t vf = *(const short8_t*)(Vb + dcol * 128 + ((chunk ^ (dcol & 7)) << 4));
          oacc[fd] = __builtin_amdgcn_mfma_f32_16x16x32_bf16(pa[ks], vf, oacc[fd], 0, 0, 0);
        }
      }
    }
    PBARRIER;
    if (T + 2 < NT) { stageK(T & 1, T + 2); stageV(T & 1, T + 2); }
  }

  float linv[4];
  #pragma unroll
  for (int j = 0; j < 4; ++j) linv[j] = 1.f / __shfl(lrun, (l & 48) | (lh * 4 + j));
  #pragma unroll
  for (int j = 0; j < 4; ++j) {
    int q = qb * 128 + w * 16 + lh * 4 + j;
    u16* op = AO + (size_t)(b * Sc + q) * DIMc + h * Dc + ln15;
    #pragma unroll
    for (int fd = 0; fd < 8; ++fd) op[fd * 16] = f2bf(oacc[fd][j] * linv[j]);
  }
}

extern "C" void kernel_launch(void* const* d_in, const int* in_sizes, int n_in,
                              void* d_out, int out_size, void* d_ws, size_t ws_size,
                              hipStream_t stream) {
  const float* x  = (const float*)d_in[0];
  const float* wq = (const float*)d_in[1];
  const float* wk = (const float*)d_in[2];
  const float* wv = (const float*)d_in[3];
  const float* wo = (const float*)d_in[4];
  float* out = (float*)d_out;

  char* ws = (char*)d_ws;
  size_t off = 0;
  auto alloc = [&](size_t bytes) -> char* {
    char* p = ws + off;
    off += (bytes + 255) & ~(size_t)255;
    return p;
  };
  float* tbl  = (float*)alloc((size_t)Sc * 64 * 2 * 4);
  u16* xb   = (u16*)alloc((size_t)BS * DIMc * 2);      // x bf16; later reused as AO
  u16* wA   = (u16*)alloc((size_t)4096 * 4096 * 2);    // wqT, later woT
  u16* wkT  = (u16*)alloc((size_t)1024 * 4096 * 2);
  u16* wvT  = (u16*)alloc((size_t)1024 * 4096 * 2);
  u16* Qb   = (u16*)alloc((size_t)BS * 4096 * 2);      // roped Q in [b][h][s][d]
  u16* Kb   = (u16*)alloc((size_t)BS * 1024 * 2);
  u16* Vb   = (u16*)alloc((size_t)BS * 1024 * 2);
  u16* Krp  = (u16*)alloc((size_t)BS * 1024 * 2);
  u16* Vtp  = (u16*)alloc((size_t)BS * 1024 * 2);
  u16* AO = xb;   // alias: xb dead after V GEMM

  rope_table_k<<<(Sc * 64) / 256, 256, 0, stream>>>(tbl);
  f32_to_bf16_k<<<(BS * DIMc / 4) / 256, 256, 0, stream>>>(x, xb, BS * DIMc / 4);

  transpose_w_k<<<dim3(64, 64), 256, 0, stream>>>(wq, wA, 4096, 4096);
  gemm256<2><<<256, 512, 131072, stream>>>(xb, wA, Qb, tbl, 4096, 4096, 4096);   // Q proj + RoPE + relayout
  transpose_w_k<<<dim3(16, 64), 256, 0, stream>>>(wk, wkT, 4096, 1024);
  gemm_bt<0><<<dim3(8, 32), 256, 0, stream>>>(xb, wkT, Kb, 4096, 1024, 4096);
  transpose_w_k<<<dim3(16, 64), 256, 0, stream>>>(wv, wvT, 4096, 1024);
  gemm_bt<0><<<dim3(8, 32), 256, 0, stream>>>(xb, wvT, Vb, 4096, 1024, 4096);

  rope_apply_k<<<(Bc * Sc * HKVc * 64) / 256, 256, 0, stream>>>(Kb, Krp, tbl, HKVc, 3, 1.0f);
  transpose_v_k<<<dim3(16, HKVc, Bc), 256, 0, stream>>>(Vb, Vtp);

  attn_k<<<dim3(8, Hc, Bc), 512, 65536, stream>>>(Qb, Krp, Vtp, AO);

  transpose_w_k<<<dim3(64, 64), 256, 0, stream>>>(wo, wA, 4096, 4096);
  gemm256<1><<<256, 512, 131072, stream>>>(AO, wA, out, tbl, 4096, 4096, 4096);
}

// Round 8
// 494.921 us; speedup vs baseline: 1.6522x; 1.2001x over previous
//
#include <hip/hip_runtime.h>

typedef unsigned short u16;
typedef unsigned int u32;
typedef __attribute__((ext_vector_type(8))) short short8_t;  // 8 bf16 (4 VGPRs)
typedef __attribute__((ext_vector_type(4))) float f32x4;

static constexpr int Bc = 4, Sc = 1024, Hc = 32, HKVc = 8, Dc = 128;
static constexpr int BS = Bc * Sc;     // 4096 rows
static constexpr int DIMc = 4096;

__device__ __forceinline__ u16 f2bf(float f) {
  u32 u = __float_as_uint(f);
  u32 r = (u + 0x7fffu + ((u >> 16) & 1u)) >> 16;  // RNE
  return (u16)r;
}
__device__ __forceinline__ float bf2f(u16 u) {
  return __uint_as_float(((u32)u) << 16);
}
__device__ __forceinline__ void gload_lds16(const void* g, void* l) {
  __builtin_amdgcn_global_load_lds((const __attribute__((address_space(1))) void*)g,
                                   (__attribute__((address_space(3))) void*)l, 16, 0, 0);
}

#define SBAR __builtin_amdgcn_sched_barrier(0)
#define PBARRIER do { SBAR; __builtin_amdgcn_s_barrier(); SBAR; } while (0)
#define WAITVM(N) asm volatile("s_waitcnt vmcnt(" #N ")" ::: "memory")

// ---------------- RoPE table: cos/sin for (s, i) ----------------
__global__ void rope_table_k(float* __restrict__ tbl) {
  int i = blockIdx.x * 256 + threadIdx.x;     // 1024*64
  int s = i >> 6, fi = i & 63;
  float freq = powf(10000.f, -(float)fi / 64.f);
  float ang = (float)s * freq;
  float sv, cv;
  sincosf(ang, &sv, &cv);
  tbl[2 * i] = cv;
  tbl[2 * i + 1] = sv;
}

// ---------------- fp32 -> bf16 convert (vectorized) ----------------
__global__ void f32_to_bf16_k(const float* __restrict__ in, u16* __restrict__ out, int n4) {
  int i = blockIdx.x * 256 + threadIdx.x;
  if (i >= n4) return;
  float4 v = *(const float4*)(in + (size_t)i * 4);
  uint2 pk;
  pk.x = (u32)f2bf(v.x) | ((u32)f2bf(v.y) << 16);
  pk.y = (u32)f2bf(v.z) | ((u32)f2bf(v.w) << 16);
  *(uint2*)(out + (size_t)i * 4) = pk;
}

// ---------------- W (K,N) fp32 -> WT (N,K) bf16, tiled transpose ----------------
__global__ __launch_bounds__(256) void transpose_w_k(const float* __restrict__ W, u16* __restrict__ WT,
                                                     int Kdim, int Ndim) {
  __shared__ float tile[64 * 65];
  const int t = threadIdx.x;
  const int n0 = blockIdx.x * 64, k0 = blockIdx.y * 64;
  #pragma unroll
  for (int p = 0; p < 4; ++p) {
    int idx = p * 256 + t;           // 1024 float4 chunks
    int r = idx >> 4, c = (idx & 15) * 4;
    float4 v = *(const float4*)(W + (size_t)(k0 + r) * Ndim + n0 + c);
    tile[r * 65 + c + 0] = v.x;
    tile[r * 65 + c + 1] = v.y;
    tile[r * 65 + c + 2] = v.z;
    tile[r * 65 + c + 3] = v.w;
  }
  __syncthreads();
  #pragma unroll
  for (int p = 0; p < 2; ++p) {
    int idx = p * 256 + t;           // 512 chunks of 8 bf16
    int n = idx >> 3, c = (idx & 7) * 8;
    alignas(16) u16 o[8];
    #pragma unroll
    for (int i = 0; i < 8; ++i) o[i] = f2bf(tile[(c + i) * 65 + n]);
    *(uint4*)(WT + (size_t)(n0 + n) * Kdim + k0 + c) = *(const uint4*)o;
  }
}

// ---------------- 256^2-tile 4-phase GEMM (R6 schedule) ----------------
// MODE 1: f32 C row-major; MODE 2: bf16 + fused RoPE + relayout to Q[b][h][s][d].
#define MFMAQ(QI)                                                                        \
  do {                                                                                   \
    __builtin_amdgcn_s_setprio(1);                                                       \
    _Pragma("unroll") for (int mf = 0; mf < 4; ++mf)                                     \
      _Pragma("unroll") for (int nf = 0; nf < 2; ++nf)                                   \
        _Pragma("unroll") for (int kk = 0; kk < 2; ++kk)                                 \
          acc[QI][mf][nf] = __builtin_amdgcn_mfma_f32_16x16x32_bf16(                     \
              af[mf][kk], bf[nf][kk], acc[QI][mf][nf], 0, 0, 0);                         \
    __builtin_amdgcn_s_setprio(0);                                                       \
  } while (0)

template <int MODE>
__global__ __launch_bounds__(512, 2) void gemm256(const u16* __restrict__ A, const u16* __restrict__ BT,
                                                  void* __restrict__ Cv, const float* __restrict__ tbl,
                                                  int M, int N, int K) {
  extern __shared__ char smem[];   // 131072 B
  const int t = threadIdx.x, l = t & 63, w = t >> 6;
  const int ln15 = l & 15, lh = l >> 4;
  const int NT = K >> 6;

  int id = blockIdx.x;
  int nwg = gridDim.x;
  int swz = ((nwg & 7) == 0) ? ((id & 7) * (nwg >> 3) + (id >> 3)) : id;
  const int nbn = N >> 8;
  const int bm = swz / nbn, bn = swz % nbn;

  const u16* Ag = A + (size_t)bm * 256 * K;
  const u16* Bg = BT + (size_t)bn * 256 * K;

  f32x4 acc[4][4][2];
  #pragma unroll
  for (int q = 0; q < 4; ++q)
    #pragma unroll
    for (int mf = 0; mf < 4; ++mf)
      #pragma unroll
      for (int nf = 0; nf < 2; ++nf) acc[q][mf][nf] = f32x4{0.f, 0.f, 0.f, 0.f};
  short8_t af[4][2], bf[2][2];

  const int srow = (l >> 3);
  const int sck  = (l & 7) ^ srow;
  auto stageA = [&](char* bufbase, int h, int tt) {
    char* lb = bufbase + h * 16384 + w * 1024;
    const u16* g = Ag + (size_t)(h * 128 + w * 8 + srow) * K + tt * 64 + (sck << 3);
    gload_lds16(g, lb);
    gload_lds16(g + (size_t)64 * K, lb + 8192);
  };
  auto stageB = [&](char* bufbase, int h, int tt) {
    char* lb = bufbase + 32768 + h * 16384 + w * 1024;
    const u16* g = Bg + (size_t)(h * 128 + w * 8 + srow) * K + tt * 64 + (sck << 3);
    gload_lds16(g, lb);
    gload_lds16(g + (size_t)64 * K, lb + 8192);
  };
  const int arow = (w >> 2) * 64 + ln15;
  const int brow = (w & 3) * 32 + ln15;
  const int rsw = ln15 & 7;
  auto LDA = [&](const char* cb, int qm) {
    #pragma unroll
    for (int mf = 0; mf < 4; ++mf)
      #pragma unroll
      for (int kk = 0; kk < 2; ++kk)
        af[mf][kk] = *(const short8_t*)(cb + qm * 16384 + (arow + mf * 16) * 128 +
                                        (((kk * 4 + lh) ^ rsw) << 4));
  };
  auto LDB = [&](const char* cb, int qn) {
    #pragma unroll
    for (int nf = 0; nf < 2; ++nf)
      #pragma unroll
      for (int kk = 0; kk < 2; ++kk)
        bf[nf][kk] = *(const short8_t*)(cb + 32768 + qn * 16384 + (brow + nf * 16) * 128 +
                                        (((kk * 4 + lh) ^ rsw) << 4));
  };

  {
    char* b0 = smem;
    char* b1 = smem + 65536;
    stageB(b0, 0, 0);   // S1 B0(0)
    stageA(b0, 1, 0);   // S2 A1(0)
    stageA(b0, 0, 0);   // S3 A0(0)
    stageB(b0, 1, 0);   // S4 B1(0)
    stageB(b1, 0, 1);   // S5 B0(1)
    stageA(b1, 1, 1);   // S6 A1(1)
  }
  WAITVM(6);
  PBARRIER;

  for (int T = 0; T < NT - 1; ++T) {
    char* cb = smem + (T & 1) * 65536;
    char* nb = smem + ((T & 1) ^ 1) * 65536;
    LDA(cb, 0); LDB(cb, 0);
    stageA(nb, 0, T + 1);
    PBARRIER;
    MFMAQ(0);
    PBARRIER;
    LDA(cb, 1);
    stageB(nb, 1, T + 1);
    PBARRIER;
    MFMAQ(1);
    WAITVM(8);
    PBARRIER;
    LDB(cb, 1);
    if (T + 2 < NT) stageB(cb, 0, T + 2);
    PBARRIER;
    MFMAQ(2);
    PBARRIER;
    LDA(cb, 0);
    if (T + 2 < NT) stageA(cb, 1, T + 2);
    PBARRIER;
    MFMAQ(3);
    if (T + 2 < NT) { WAITVM(6); }
    else            { WAITVM(2); }
    PBARRIER;
  }
  {
    char* cb = smem + ((NT - 1) & 1) * 65536;
    LDA(cb, 0); LDB(cb, 0);
    PBARRIER; MFMAQ(0); PBARRIER;
    LDA(cb, 1);
    PBARRIER; MFMAQ(1);
    WAITVM(0);
    PBARRIER;
    LDB(cb, 1);
    PBARRIER; MFMAQ(2); PBARRIER;
    LDA(cb, 0);
    PBARRIER; MFMAQ(3);
  }

  // ---- epilogue ----
  const int rw = (w >> 2) * 64, cw = (w & 3) * 32;
  #pragma unroll
  for (int qi = 0; qi < 4; ++qi) {
    const int qm = (qi == 1 || qi == 2) ? 1 : 0;
    const int qn = (qi >= 2) ? 1 : 0;
    #pragma unroll
    for (int mf = 0; mf < 4; ++mf)
      #pragma unroll
      for (int nf = 0; nf < 2; ++nf)
        #pragma unroll
        for (int e = 0; e < 4; ++e) {
          int row = bm * 256 + qm * 128 + rw + mf * 16 + lh * 4 + e;
          int col = bn * 256 + qn * 128 + cw + nf * 16 + ln15;
          float v = acc[qi][mf][nf][e];
          if (MODE == 2) {
            float pv = __shfl_xor(v, 1);        // partner holds col^1 (same row)
            int d = col & 127, hh = col >> 7;
            int s = row & (Sc - 1), bb = row >> 10;
            float2 cs = *(const float2*)(tbl + (size_t)(s * 64 + (d >> 1)) * 2);
            float o = (d & 1) ? (v * cs.x + pv * cs.y) : (v * cs.x - pv * cs.y);
            o *= 0.08838834764831845f;
            ((u16*)Cv)[(((size_t)(bb * Hc + hh) * Sc + s) << 7) + d] = f2bf(o);
          } else {
            size_t idx = (size_t)row * N + col;
            ((float*)Cv)[idx] = v;
          }
        }
  }
}

// ---------------- Fused K+V projection GEMM ----------------
// C[4096, 2048] = xb @ [wkT ; wvT]^T with BM=256, BN=128, BK=64, grid 16x16=256.
// 2 phases/tile (split by A-half, B reg-resident). Epilogue: cols<1024 -> K with
// RoPE into Krp[b][hkv][s][d]; cols>=1024 -> V into Vtp[b][hkv][d][sigma(s)].
#define MFMAKV(QM)                                                                       \
  do {                                                                                   \
    __builtin_amdgcn_s_setprio(1);                                                       \
    _Pragma("unroll") for (int mf = 0; mf < 4; ++mf)                                     \
      _Pragma("unroll") for (int nf = 0; nf < 2; ++nf)                                   \
        _Pragma("unroll") for (int kk = 0; kk < 2; ++kk)                                 \
          acc[QM][mf][nf] = __builtin_amdgcn_mfma_f32_16x16x32_bf16(                     \
              af[mf][kk], bf[nf][kk], acc[QM][mf][nf], 0, 0, 0);                         \
    __builtin_amdgcn_s_setprio(0);                                                       \
  } while (0)

__global__ __launch_bounds__(512, 1) void gemm_kv(const u16* __restrict__ A, const u16* __restrict__ BT,
                                                  u16* __restrict__ Krp, u16* __restrict__ Vtp,
                                                  const float* __restrict__ tbl) {
  extern __shared__ char smem[];   // A dbuf 2x32KB @0 | B dbuf 2x16KB @65536 = 98304 B
  const int t = threadIdx.x, l = t & 63, w = t >> 6;
  const int ln15 = l & 15, lh = l >> 4;
  const int K = 4096, NT = 64;

  int id = blockIdx.x;
  int swz = (id & 7) * 32 + (id >> 3);      // 256 blocks, XCD-bijective
  const int bm = swz >> 4, bn = swz & 15;

  const u16* Ag = A + (size_t)bm * 256 * K;
  const u16* Bg = BT + (size_t)bn * 128 * K;

  f32x4 acc[2][4][2];
  #pragma unroll
  for (int q = 0; q < 2; ++q)
    #pragma unroll
    for (int mf = 0; mf < 4; ++mf)
      #pragma unroll
      for (int nf = 0; nf < 2; ++nf) acc[q][mf][nf] = f32x4{0.f, 0.f, 0.f, 0.f};
  short8_t af[4][2], bf[2][2];

  const int srow = (l >> 3);
  const int sck  = (l & 7) ^ srow;
  auto stageA = [&](int buf, int h, int tt) {   // one A half = 128 rows x 64 K = 16KB
    char* lb = smem + buf * 32768 + h * 16384 + w * 2048;
    const u16* g = Ag + (size_t)(h * 128 + w * 16 + srow) * K + tt * 64 + (sck << 3);
    gload_lds16(g, lb);
    gload_lds16(g + (size_t)8 * K, lb + 1024);
  };
  auto stageB = [&](int buf, int tt) {          // B tile = 128 rows x 64 K = 16KB
    char* lb = smem + 65536 + buf * 16384 + w * 2048;
    const u16* g = Bg + (size_t)(w * 16 + srow) * K + tt * 64 + (sck << 3);
    gload_lds16(g, lb);
    gload_lds16(g + (size_t)8 * K, lb + 1024);
  };
  const int arow = (w >> 2) * 64 + ln15;        // within A half
  const int brow = (w & 3) * 32 + ln15;         // within B tile (128 rows)
  const int rsw = ln15 & 7;
  auto LDA = [&](int buf, int qm) {
    #pragma unroll
    for (int mf = 0; mf < 4; ++mf)
      #pragma unroll
      for (int kk = 0; kk < 2; ++kk)
        af[mf][kk] = *(const short8_t*)(smem + buf * 32768 + qm * 16384 + (arow + mf * 16) * 128 +
                                        (((kk * 4 + lh) ^ rsw) << 4));
  };
  auto LDB = [&](int buf) {
    #pragma unroll
    for (int nf = 0; nf < 2; ++nf)
      #pragma unroll
      for (int kk = 0; kk < 2; ++kk)
        bf[nf][kk] = *(const short8_t*)(smem + 65536 + buf * 16384 + (brow + nf * 16) * 128 +
                                        (((kk * 4 + lh) ^ rsw) << 4));
  };

  // prologue: A0(0), B(0), A1(0) -> retire A0,B (leave A1 in flight)
  stageA(0, 0, 0);
  stageB(0, 0);
  stageA(0, 1, 0);
  WAITVM(2);
  PBARRIER;

  for (int T = 0; T < NT; ++T) {
    const int cb = T & 1, nb = cb ^ 1;
    const bool st = (T + 1 < NT);
    // p1: qm=0 (reads A0 + all B)
    LDA(cb, 0); LDB(cb);
    if (st) stageA(nb, 0, T + 1);
    PBARRIER;
    MFMAKV(0);
    if (st) { WAITVM(2); } else { WAITVM(0); }   // retire A1(T)
    PBARRIER;
    // p2: qm=1 (reads A1; B in regs)
    LDA(cb, 1);
    if (st) { stageB(nb, T + 1); stageA(nb, 1, T + 1); }
    PBARRIER;
    MFMAKV(1);
    if (st) { WAITVM(2); }                       // retire A0(T+1), B(T+1)
    PBARRIER;
  }

  // epilogue
  #pragma unroll
  for (int qm = 0; qm < 2; ++qm)
    #pragma unroll
    for (int mf = 0; mf < 4; ++mf)
      #pragma unroll
      for (int nf = 0; nf < 2; ++nf)
        #pragma unroll
        for (int e = 0; e < 4; ++e) {
          int row = bm * 256 + qm * 128 + (w >> 2) * 64 + mf * 16 + lh * 4 + e;
          int col = bn * 128 + (w & 3) * 32 + nf * 16 + ln15;
          float v = acc[qm][mf][nf][e];
          float pv = __shfl_xor(v, 1);
          int s = row & (Sc - 1), bb = row >> 10;
          if (col < 1024) {          // K + RoPE
            int hkv = col >> 7, d = col & 127;
            float2 cs = *(const float2*)(tbl + (size_t)(s * 64 + (d >> 1)) * 2);
            float o = (d & 1) ? (v * cs.x + pv * cs.y) : (v * cs.x - pv * cs.y);
            Krp[(((size_t)(bb * HKVc + hkv) * Sc + s) << 7) + d] = f2bf(o);
          } else {                   // V, sigma-permuted transpose
            int vc = col - 1024;
            int hkv = vc >> 7, d = vc & 127;
            int sl = s & 63;
            int sg = (sl & 32) | (((sl >> 2) & 3) << 3) | (((sl >> 4) & 1) << 2) | (sl & 3);
            Vtp[((size_t)(bb * HKVc + hkv) * Dc + d) * Sc + (s & ~63) + sg] = f2bf(v);
          }
        }
}

// ---------------- Flash attention (causal, GQA), swapped-QK^T, P in registers ----------------
__global__ __launch_bounds__(512, 4) void attn_k(const u16* __restrict__ Q, const u16* __restrict__ Kr,
                                                 const u16* __restrict__ Vt, u16* __restrict__ AO) {
  extern __shared__ char smem[];
  const int t = threadIdx.x, l = t & 63, w = t >> 6;
  const int qb = (int)gridDim.x - 1 - (int)blockIdx.x;   // big causal tiles dispatched first
  const int h = blockIdx.y, b = blockIdx.z;
  const int hkv = h >> 2;
  const int ln15 = l & 15, lh = l >> 4;
  const int NT = 2 * qb + 2;

  const u16* Kg0 = Kr + (size_t)(b * HKVc + hkv) * Sc * Dc;
  const u16* Vg0 = Vt + (size_t)(b * HKVc + hkv) * Dc * Sc;

  auto stageK = [&](int buf, int tt) {
    char* base = smem + buf * 16384 + w * 2048;
    #pragma unroll
    for (int i = 0; i < 2; ++i) {
      int row = w * 8 + i * 4 + (l >> 4);
      int c = l & 15;
      gload_lds16(Kg0 + (size_t)(tt * 64 + row) * Dc + ((c ^ (row & 7)) << 3), base + i * 1024);
    }
  };
  auto stageV = [&](int buf, int tt) {
    char* base = smem + 32768 + buf * 16384 + w * 2048;
    #pragma unroll
    for (int i = 0; i < 2; ++i) {
      int d = w * 16 + i * 8 + (l >> 3);
      int c = l & 7;
      gload_lds16(Vg0 + (size_t)d * Sc + tt * 64 + ((c ^ (d & 7)) << 3), base + i * 1024);
    }
  };

  short8_t qf[4];
  {
    int q = qb * 128 + w * 16 + ln15;
    const u16* qp = Q + ((size_t)(b * Hc + h) * Sc + q) * Dc + lh * 8;
    #pragma unroll
    for (int ks = 0; ks < 4; ++ks) qf[ks] = *(const short8_t*)(qp + ks * 32);
  }
  SBAR;   // qf loads issued before staging (vmcnt ordering)

  f32x4 oacc[8];
  #pragma unroll
  for (int i = 0; i < 8; ++i) oacc[i] = f32x4{0.f, 0.f, 0.f, 0.f};
  float mrun = -1e30f, lrun = 0.f;

  stageK(0, 0); stageV(0, 0);
  stageK(1, 1); stageV(1, 1);

  const int qmaxw = qb * 128 + w * 16 + 15;
  const int qlane = qb * 128 + w * 16 + ln15;

  for (int T = 0; T < NT; ++T) {
    if (T < NT - 1) { WAITVM(4); } else { WAITVM(0); }
    PBARRIER;
    const char* Kb = smem + (T & 1) * 16384;
    const char* Vb = smem + 32768 + (T & 1) * 16384;

    if (T * 64 <= qmaxw) {
      f32x4 sf[4];
      #pragma unroll
      for (int fc = 0; fc < 4; ++fc) {
        sf[fc] = f32x4{0.f, 0.f, 0.f, 0.f};
        int kvr = fc * 16 + ln15;
        #pragma unroll
        for (int ks = 0; ks < 4; ++ks) {
          int chunk = ks * 4 + lh;
          short8_t kf = *(const short8_t*)(Kb + kvr * 256 + ((chunk ^ (kvr & 7)) << 4));
          sf[fc] = __builtin_amdgcn_mfma_f32_16x16x32_bf16(kf, qf[ks], sf[fc], 0, 0, 0);
        }
      }
      if (T * 64 + 63 > qb * 128 + w * 16) {
        #pragma unroll
        for (int fc = 0; fc < 4; ++fc)
          #pragma unroll
          for (int j = 0; j < 4; ++j) {
            int kvg = T * 64 + fc * 16 + lh * 4 + j;
            if (kvg > qlane) sf[fc][j] = -1e30f;
          }
      }
      float mx = sf[0][0];
      #pragma unroll
      for (int fc = 0; fc < 4; ++fc)
        #pragma unroll
        for (int j = 0; j < 4; ++j) mx = fmaxf(mx, sf[fc][j]);
      mx = fmaxf(mx, __shfl_xor(mx, 16));
      mx = fmaxf(mx, __shfl_xor(mx, 32));
      float mnew = fmaxf(mrun, mx);
      float alpha = __expf(mrun - mnew);
      mrun = mnew;
      float rs = 0.f;
      #pragma unroll
      for (int fc = 0; fc < 4; ++fc)
        #pragma unroll
        for (int j = 0; j < 4; ++j) {
          float p = __expf(sf[fc][j] - mnew);
          sf[fc][j] = p;
          rs += p;
        }
      rs += __shfl_xor(rs, 16);
      rs += __shfl_xor(rs, 32);
      lrun = lrun * alpha + rs;
      float arow[4];
      #pragma unroll
      for (int j = 0; j < 4; ++j) arow[j] = __shfl(alpha, (l & 48) | (lh * 4 + j));
      #pragma unroll
      for (int fd = 0; fd < 8; ++fd)
        #pragma unroll
        for (int j = 0; j < 4; ++j) oacc[fd][j] *= arow[j];
      short8_t pa[2];
      #pragma unroll
      for (int ks = 0; ks < 2; ++ks)
        #pragma unroll
        for (int b2 = 0; b2 < 2; ++b2)
          #pragma unroll
          for (int j = 0; j < 4; ++j) pa[ks][b2 * 4 + j] = (short)f2bf(sf[ks * 2 + b2][j]);
      #pragma unroll
      for (int fd = 0; fd < 8; ++fd) {
        int dcol = fd * 16 + ln15;
        #pragma unroll
        for (int ks = 0; ks < 2; ++ks) {
          int chunk = ks * 4 + lh;
          short8_t vf = *(const short8_t*)(Vb + dcol * 128 + ((chunk ^ (dcol & 7)) << 4));
          oacc[fd] = __builtin_amdgcn_mfma_f32_16x16x32_bf16(pa[ks], vf, oacc[fd], 0, 0, 0);
        }
      }
    }
    PBARRIER;
    if (T + 2 < NT) { stageK(T & 1, T + 2); stageV(T & 1, T + 2); }
  }

  float linv[4];
  #pragma unroll
  for (int j = 0; j < 4; ++j) linv[j] = 1.f / __shfl(lrun, (l & 48) | (lh * 4 + j));
  #pragma unroll
  for (int j = 0; j < 4; ++j) {
    int q = qb * 128 + w * 16 + lh * 4 + j;
    u16* op = AO + (size_t)(b * Sc + q) * DIMc + h * Dc + ln15;
    #pragma unroll
    for (int fd = 0; fd < 8; ++fd) op[fd * 16] = f2bf(oacc[fd][j] * linv[j]);
  }
}

extern "C" void kernel_launch(void* const* d_in, const int* in_sizes, int n_in,
                              void* d_out, int out_size, void* d_ws, size_t ws_size,
                              hipStream_t stream) {
  const float* x  = (const float*)d_in[0];
  const float* wq = (const float*)d_in[1];
  const float* wk = (const float*)d_in[2];
  const float* wv = (const float*)d_in[3];
  const float* wo = (const float*)d_in[4];
  float* out = (float*)d_out;

  char* ws = (char*)d_ws;
  size_t off = 0;
  auto alloc = [&](size_t bytes) -> char* {
    char* p = ws + off;
    off += (bytes + 255) & ~(size_t)255;
    return p;
  };
  float* tbl  = (float*)alloc((size_t)Sc * 64 * 2 * 4);
  u16* xb    = (u16*)alloc((size_t)BS * DIMc * 2);     // x bf16; later reused as AO
  u16* wqT   = (u16*)alloc((size_t)4096 * 4096 * 2);   // wqT; later woT
  u16* wkvT  = (u16*)alloc((size_t)2048 * 4096 * 2);   // [wkT ; wvT]
  u16* Qb    = (u16*)alloc((size_t)BS * 4096 * 2);     // roped Q in [b][h][s][d]
  u16* Krp   = (u16*)alloc((size_t)BS * 1024 * 2);     // roped K in [b][hkv][s][d]
  u16* Vtp   = (u16*)alloc((size_t)BS * 1024 * 2);     // V in [b][hkv][d][sigma(s)]
  u16* AO = xb;    // alias: xb dead after K/V GEMM
  u16* woT = wqT;  // alias: wqT dead after Q GEMM

  rope_table_k<<<(Sc * 64) / 256, 256, 0, stream>>>(tbl);
  f32_to_bf16_k<<<(BS * DIMc / 4) / 256, 256, 0, stream>>>(x, xb, BS * DIMc / 4);

  transpose_w_k<<<dim3(64, 64), 256, 0, stream>>>(wq, wqT, 4096, 4096);
  gemm256<2><<<256, 512, 131072, stream>>>(xb, wqT, Qb, tbl, 4096, 4096, 4096);  // Q + RoPE + relayout

  transpose_w_k<<<dim3(16, 64), 256, 0, stream>>>(wk, wkvT, 4096, 1024);
  transpose_w_k<<<dim3(16, 64), 256, 0, stream>>>(wv, wkvT + (size_t)1024 * 4096, 4096, 1024);
  gemm_kv<<<256, 512, 98304, stream>>>(xb, wkvT, Krp, Vtp, tbl);                 // K+RoPE, V+sigma-transpose

  attn_k<<<dim3(8, Hc, Bc), 512, 65536, stream>>>(Qb, Krp, Vtp, AO);

  transpose_w_k<<<dim3(64, 64), 256, 0, stream>>>(wo, woT, 4096, 4096);
  gemm256<1><<<256, 512, 131072, stream>>>(AO, woT, out, tbl, 4096, 4096, 4096);
}

// Round 9
// 487.137 us; speedup vs baseline: 1.6786x; 1.0160x over previous
//
#include <hip/hip_runtime.h>

typedef unsigned short u16;
typedef unsigned int u32;
typedef __attribute__((ext_vector_type(8))) short short8_t;  // 8 bf16 (4 VGPRs)
typedef __attribute__((ext_vector_type(4))) float f32x4;

static constexpr int Bc = 4, Sc = 1024, Hc = 32, HKVc = 8, Dc = 128;
static constexpr int BS = Bc * Sc;     // 4096 rows
static constexpr int DIMc = 4096;

__device__ __forceinline__ u16 f2bf(float f) {
  u32 u = __float_as_uint(f);
  u32 r = (u + 0x7fffu + ((u >> 16) & 1u)) >> 16;  // RNE
  return (u16)r;
}
__device__ __forceinline__ float bf2f(u16 u) {
  return __uint_as_float(((u32)u) << 16);
}
__device__ __forceinline__ void gload_lds16(const void* g, void* l) {
  __builtin_amdgcn_global_load_lds((const __attribute__((address_space(1))) void*)g,
                                   (__attribute__((address_space(3))) void*)l, 16, 0, 0);
}

#define SBAR __builtin_amdgcn_sched_barrier(0)
#define PBARRIER do { SBAR; __builtin_amdgcn_s_barrier(); SBAR; } while (0)
#define WAITVM(N) asm volatile("s_waitcnt vmcnt(" #N ")" ::: "memory")

// ---------------- RoPE table: cos/sin for (s, i) ----------------
__global__ void rope_table_k(float* __restrict__ tbl) {
  int i = blockIdx.x * 256 + threadIdx.x;     // 1024*64
  int s = i >> 6, fi = i & 63;
  float freq = powf(10000.f, -(float)fi / 64.f);
  float ang = (float)s * freq;
  float sv, cv;
  sincosf(ang, &sv, &cv);
  tbl[2 * i] = cv;
  tbl[2 * i + 1] = sv;
}

// ---------------- fp32 -> bf16 convert (vectorized) ----------------
__global__ void f32_to_bf16_k(const float* __restrict__ in, u16* __restrict__ out, int n4) {
  int i = blockIdx.x * 256 + threadIdx.x;
  if (i >= n4) return;
  float4 v = *(const float4*)(in + (size_t)i * 4);
  uint2 pk;
  pk.x = (u32)f2bf(v.x) | ((u32)f2bf(v.y) << 16);
  pk.y = (u32)f2bf(v.z) | ((u32)f2bf(v.w) << 16);
  *(uint2*)(out + (size_t)i * 4) = pk;
}

// ---------------- W (K,N) fp32 -> WT (N,K) bf16, tiled transpose ----------------
__global__ __launch_bounds__(256) void transpose_w_k(const float* __restrict__ W, u16* __restrict__ WT,
                                                     int Kdim, int Ndim) {
  __shared__ float tile[64 * 65];
  const int t = threadIdx.x;
  const int n0 = blockIdx.x * 64, k0 = blockIdx.y * 64;
  #pragma unroll
  for (int p = 0; p < 4; ++p) {
    int idx = p * 256 + t;           // 1024 float4 chunks
    int r = idx >> 4, c = (idx & 15) * 4;
    float4 v = *(const float4*)(W + (size_t)(k0 + r) * Ndim + n0 + c);
    tile[r * 65 + c + 0] = v.x;
    tile[r * 65 + c + 1] = v.y;
    tile[r * 65 + c + 2] = v.z;
    tile[r * 65 + c + 3] = v.w;
  }
  __syncthreads();
  #pragma unroll
  for (int p = 0; p < 2; ++p) {
    int idx = p * 256 + t;           // 512 chunks of 8 bf16
    int n = idx >> 3, c = (idx & 7) * 8;
    alignas(16) u16 o[8];
    #pragma unroll
    for (int i = 0; i < 8; ++i) o[i] = f2bf(tile[(c + i) * 65 + n]);
    *(uint4*)(WT + (size_t)(n0 + n) * Kdim + k0 + c) = *(const uint4*)o;
  }
}

// ---------------- 256^2-tile GEMM, 4-phase / 4-barrier schedule ----------------
// MODE 1: f32 C row-major; MODE 2: bf16 + fused RoPE + relayout to Q[b][h][s][d].
// Per phase: {ds_read frags; issue 1 half-tile stage; MFMA quadrant; barrier}.
// No pre-MFMA barrier: tile-T reads were validated by tile-(T-1)'s vmcnt+barrier;
// stage WAR holds because each stage targets the region whose last read was the
// PREVIOUS phase (p1:A0(T+1)->nb; p2:B0(T+2); p3:A1(T+2); p4:B1(T+2), into cb).
// Single vmcnt(6) per tile (pre-p4-barrier) retires all of tile T+1.
#define MFMAQ(QI)                                                                        \
  do {                                                                                   \
    __builtin_amdgcn_s_setprio(1);                                                       \
    _Pragma("unroll") for (int mf = 0; mf < 4; ++mf)                                     \
      _Pragma("unroll") for (int nf = 0; nf < 2; ++nf)                                   \
        _Pragma("unroll") for (int kk = 0; kk < 2; ++kk)                                 \
          acc[QI][mf][nf] = __builtin_amdgcn_mfma_f32_16x16x32_bf16(                     \
              af[mf][kk], bf[nf][kk], acc[QI][mf][nf], 0, 0, 0);                         \
    __builtin_amdgcn_s_setprio(0);                                                       \
  } while (0)

template <int MODE>
__global__ __launch_bounds__(512, 2) void gemm256(const u16* __restrict__ A, const u16* __restrict__ BT,
                                                  void* __restrict__ Cv, const float* __restrict__ tbl,
                                                  int M, int N, int K) {
  extern __shared__ char smem[];   // 131072 B
  const int t = threadIdx.x, l = t & 63, w = t >> 6;
  const int ln15 = l & 15, lh = l >> 4;
  const int NT = K >> 6;

  int id = blockIdx.x;
  int nwg = gridDim.x;
  int swz = ((nwg & 7) == 0) ? ((id & 7) * (nwg >> 3) + (id >> 3)) : id;
  const int nbn = N >> 8;
  const int bm = swz / nbn, bn = swz % nbn;

  const u16* Ag = A + (size_t)bm * 256 * K;
  const u16* Bg = BT + (size_t)bn * 256 * K;

  f32x4 acc[4][4][2];
  #pragma unroll
  for (int q = 0; q < 4; ++q)
    #pragma unroll
    for (int mf = 0; mf < 4; ++mf)
      #pragma unroll
      for (int nf = 0; nf < 2; ++nf) acc[q][mf][nf] = f32x4{0.f, 0.f, 0.f, 0.f};
  short8_t af[4][2], bf[2][2];

  const int srow = (l >> 3);
  const int sck  = (l & 7) ^ srow;
  auto stageA = [&](char* bufbase, int h, int tt) {
    char* lb = bufbase + h * 16384 + w * 1024;
    const u16* g = Ag + (size_t)(h * 128 + w * 8 + srow) * K + tt * 64 + (sck << 3);
    gload_lds16(g, lb);
    gload_lds16(g + (size_t)64 * K, lb + 8192);
  };
  auto stageB = [&](char* bufbase, int h, int tt) {
    char* lb = bufbase + 32768 + h * 16384 + w * 1024;
    const u16* g = Bg + (size_t)(h * 128 + w * 8 + srow) * K + tt * 64 + (sck << 3);
    gload_lds16(g, lb);
    gload_lds16(g + (size_t)64 * K, lb + 8192);
  };
  const int arow = (w >> 2) * 64 + ln15;
  const int brow = (w & 3) * 32 + ln15;
  const int rsw = ln15 & 7;
  auto LDA = [&](const char* cb, int qm) {
    #pragma unroll
    for (int mf = 0; mf < 4; ++mf)
      #pragma unroll
      for (int kk = 0; kk < 2; ++kk)
        af[mf][kk] = *(const short8_t*)(cb + qm * 16384 + (arow + mf * 16) * 128 +
                                        (((kk * 4 + lh) ^ rsw) << 4));
  };
  auto LDB = [&](const char* cb, int qn) {
    #pragma unroll
    for (int nf = 0; nf < 2; ++nf)
      #pragma unroll
      for (int kk = 0; kk < 2; ++kk)
        bf[nf][kk] = *(const short8_t*)(cb + 32768 + qn * 16384 + (brow + nf * 16) * 128 +
                                        (((kk * 4 + lh) ^ rsw) << 4));
  };

  // ---- prologue: tile0 fully + 3 of tile1's halves; retire tile0 ----
  {
    char* b0 = smem;
    char* b1 = smem + 65536;
    stageB(b0, 0, 0);   // B0(0)
    stageA(b0, 1, 0);   // A1(0)
    stageA(b0, 0, 0);   // A0(0)
    stageB(b0, 1, 0);   // B1(0)
    stageB(b1, 0, 1);   // B0(1)
    stageA(b1, 1, 1);   // A1(1)
    stageB(b1, 1, 1);   // B1(1)
  }
  WAITVM(6);    // retire the 4 tile-0 halves; tile-1's 3 remain in flight
  PBARRIER;

  for (int T = 0; T < NT; ++T) {
    char* cb = smem + (T & 1) * 65536;
    char* nb = smem + ((T & 1) ^ 1) * 65536;
    const bool s1 = (T + 1 < NT), s2 = (T + 2 < NT);
    // p1: Q00 (reads A0,B0); stage A0(T+1) -> nb (A0(T-1) dead since p4(T-1))
    LDA(cb, 0); LDB(cb, 0);
    if (s1) stageA(nb, 0, T + 1);
    MFMAQ(0);
    PBARRIER;
    // p2: Q10 (reads A1; B0 in regs); stage B0(T+2) -> cb (B0(T) last read p1)
    LDA(cb, 1);
    if (s2) stageB(cb, 0, T + 2);
    MFMAQ(1);
    PBARRIER;
    // p3: Q11 (reads B1; A1 in regs); stage A1(T+2) -> cb (A1(T) last read p2)
    LDB(cb, 1);
    if (s2) stageA(cb, 1, T + 2);
    MFMAQ(2);
    PBARRIER;
    // p4: Q01 (re-reads A0; B1 in regs); stage B1(T+2) -> cb (B1(T) last read p3)
    LDA(cb, 0);
    if (s2) stageB(cb, 1, T + 2);
    MFMAQ(3);
    if (s2)      { WAITVM(6); }   // keep only the 3 T+2 halves in flight
    else if (s1) { WAITVM(0); }   // drain before the final tile
    PBARRIER;
  }

  // ---- epilogue ----
  const int rw = (w >> 2) * 64, cw = (w & 3) * 32;
  #pragma unroll
  for (int qi = 0; qi < 4; ++qi) {
    const int qm = (qi == 1 || qi == 2) ? 1 : 0;
    const int qn = (qi >= 2) ? 1 : 0;
    #pragma unroll
    for (int mf = 0; mf < 4; ++mf)
      #pragma unroll
      for (int nf = 0; nf < 2; ++nf)
        #pragma unroll
        for (int e = 0; e < 4; ++e) {
          int row = bm * 256 + qm * 128 + rw + mf * 16 + lh * 4 + e;
          int col = bn * 256 + qn * 128 + cw + nf * 16 + ln15;
          float v = acc[qi][mf][nf][e];
          if (MODE == 2) {
            float pv = __shfl_xor(v, 1);        // partner holds col^1 (same row)
            int d = col & 127, hh = col >> 7;
            int s = row & (Sc - 1), bb = row >> 10;
            float2 cs = *(const float2*)(tbl + (size_t)(s * 64 + (d >> 1)) * 2);
            float o = (d & 1) ? (v * cs.x + pv * cs.y) : (v * cs.x - pv * cs.y);
            o *= 0.08838834764831845f;
            ((u16*)Cv)[(((size_t)(bb * Hc + hh) * Sc + s) << 7) + d] = f2bf(o);
          } else {
            size_t idx = (size_t)row * N + col;
            ((float*)Cv)[idx] = v;
          }
        }
  }
}

// ---------------- Fused K+V projection GEMM (2-phase / 2-barrier) ----------------
#define MFMAKV(QM)                                                                       \
  do {                                                                                   \
    __builtin_amdgcn_s_setprio(1);                                                       \
    _Pragma("unroll") for (int mf = 0; mf < 4; ++mf)                                     \
      _Pragma("unroll") for (int nf = 0; nf < 2; ++nf)                                   \
        _Pragma("unroll") for (int kk = 0; kk < 2; ++kk)                                 \
          acc[QM][mf][nf] = __builtin_amdgcn_mfma_f32_16x16x32_bf16(                     \
              af[mf][kk], bf[nf][kk], acc[QM][mf][nf], 0, 0, 0);                         \
    __builtin_amdgcn_s_setprio(0);                                                       \
  } while (0)

__global__ __launch_bounds__(512, 1) void gemm_kv(const u16* __restrict__ A, const u16* __restrict__ BT,
                                                  u16* __restrict__ Krp, u16* __restrict__ Vtp,
                                                  const float* __restrict__ tbl) {
  extern __shared__ char smem[];   // A dbuf 2x32KB @0 | B dbuf 2x16KB @65536 = 98304 B
  const int t = threadIdx.x, l = t & 63, w = t >> 6;
  const int ln15 = l & 15, lh = l >> 4;
  const int K = 4096, NT = 64;

  int id = blockIdx.x;
  int swz = (id & 7) * 32 + (id >> 3);      // 256 blocks, XCD-bijective
  const int bm = swz >> 4, bn = swz & 15;

  const u16* Ag = A + (size_t)bm * 256 * K;
  const u16* Bg = BT + (size_t)bn * 128 * K;

  f32x4 acc[2][4][2];
  #pragma unroll
  for (int q = 0; q < 2; ++q)
    #pragma unroll
    for (int mf = 0; mf < 4; ++mf)
      #pragma unroll
      for (int nf = 0; nf < 2; ++nf) acc[q][mf][nf] = f32x4{0.f, 0.f, 0.f, 0.f};
  short8_t af[4][2], bf[2][2];

  const int srow = (l >> 3);
  const int sck  = (l & 7) ^ srow;
  auto stageA = [&](int buf, int h, int tt) {   // one A half = 128 rows x 64 K = 16KB
    char* lb = smem + buf * 32768 + h * 16384 + w * 2048;
    const u16* g = Ag + (size_t)(h * 128 + w * 16 + srow) * K + tt * 64 + (sck << 3);
    gload_lds16(g, lb);
    gload_lds16(g + (size_t)8 * K, lb + 1024);
  };
  auto stageB = [&](int buf, int tt) {          // B tile = 128 rows x 64 K = 16KB
    char* lb = smem + 65536 + buf * 16384 + w * 2048;
    const u16* g = Bg + (size_t)(w * 16 + srow) * K + tt * 64 + (sck << 3);
    gload_lds16(g, lb);
    gload_lds16(g + (size_t)8 * K, lb + 1024);
  };
  const int arow = (w >> 2) * 64 + ln15;        // within A half
  const int brow = (w & 3) * 32 + ln15;         // within B tile (128 rows)
  const int rsw = ln15 & 7;
  auto LDA = [&](int buf, int qm) {
    #pragma unroll
    for (int mf = 0; mf < 4; ++mf)
      #pragma unroll
      for (int kk = 0; kk < 2; ++kk)
        af[mf][kk] = *(const short8_t*)(smem + buf * 32768 + qm * 16384 + (arow + mf * 16) * 128 +
                                        (((kk * 4 + lh) ^ rsw) << 4));
  };
  auto LDB = [&](int buf) {
    #pragma unroll
    for (int nf = 0; nf < 2; ++nf)
      #pragma unroll
      for (int kk = 0; kk < 2; ++kk)
        bf[nf][kk] = *(const short8_t*)(smem + 65536 + buf * 16384 + (brow + nf * 16) * 128 +
                                        (((kk * 4 + lh) ^ rsw) << 4));
  };

  // prologue: A0(0), B(0), A1(0) -> retire A0,B (leave A1 in flight)
  stageA(0, 0, 0);
  stageB(0, 0);
  stageA(0, 1, 0);
  WAITVM(2);
  PBARRIER;

  for (int T = 0; T < NT; ++T) {
    const int cb = T & 1, nb = cb ^ 1;
    const bool st = (T + 1 < NT);
    // p1: qm=0 (reads A0 + all B); stage A0(T+1) -> nb
    LDA(cb, 0); LDB(cb);
    if (st) stageA(nb, 0, T + 1);
    MFMAKV(0);
    if (st) { WAITVM(2); } else { WAITVM(0); }   // retire A1(T)
    PBARRIER;
    // p2: qm=1 (reads A1; B in regs); stage B(T+1), A1(T+1) -> nb
    LDA(cb, 1);
    if (st) { stageB(nb, T + 1); stageA(nb, 1, T + 1); }
    MFMAKV(1);
    if (st) { WAITVM(2); }                       // retire A0(T+1), B(T+1)
    PBARRIER;
  }

  // epilogue
  #pragma unroll
  for (int qm = 0; qm < 2; ++qm)
    #pragma unroll
    for (int mf = 0; mf < 4; ++mf)
      #pragma unroll
      for (int nf = 0; nf < 2; ++nf)
        #pragma unroll
        for (int e = 0; e < 4; ++e) {
          int row = bm * 256 + qm * 128 + (w >> 2) * 64 + mf * 16 + lh * 4 + e;
          int col = bn * 128 + (w & 3) * 32 + nf * 16 + ln15;
          float v = acc[qm][mf][nf][e];
          float pv = __shfl_xor(v, 1);
          int s = row & (Sc - 1), bb = row >> 10;
          if (col < 1024) {          // K + RoPE
            int hkv = col >> 7, d = col & 127;
            float2 cs = *(const float2*)(tbl + (size_t)(s * 64 + (d >> 1)) * 2);
            float o = (d & 1) ? (v * cs.x + pv * cs.y) : (v * cs.x - pv * cs.y);
            Krp[(((size_t)(bb * HKVc + hkv) * Sc + s) << 7) + d] = f2bf(o);
          } else {                   // V, sigma-permuted transpose
            int vc = col - 1024;
            int hkv = vc >> 7, d = vc & 127;
            int sl = s & 63;
            int sg = (sl & 32) | (((sl >> 2) & 3) << 3) | (((sl >> 4) & 1) << 2) | (sl & 3);
            Vtp[((size_t)(bb * HKVc + hkv) * Dc + d) * Sc + (s & ~63) + sg] = f2bf(v);
          }
        }
}

// ---------------- Flash attention (causal, GQA), swapped-QK^T, P in registers ----------------
__global__ __launch_bounds__(512, 4) void attn_k(const u16* __restrict__ Q, const u16* __restrict__ Kr,
                                                 const u16* __restrict__ Vt, u16* __restrict__ AO) {
  extern __shared__ char smem[];
  const int t = threadIdx.x, l = t & 63, w = t >> 6;
  const int qb = (int)gridDim.x - 1 - (int)blockIdx.x;   // big causal tiles dispatched first
  const int h = blockIdx.y, b = blockIdx.z;
  const int hkv = h >> 2;
  const int ln15 = l & 15, lh = l >> 4;
  const int NT = 2 * qb + 2;

  const u16* Kg0 = Kr + (size_t)(b * HKVc + hkv) * Sc * Dc;
  const u16* Vg0 = Vt + (size_t)(b * HKVc + hkv) * Dc * Sc;

  auto stageK = [&](int buf, int tt) {
    char* base = smem + buf * 16384 + w * 2048;
    #pragma unroll
    for (int i = 0; i < 2; ++i) {
      int row = w * 8 + i * 4 + (l >> 4);
      int c = l & 15;
      gload_lds16(Kg0 + (size_t)(tt * 64 + row) * Dc + ((c ^ (row & 7)) << 3), base + i * 1024);
    }
  };
  auto stageV = [&](int buf, int tt) {
    char* base = smem + 32768 + buf * 16384 + w * 2048;
    #pragma unroll
    for (int i = 0; i < 2; ++i) {
      int d = w * 16 + i * 8 + (l >> 3);
      int c = l & 7;
      gload_lds16(Vg0 + (size_t)d * Sc + tt * 64 + ((c ^ (d & 7)) << 3), base + i * 1024);
    }
  };

  short8_t qf[4];
  {
    int q = qb * 128 + w * 16 + ln15;
    const u16* qp = Q + ((size_t)(b * Hc + h) * Sc + q) * Dc + lh * 8;
    #pragma unroll
    for (int ks = 0; ks < 4; ++ks) qf[ks] = *(const short8_t*)(qp + ks * 32);
  }
  SBAR;   // qf loads issued before staging (vmcnt ordering)

  f32x4 oacc[8];
  #pragma unroll
  for (int i = 0; i < 8; ++i) oacc[i] = f32x4{0.f, 0.f, 0.f, 0.f};
  float mrun = -1e30f, lrun = 0.f;

  stageK(0, 0); stageV(0, 0);
  stageK(1, 1); stageV(1, 1);

  const int qmaxw = qb * 128 + w * 16 + 15;
  const int qlane = qb * 128 + w * 16 + ln15;

  for (int T = 0; T < NT; ++T) {
    if (T < NT - 1) { WAITVM(4); } else { WAITVM(0); }
    PBARRIER;
    const char* Kb = smem + (T & 1) * 16384;
    const char* Vb = smem + 32768 + (T & 1) * 16384;

    if (T * 64 <= qmaxw) {
      f32x4 sf[4];
      #pragma unroll
      for (int fc = 0; fc < 4; ++fc) {
        sf[fc] = f32x4{0.f, 0.f, 0.f, 0.f};
        int kvr = fc * 16 + ln15;
        #pragma unroll
        for (int ks = 0; ks < 4; ++ks) {
          int chunk = ks * 4 + lh;
          short8_t kf = *(const short8_t*)(Kb + kvr * 256 + ((chunk ^ (kvr & 7)) << 4));
          sf[fc] = __builtin_amdgcn_mfma_f32_16x16x32_bf16(kf, qf[ks], sf[fc], 0, 0, 0);
        }
      }
      if (T * 64 + 63 > qb * 128 + w * 16) {
        #pragma unroll
        for (int fc = 0; fc < 4; ++fc)
          #pragma unroll
          for (int j = 0; j < 4; ++j) {
            int kvg = T * 64 + fc * 16 + lh * 4 + j;
            if (kvg > qlane) sf[fc][j] = -1e30f;
          }
      }
      float mx = sf[0][0];
      #pragma unroll
      for (int fc = 0; fc < 4; ++fc)
        #pragma unroll
        for (int j = 0; j < 4; ++j) mx = fmaxf(mx, sf[fc][j]);
      mx = fmaxf(mx, __shfl_xor(mx, 16));
      mx = fmaxf(mx, __shfl_xor(mx, 32));
      float mnew = fmaxf(mrun, mx);
      float alpha = __expf(mrun - mnew);
      mrun = mnew;
      float rs = 0.f;
      #pragma unroll
      for (int fc = 0; fc < 4; ++fc)
        #pragma unroll
        for (int j = 0; j < 4; ++j) {
          float p = __expf(sf[fc][j] - mnew);
          sf[fc][j] = p;
          rs += p;
        }
      rs += __shfl_xor(rs, 16);
      rs += __shfl_xor(rs, 32);
      lrun = lrun * alpha + rs;
      float arow[4];
      #pragma unroll
      for (int j = 0; j < 4; ++j) arow[j] = __shfl(alpha, (l & 48) | (lh * 4 + j));
      #pragma unroll
      for (int fd = 0; fd < 8; ++fd)
        #pragma unroll
        for (int j = 0; j < 4; ++j) oacc[fd][j] *= arow[j];
      short8_t pa[2];
      #pragma unroll
      for (int ks = 0; ks < 2; ++ks)
        #pragma unroll
        for (int b2 = 0; b2 < 2; ++b2)
          #pragma unroll
          for (int j = 0; j < 4; ++j) pa[ks][b2 * 4 + j] = (short)f2bf(sf[ks * 2 + b2][j]);
      #pragma unroll
      for (int fd = 0; fd < 8; ++fd) {
        int dcol = fd * 16 + ln15;
        #pragma unroll
        for (int ks = 0; ks < 2; ++ks) {
          int chunk = ks * 4 + lh;
          short8_t vf = *(const short8_t*)(Vb + dcol * 128 + ((chunk ^ (dcol & 7)) << 4));
          oacc[fd] = __builtin_amdgcn_mfma_f32_16x16x32_bf16(pa[ks], vf, oacc[fd], 0, 0, 0);
        }
      }
    }
    PBARRIER;
    if (T + 2 < NT) { stageK(T & 1, T + 2); stageV(T & 1, T + 2); }
  }

  float linv[4];
  #pragma unroll
  for (int j = 0; j < 4; ++j) linv[j] = 1.f / __shfl(lrun, (l & 48) | (lh * 4 + j));
  #pragma unroll
  for (int j = 0; j < 4; ++j) {
    int q = qb * 128 + w * 16 + lh * 4 + j;
    u16* op = AO + (size_t)(b * Sc + q) * DIMc + h * Dc + ln15;
    #pragma unroll
    for (int fd = 0; fd < 8; ++fd) op[fd * 16] = f2bf(oacc[fd][j] * linv[j]);
  }
}

extern "C" void kernel_launch(void* const* d_in, const int* in_sizes, int n_in,
                              void* d_out, int out_size, void* d_ws, size_t ws_size,
                              hipStream_t stream) {
  const float* x  = (const float*)d_in[0];
  const float* wq = (const float*)d_in[1];
  const float* wk = (const float*)d_in[2];
  const float* wv = (const float*)d_in[3];
  const float* wo = (const float*)d_in[4];
  float* out = (float*)d_out;

  char* ws = (char*)d_ws;
  size_t off = 0;
  auto alloc = [&](size_t bytes) -> char* {
    char* p = ws + off;
    off += (bytes + 255) & ~(size_t)255;
    return p;
  };
  float* tbl  = (float*)alloc((size_t)Sc * 64 * 2 * 4);
  u16* xb    = (u16*)alloc((size_t)BS * DIMc * 2);     // x bf16; later reused as AO
  u16* wqT   = (u16*)alloc((size_t)4096 * 4096 * 2);   // wqT; later woT
  u16* wkvT  = (u16*)alloc((size_t)2048 * 4096 * 2);   // [wkT ; wvT]
  u16* Qb    = (u16*)alloc((size_t)BS * 4096 * 2);     // roped Q in [b][h][s][d]
  u16* Krp   = (u16*)alloc((size_t)BS * 1024 * 2);     // roped K in [b][hkv][s][d]
  u16* Vtp   = (u16*)alloc((size_t)BS * 1024 * 2);     // V in [b][hkv][d][sigma(s)]
  u16* AO = xb;    // alias: xb dead after K/V GEMM
  u16* woT = wqT;  // alias: wqT dead after Q GEMM

  rope_table_k<<<(Sc * 64) / 256, 256, 0, stream>>>(tbl);
  f32_to_bf16_k<<<(BS * DIMc / 4) / 256, 256, 0, stream>>>(x, xb, BS * DIMc / 4);

  transpose_w_k<<<dim3(64, 64), 256, 0, stream>>>(wq, wqT, 4096, 4096);
  gemm256<2><<<256, 512, 131072, stream>>>(xb, wqT, Qb, tbl, 4096, 4096, 4096);  // Q + RoPE + relayout

  transpose_w_k<<<dim3(16, 64), 256, 0, stream>>>(wk, wkvT, 4096, 1024);
  transpose_w_k<<<dim3(16, 64), 256, 0, stream>>>(wv, wkvT + (size_t)1024 * 4096, 4096, 1024);
  gemm_kv<<<256, 512, 98304, stream>>>(xb, wkvT, Krp, Vtp, tbl);                 // K+RoPE, V+sigma-transpose

  attn_k<<<dim3(8, Hc, Bc), 512, 65536, stream>>>(Qb, Krp, Vtp, AO);

  transpose_w_k<<<dim3(64, 64), 256, 0, stream>>>(wo, woT, 4096, 4096);
  gemm256<1><<<256, 512, 131072, stream>>>(AO, woT, out, tbl, 4096, 4096, 4096);
}

// Round 10
// 477.516 us; speedup vs baseline: 1.7124x; 1.0201x over previous
//
#include <hip/hip_runtime.h>

typedef unsigned short u16;
typedef unsigned int u32;
typedef __attribute__((ext_vector_type(8))) short short8_t;  // 8 bf16 (4 VGPRs)
typedef __attribute__((ext_vector_type(4))) float f32x4;

static constexpr int Bc = 4, Sc = 1024, Hc = 32, HKVc = 8, Dc = 128;
static constexpr int BS = Bc * Sc;     // 4096 rows
static constexpr int DIMc = 4096;

__device__ __forceinline__ u16 f2bf(float f) {
  u32 u = __float_as_uint(f);
  u32 r = (u + 0x7fffu + ((u >> 16) & 1u)) >> 16;  // RNE
  return (u16)r;
}
__device__ __forceinline__ float bf2f(u16 u) {
  return __uint_as_float(((u32)u) << 16);
}
__device__ __forceinline__ void gload_lds16(const void* g, void* l) {
  __builtin_amdgcn_global_load_lds((const __attribute__((address_space(1))) void*)g,
                                   (__attribute__((address_space(3))) void*)l, 16, 0, 0);
}

#define SBAR __builtin_amdgcn_sched_barrier(0)
#define PBARRIER do { SBAR; __builtin_amdgcn_s_barrier(); SBAR; } while (0)
#define WAITVM(N) asm volatile("s_waitcnt vmcnt(" #N ")" ::: "memory")

// ---------------- RoPE table: cos/sin for (s, i) ----------------
__global__ void rope_table_k(float* __restrict__ tbl) {
  int i = blockIdx.x * 256 + threadIdx.x;     // 1024*64
  int s = i >> 6, fi = i & 63;
  float freq = powf(10000.f, -(float)fi / 64.f);
  float ang = (float)s * freq;
  float sv, cv;
  sincosf(ang, &sv, &cv);
  tbl[2 * i] = cv;
  tbl[2 * i + 1] = sv;
}

// ---------------- fp32 -> bf16 convert (vectorized) ----------------
__global__ void f32_to_bf16_k(const float* __restrict__ in, u16* __restrict__ out, int n4) {
  int i = blockIdx.x * 256 + threadIdx.x;
  if (i >= n4) return;
  float4 v = *(const float4*)(in + (size_t)i * 4);
  uint2 pk;
  pk.x = (u32)f2bf(v.x) | ((u32)f2bf(v.y) << 16);
  pk.y = (u32)f2bf(v.z) | ((u32)f2bf(v.w) << 16);
  *(uint2*)(out + (size_t)i * 4) = pk;
}

// ---------------- W (K,N) fp32 -> WT (N,K) bf16, tiled transpose ----------------
__global__ __launch_bounds__(256) void transpose_w_k(const float* __restrict__ W, u16* __restrict__ WT,
                                                     int Kdim, int Ndim) {
  __shared__ float tile[64 * 65];
  const int t = threadIdx.x;
  const int n0 = blockIdx.x * 64, k0 = blockIdx.y * 64;
  #pragma unroll
  for (int p = 0; p < 4; ++p) {
    int idx = p * 256 + t;           // 1024 float4 chunks
    int r = idx >> 4, c = (idx & 15) * 4;
    float4 v = *(const float4*)(W + (size_t)(k0 + r) * Ndim + n0 + c);
    tile[r * 65 + c + 0] = v.x;
    tile[r * 65 + c + 1] = v.y;
    tile[r * 65 + c + 2] = v.z;
    tile[r * 65 + c + 3] = v.w;
  }
  __syncthreads();
  #pragma unroll
  for (int p = 0; p < 2; ++p) {
    int idx = p * 256 + t;           // 512 chunks of 8 bf16
    int n = idx >> 3, c = (idx & 7) * 8;
    alignas(16) u16 o[8];
    #pragma unroll
    for (int i = 0; i < 8; ++i) o[i] = f2bf(tile[(c + i) * 65 + n]);
    *(uint4*)(WT + (size_t)(n0 + n) * Kdim + k0 + c) = *(const uint4*)o;
  }
}

// ---------------- 256^2-tile GEMM, each-frag-once / 1-barrier-per-tile ----------------
// MODE 1: f32 C row-major; MODE 2: bf16 + fused RoPE + relayout to Q[b][h][s][d].
// B-frags (both halves, 8 frags) resident across the tile; A-halves read per
// phase (af/af2). 24 ds_read_b128/tile/wave = geometric floor (each frag once).
// One vmcnt(0)+barrier per tile; all 4 stages of T+1 issued in p1/p2.
// acc quadrant ids: 0=Q00(A0B0) 1=Q10(A1B0) 2=Q11(A1B1) 3=Q01(A0B1).
#define MFMAQ(QI, AF, BF)                                                                \
  do {                                                                                   \
    __builtin_amdgcn_s_setprio(1);                                                       \
    _Pragma("unroll") for (int mf = 0; mf < 4; ++mf)                                     \
      _Pragma("unroll") for (int nf = 0; nf < 2; ++nf)                                   \
        _Pragma("unroll") for (int kk = 0; kk < 2; ++kk)                                 \
          acc[QI][mf][nf] = __builtin_amdgcn_mfma_f32_16x16x32_bf16(                     \
              AF[mf][kk], BF[nf][kk], acc[QI][mf][nf], 0, 0, 0);                         \
    __builtin_amdgcn_s_setprio(0);                                                       \
  } while (0)

template <int MODE>
__global__ __launch_bounds__(512, 2) void gemm256(const u16* __restrict__ A, const u16* __restrict__ BT,
                                                  void* __restrict__ Cv, const float* __restrict__ tbl,
                                                  int M, int N, int K) {
  extern __shared__ char smem[];   // 131072 B
  const int t = threadIdx.x, l = t & 63, w = t >> 6;
  const int ln15 = l & 15, lh = l >> 4;
  const int NT = K >> 6;

  int id = blockIdx.x;
  int nwg = gridDim.x;
  int swz = ((nwg & 7) == 0) ? ((id & 7) * (nwg >> 3) + (id >> 3)) : id;
  const int nbn = N >> 8;
  const int bm = swz / nbn, bn = swz % nbn;

  const u16* Ag = A + (size_t)bm * 256 * K;
  const u16* Bg = BT + (size_t)bn * 256 * K;

  f32x4 acc[4][4][2];
  #pragma unroll
  for (int q = 0; q < 4; ++q)
    #pragma unroll
    for (int mf = 0; mf < 4; ++mf)
      #pragma unroll
      for (int nf = 0; nf < 2; ++nf) acc[q][mf][nf] = f32x4{0.f, 0.f, 0.f, 0.f};
  short8_t af[4][2], af2[4][2], bfB0[2][2], bfB1[2][2];

  const int srow = (l >> 3);
  const int sck  = (l & 7) ^ srow;
  auto stageA = [&](char* bufbase, int h, int tt) {
    char* lb = bufbase + h * 16384 + w * 1024;
    const u16* g = Ag + (size_t)(h * 128 + w * 8 + srow) * K + tt * 64 + (sck << 3);
    gload_lds16(g, lb);
    gload_lds16(g + (size_t)64 * K, lb + 8192);
  };
  auto stageB = [&](char* bufbase, int h, int tt) {
    char* lb = bufbase + 32768 + h * 16384 + w * 1024;
    const u16* g = Bg + (size_t)(h * 128 + w * 8 + srow) * K + tt * 64 + (sck << 3);
    gload_lds16(g, lb);
    gload_lds16(g + (size_t)64 * K, lb + 8192);
  };
  const int arow = (w >> 2) * 64 + ln15;
  const int brow = (w & 3) * 32 + ln15;
  const int rsw = ln15 & 7;
  auto LDA = [&](const char* cb, int qm, short8_t (&dst)[4][2]) {
    #pragma unroll
    for (int mf = 0; mf < 4; ++mf)
      #pragma unroll
      for (int kk = 0; kk < 2; ++kk)
        dst[mf][kk] = *(const short8_t*)(cb + qm * 16384 + (arow + mf * 16) * 128 +
                                         (((kk * 4 + lh) ^ rsw) << 4));
  };
  auto LDB = [&](const char* cb, int qn, short8_t (&dst)[2][2]) {
    #pragma unroll
    for (int nf = 0; nf < 2; ++nf)
      #pragma unroll
      for (int kk = 0; kk < 2; ++kk)
        dst[nf][kk] = *(const short8_t*)(cb + 32768 + qn * 16384 + (brow + nf * 16) * 128 +
                                         (((kk * 4 + lh) ^ rsw) << 4));
  };

  // ---- prologue: stage tile 0, retire, read resident B ----
  stageA(smem, 0, 0);
  stageB(smem, 0, 0);
  stageA(smem, 1, 0);
  stageB(smem, 1, 0);
  WAITVM(0);
  PBARRIER;
  LDB(smem, 0, bfB0);
  LDB(smem, 1, bfB1);

  for (int T = 0; T < NT; ++T) {
    char* cb = smem + (T & 1) * 65536;
    char* nb = smem + ((T & 1) ^ 1) * 65536;
    const bool s1 = (T + 1 < NT);
    // p1: A0 phase
    if (s1) { stageA(nb, 0, T + 1); stageB(nb, 0, T + 1); }
    LDA(cb, 0, af);
    MFMAQ(0, af, bfB0);     // Q00
    MFMAQ(3, af, bfB1);     // Q01
    // p2: A1 phase
    if (s1) { stageA(nb, 1, T + 1); stageB(nb, 1, T + 1); }
    LDA(cb, 1, af2);
    MFMAQ(1, af2, bfB0);    // Q10
    MFMAQ(2, af2, bfB1);    // Q11
    WAITVM(0);              // retire tile T+1's stages (issued p1/p2)
    PBARRIER;               // all waves done reading cb; nb valid for all
    if (s1) { LDB(nb, 0, bfB0); LDB(nb, 1, bfB1); }   // resident B for T+1
  }

  // ---- epilogue ----
  const int rw = (w >> 2) * 64, cw = (w & 3) * 32;
  #pragma unroll
  for (int qi = 0; qi < 4; ++qi) {
    const int qm = (qi == 1 || qi == 2) ? 1 : 0;
    const int qn = (qi >= 2) ? 1 : 0;
    #pragma unroll
    for (int mf = 0; mf < 4; ++mf)
      #pragma unroll
      for (int nf = 0; nf < 2; ++nf)
        #pragma unroll
        for (int e = 0; e < 4; ++e) {
          int row = bm * 256 + qm * 128 + rw + mf * 16 + lh * 4 + e;
          int col = bn * 256 + qn * 128 + cw + nf * 16 + ln15;
          float v = acc[qi][mf][nf][e];
          if (MODE == 2) {
            float pv = __shfl_xor(v, 1);        // partner holds col^1 (same row)
            int d = col & 127, hh = col >> 7;
            int s = row & (Sc - 1), bb = row >> 10;
            float2 cs = *(const float2*)(tbl + (size_t)(s * 64 + (d >> 1)) * 2);
            float o = (d & 1) ? (v * cs.x + pv * cs.y) : (v * cs.x - pv * cs.y);
            o *= 0.08838834764831845f;
            ((u16*)Cv)[(((size_t)(bb * Hc + hh) * Sc + s) << 7) + d] = f2bf(o);
          } else {
            size_t idx = (size_t)row * N + col;
            ((float*)Cv)[idx] = v;
          }
        }
  }
}

// ---------------- Fused K+V projection GEMM (each-frag-once / 1-barrier) ----------------
#define MFMAKV(QM, AF)                                                                   \
  do {                                                                                   \
    __builtin_amdgcn_s_setprio(1);                                                       \
    _Pragma("unroll") for (int mf = 0; mf < 4; ++mf)                                     \
      _Pragma("unroll") for (int nf = 0; nf < 2; ++nf)                                   \
        _Pragma("unroll") for (int kk = 0; kk < 2; ++kk)                                 \
          acc[QM][mf][nf] = __builtin_amdgcn_mfma_f32_16x16x32_bf16(                     \
              AF[mf][kk], bf[nf][kk], acc[QM][mf][nf], 0, 0, 0);                         \
    __builtin_amdgcn_s_setprio(0);                                                       \
  } while (0)

__global__ __launch_bounds__(512, 1) void gemm_kv(const u16* __restrict__ A, const u16* __restrict__ BT,
                                                  u16* __restrict__ Krp, u16* __restrict__ Vtp,
                                                  const float* __restrict__ tbl) {
  extern __shared__ char smem[];   // A dbuf 2x32KB @0 | B dbuf 2x16KB @65536 = 98304 B
  const int t = threadIdx.x, l = t & 63, w = t >> 6;
  const int ln15 = l & 15, lh = l >> 4;
  const int K = 4096, NT = 64;

  int id = blockIdx.x;
  int swz = (id & 7) * 32 + (id >> 3);      // 256 blocks, XCD-bijective
  const int bm = swz >> 4, bn = swz & 15;

  const u16* Ag = A + (size_t)bm * 256 * K;
  const u16* Bg = BT + (size_t)bn * 128 * K;

  f32x4 acc[2][4][2];
  #pragma unroll
  for (int q = 0; q < 2; ++q)
    #pragma unroll
    for (int mf = 0; mf < 4; ++mf)
      #pragma unroll
      for (int nf = 0; nf < 2; ++nf) acc[q][mf][nf] = f32x4{0.f, 0.f, 0.f, 0.f};
  short8_t af[4][2], af2[4][2], bf[2][2];

  const int srow = (l >> 3);
  const int sck  = (l & 7) ^ srow;
  auto stageA = [&](int buf, int h, int tt) {   // one A half = 128 rows x 64 K = 16KB
    char* lb = smem + buf * 32768 + h * 16384 + w * 2048;
    const u16* g = Ag + (size_t)(h * 128 + w * 16 + srow) * K + tt * 64 + (sck << 3);
    gload_lds16(g, lb);
    gload_lds16(g + (size_t)8 * K, lb + 1024);
  };
  auto stageB = [&](int buf, int tt) {          // B tile = 128 rows x 64 K = 16KB
    char* lb = smem + 65536 + buf * 16384 + w * 2048;
    const u16* g = Bg + (size_t)(w * 16 + srow) * K + tt * 64 + (sck << 3);
    gload_lds16(g, lb);
    gload_lds16(g + (size_t)8 * K, lb + 1024);
  };
  const int arow = (w >> 2) * 64 + ln15;        // within A half
  const int brow = (w & 3) * 32 + ln15;         // within B tile (128 rows)
  const int rsw = ln15 & 7;
  auto LDA = [&](int buf, int qm, short8_t (&dst)[4][2]) {
    #pragma unroll
    for (int mf = 0; mf < 4; ++mf)
      #pragma unroll
      for (int kk = 0; kk < 2; ++kk)
        dst[mf][kk] = *(const short8_t*)(smem + buf * 32768 + qm * 16384 + (arow + mf * 16) * 128 +
                                         (((kk * 4 + lh) ^ rsw) << 4));
  };
  auto LDB = [&](int buf) {
    #pragma unroll
    for (int nf = 0; nf < 2; ++nf)
      #pragma unroll
      for (int kk = 0; kk < 2; ++kk)
        bf[nf][kk] = *(const short8_t*)(smem + 65536 + buf * 16384 + (brow + nf * 16) * 128 +
                                        (((kk * 4 + lh) ^ rsw) << 4));
  };

  // prologue: stage tile 0 fully, retire, read resident B
  stageA(0, 0, 0);
  stageB(0, 0);
  stageA(0, 1, 0);
  WAITVM(0);
  PBARRIER;
  LDB(0);

  for (int T = 0; T < NT; ++T) {
    const int cb = T & 1, nb = cb ^ 1;
    const bool st = (T + 1 < NT);
    // p1: A0 phase
    if (st) { stageA(nb, 0, T + 1); stageB(nb, T + 1); }
    LDA(cb, 0, af);
    MFMAKV(0, af);
    // p2: A1 phase
    if (st) stageA(nb, 1, T + 1);
    LDA(cb, 1, af2);
    MFMAKV(1, af2);
    WAITVM(0);
    PBARRIER;
    if (st) LDB(nb);
  }

  // epilogue
  #pragma unroll
  for (int qm = 0; qm < 2; ++qm)
    #pragma unroll
    for (int mf = 0; mf < 4; ++mf)
      #pragma unroll
      for (int nf = 0; nf < 2; ++nf)
        #pragma unroll
        for (int e = 0; e < 4; ++e) {
          int row = bm * 256 + qm * 128 + (w >> 2) * 64 + mf * 16 + lh * 4 + e;
          int col = bn * 128 + (w & 3) * 32 + nf * 16 + ln15;
          float v = acc[qm][mf][nf][e];
          float pv = __shfl_xor(v, 1);
          int s = row & (Sc - 1), bb = row >> 10;
          if (col < 1024) {          // K + RoPE
            int hkv = col >> 7, d = col & 127;
            float2 cs = *(const float2*)(tbl + (size_t)(s * 64 + (d >> 1)) * 2);
            float o = (d & 1) ? (v * cs.x + pv * cs.y) : (v * cs.x - pv * cs.y);
            Krp[(((size_t)(bb * HKVc + hkv) * Sc + s) << 7) + d] = f2bf(o);
          } else {                   // V, sigma-permuted transpose
            int vc = col - 1024;
            int hkv = vc >> 7, d = vc & 127;
            int sl = s & 63;
            int sg = (sl & 32) | (((sl >> 2) & 3) << 3) | (((sl >> 4) & 1) << 2) | (sl & 3);
            Vtp[((size_t)(bb * HKVc + hkv) * Dc + d) * Sc + (s & ~63) + sg] = f2bf(v);
          }
        }
}

// ---------------- Flash attention (causal, GQA), swapped-QK^T, P in registers ----------------
__global__ __launch_bounds__(512, 4) void attn_k(const u16* __restrict__ Q, const u16* __restrict__ Kr,
                                                 const u16* __restrict__ Vt, u16* __restrict__ AO) {
  extern __shared__ char smem[];
  const int t = threadIdx.x, l = t & 63, w = t >> 6;
  const int qb = (int)gridDim.x - 1 - (int)blockIdx.x;   // big causal tiles dispatched first
  const int h = blockIdx.y, b = blockIdx.z;
  const int hkv = h >> 2;
  const int ln15 = l & 15, lh = l >> 4;
  const int NT = 2 * qb + 2;

  const u16* Kg0 = Kr + (size_t)(b * HKVc + hkv) * Sc * Dc;
  const u16* Vg0 = Vt + (size_t)(b * HKVc + hkv) * Dc * Sc;

  auto stageK = [&](int buf, int tt) {
    char* base = smem + buf * 16384 + w * 2048;
    #pragma unroll
    for (int i = 0; i < 2; ++i) {
      int row = w * 8 + i * 4 + (l >> 4);
      int c = l & 15;
      gload_lds16(Kg0 + (size_t)(tt * 64 + row) * Dc + ((c ^ (row & 7)) << 3), base + i * 1024);
    }
  };
  auto stageV = [&](int buf, int tt) {
    char* base = smem + 32768 + buf * 16384 + w * 2048;
    #pragma unroll
    for (int i = 0; i < 2; ++i) {
      int d = w * 16 + i * 8 + (l >> 3);
      int c = l & 7;
      gload_lds16(Vg0 + (size_t)d * Sc + tt * 64 + ((c ^ (d & 7)) << 3), base + i * 1024);
    }
  };

  short8_t qf[4];
  {
    int q = qb * 128 + w * 16 + ln15;
    const u16* qp = Q + ((size_t)(b * Hc + h) * Sc + q) * Dc + lh * 8;
    #pragma unroll
    for (int ks = 0; ks < 4; ++ks) qf[ks] = *(const short8_t*)(qp + ks * 32);
  }
  SBAR;   // qf loads issued before staging (vmcnt ordering)

  f32x4 oacc[8];
  #pragma unroll
  for (int i = 0; i < 8; ++i) oacc[i] = f32x4{0.f, 0.f, 0.f, 0.f};
  float mrun = -1e30f, lrun = 0.f;

  stageK(0, 0); stageV(0, 0);
  stageK(1, 1); stageV(1, 1);

  const int qmaxw = qb * 128 + w * 16 + 15;
  const int qlane = qb * 128 + w * 16 + ln15;

  for (int T = 0; T < NT; ++T) {
    if (T < NT - 1) { WAITVM(4); } else { WAITVM(0); }
    PBARRIER;
    const char* Kb = smem + (T & 1) * 16384;
    const char* Vb = smem + 32768 + (T & 1) * 16384;

    if (T * 64 <= qmaxw) {
      f32x4 sf[4];
      #pragma unroll
      for (int fc = 0; fc < 4; ++fc) {
        sf[fc] = f32x4{0.f, 0.f, 0.f, 0.f};
        int kvr = fc * 16 + ln15;
        #pragma unroll
        for (int ks = 0; ks < 4; ++ks) {
          int chunk = ks * 4 + lh;
          short8_t kf = *(const short8_t*)(Kb + kvr * 256 + ((chunk ^ (kvr & 7)) << 4));
          sf[fc] = __builtin_amdgcn_mfma_f32_16x16x32_bf16(kf, qf[ks], sf[fc], 0, 0, 0);
        }
      }
      if (T * 64 + 63 > qb * 128 + w * 16) {
        #pragma unroll
        for (int fc = 0; fc < 4; ++fc)
          #pragma unroll
          for (int j = 0; j < 4; ++j) {
            int kvg = T * 64 + fc * 16 + lh * 4 + j;
            if (kvg > qlane) sf[fc][j] = -1e30f;
          }
      }
      float mx = sf[0][0];
      #pragma unroll
      for (int fc = 0; fc < 4; ++fc)
        #pragma unroll
        for (int j = 0; j < 4; ++j) mx = fmaxf(mx, sf[fc][j]);
      mx = fmaxf(mx, __shfl_xor(mx, 16));
      mx = fmaxf(mx, __shfl_xor(mx, 32));
      float mnew = fmaxf(mrun, mx);
      float alpha = __expf(mrun - mnew);
      mrun = mnew;
      float rs = 0.f;
      #pragma unroll
      for (int fc = 0; fc < 4; ++fc)
        #pragma unroll
        for (int j = 0; j < 4; ++j) {
          float p = __expf(sf[fc][j] - mnew);
          sf[fc][j] = p;
          rs += p;
        }
      rs += __shfl_xor(rs, 16);
      rs += __shfl_xor(rs, 32);
      lrun = lrun * alpha + rs;
      float arow[4];
      #pragma unroll
      for (int j = 0; j < 4; ++j) arow[j] = __shfl(alpha, (l & 48) | (lh * 4 + j));
      #pragma unroll
      for (int fd = 0; fd < 8; ++fd)
        #pragma unroll
        for (int j = 0; j < 4; ++j) oacc[fd][j] *= arow[j];
      short8_t pa[2];
      #pragma unroll
      for (int ks = 0; ks < 2; ++ks)
        #pragma unroll
        for (int b2 = 0; b2 < 2; ++b2)
          #pragma unroll
          for (int j = 0; j < 4; ++j) pa[ks][b2 * 4 + j] = (short)f2bf(sf[ks * 2 + b2][j]);
      #pragma unroll
      for (int fd = 0; fd < 8; ++fd) {
        int dcol = fd * 16 + ln15;
        #pragma unroll
        for (int ks = 0; ks < 2; ++ks) {
          int chunk = ks * 4 + lh;
          short8_t vf = *(const short8_t*)(Vb + dcol * 128 + ((chunk ^ (dcol & 7)) << 4));
          oacc[fd] = __builtin_amdgcn_mfma_f32_16x16x32_bf16(pa[ks], vf, oacc[fd], 0, 0, 0);
        }
      }
    }
    PBARRIER;
    if (T + 2 < NT) { stageK(T & 1, T + 2); stageV(T & 1, T + 2); }
  }

  float linv[4];
  #pragma unroll
  for (int j = 0; j < 4; ++j) linv[j] = 1.f / __shfl(lrun, (l & 48) | (lh * 4 + j));
  #pragma unroll
  for (int j = 0; j < 4; ++j) {
    int q = qb * 128 + w * 16 + lh * 4 + j;
    u16* op = AO + (size_t)(b * Sc + q) * DIMc + h * Dc + ln15;
    #pragma unroll
    for (int fd = 0; fd < 8; ++fd) op[fd * 16] = f2bf(oacc[fd][j] * linv[j]);
  }
}

extern "C" void kernel_launch(void* const* d_in, const int* in_sizes, int n_in,
                              void* d_out, int out_size, void* d_ws, size_t ws_size,
                              hipStream_t stream) {
  const float* x  = (const float*)d_in[0];
  const float* wq = (const float*)d_in[1];
  const float* wk = (const float*)d_in[2];
  const float* wv = (const float*)d_in[3];
  const float* wo = (const float*)d_in[4];
  float* out = (float*)d_out;

  char* ws = (char*)d_ws;
  size_t off = 0;
  auto alloc = [&](size_t bytes) -> char* {
    char* p = ws + off;
    off += (bytes + 255) & ~(size_t)255;
    return p;
  };
  float* tbl  = (float*)alloc((size_t)Sc * 64 * 2 * 4);
  u16* xb    = (u16*)alloc((size_t)BS * DIMc * 2);     // x bf16; later reused as AO
  u16* wqT   = (u16*)alloc((size_t)4096 * 4096 * 2);   // wqT; later woT
  u16* wkvT  = (u16*)alloc((size_t)2048 * 4096 * 2);   // [wkT ; wvT]
  u16* Qb    = (u16*)alloc((size_t)BS * 4096 * 2);     // roped Q in [b][h][s][d]
  u16* Krp   = (u16*)alloc((size_t)BS * 1024 * 2);     // roped K in [b][hkv][s][d]
  u16* Vtp   = (u16*)alloc((size_t)BS * 1024 * 2);     // V in [b][hkv][d][sigma(s)]
  u16* AO = xb;    // alias: xb dead after K/V GEMM
  u16* woT = wqT;  // alias: wqT dead after Q GEMM

  rope_table_k<<<(Sc * 64) / 256, 256, 0, stream>>>(tbl);
  f32_to_bf16_k<<<(BS * DIMc / 4) / 256, 256, 0, stream>>>(x, xb, BS * DIMc / 4);

  transpose_w_k<<<dim3(64, 64), 256, 0, stream>>>(wq, wqT, 4096, 4096);
  gemm256<2><<<256, 512, 131072, stream>>>(xb, wqT, Qb, tbl, 4096, 4096, 4096);  // Q + RoPE + relayout

  transpose_w_k<<<dim3(16, 64), 256, 0, stream>>>(wk, wkvT, 4096, 1024);
  transpose_w_k<<<dim3(16, 64), 256, 0, stream>>>(wv, wkvT + (size_t)1024 * 4096, 4096, 1024);
  gemm_kv<<<256, 512, 98304, stream>>>(xb, wkvT, Krp, Vtp, tbl);                 // K+RoPE, V+sigma-transpose

  attn_k<<<dim3(8, Hc, Bc), 512, 65536, stream>>>(Qb, Krp, Vtp, AO);

  transpose_w_k<<<dim3(64, 64), 256, 0, stream>>>(wo, woT, 4096, 4096);
  gemm256<1><<<256, 512, 131072, stream>>>(AO, woT, out, tbl, 4096, 4096, 4096);
}

// Round 11
// 473.166 us; speedup vs baseline: 1.7281x; 1.0092x over previous
//
#include <hip/hip_runtime.h>

typedef unsigned short u16;
typedef unsigned int u32;
typedef __attribute__((ext_vector_type(8))) short short8_t;  // 8 bf16 (4 VGPRs)
typedef __attribute__((ext_vector_type(4))) float f32x4;

static constexpr int Bc = 4, Sc = 1024, Hc = 32, HKVc = 8, Dc = 128;
static constexpr int BS = Bc * Sc;     // 4096 rows
static constexpr int DIMc = 4096;

__device__ __forceinline__ u16 f2bf(float f) {
  u32 u = __float_as_uint(f);
  u32 r = (u + 0x7fffu + ((u >> 16) & 1u)) >> 16;  // RNE
  return (u16)r;
}
__device__ __forceinline__ float bf2f(u16 u) {
  return __uint_as_float(((u32)u) << 16);
}
__device__ __forceinline__ void gload_lds16(const void* g, void* l) {
  __builtin_amdgcn_global_load_lds((const __attribute__((address_space(1))) void*)g,
                                   (__attribute__((address_space(3))) void*)l, 16, 0, 0);
}

#define SBAR __builtin_amdgcn_sched_barrier(0)
#define PBARRIER do { SBAR; __builtin_amdgcn_s_barrier(); SBAR; } while (0)
#define WAITVM(N) asm volatile("s_waitcnt vmcnt(" #N ")" ::: "memory")

// ---------------- RoPE table: cos/sin for (s, i) ----------------
__global__ void rope_table_k(float* __restrict__ tbl) {
  int i = blockIdx.x * 256 + threadIdx.x;     // 1024*64
  int s = i >> 6, fi = i & 63;
  float freq = powf(10000.f, -(float)fi / 64.f);
  float ang = (float)s * freq;
  float sv, cv;
  sincosf(ang, &sv, &cv);
  tbl[2 * i] = cv;
  tbl[2 * i + 1] = sv;
}

// ---------------- fp32 -> bf16 convert (vectorized) ----------------
__global__ void f32_to_bf16_k(const float* __restrict__ in, u16* __restrict__ out, int n4) {
  int i = blockIdx.x * 256 + threadIdx.x;
  if (i >= n4) return;
  float4 v = *(const float4*)(in + (size_t)i * 4);
  uint2 pk;
  pk.x = (u32)f2bf(v.x) | ((u32)f2bf(v.y) << 16);
  pk.y = (u32)f2bf(v.z) | ((u32)f2bf(v.w) << 16);
  *(uint2*)(out + (size_t)i * 4) = pk;
}

// ---------------- W (K,N) fp32 -> WT (N,K) bf16, tiled transpose ----------------
__global__ __launch_bounds__(256) void transpose_w_k(const float* __restrict__ W, u16* __restrict__ WT,
                                                     int Kdim, int Ndim) {
  __shared__ float tile[64 * 65];
  const int t = threadIdx.x;
  const int n0 = blockIdx.x * 64, k0 = blockIdx.y * 64;
  #pragma unroll
  for (int p = 0; p < 4; ++p) {
    int idx = p * 256 + t;           // 1024 float4 chunks
    int r = idx >> 4, c = (idx & 15) * 4;
    float4 v = *(const float4*)(W + (size_t)(k0 + r) * Ndim + n0 + c);
    tile[r * 65 + c + 0] = v.x;
    tile[r * 65 + c + 1] = v.y;
    tile[r * 65 + c + 2] = v.z;
    tile[r * 65 + c + 3] = v.w;
  }
  __syncthreads();
  #pragma unroll
  for (int p = 0; p < 2; ++p) {
    int idx = p * 256 + t;           // 512 chunks of 8 bf16
    int n = idx >> 3, c = (idx & 7) * 8;
    alignas(16) u16 o[8];
    #pragma unroll
    for (int i = 0; i < 8; ++i) o[i] = f2bf(tile[(c + i) * 65 + n]);
    *(uint4*)(WT + (size_t)(n0 + n) * Kdim + k0 + c) = *(const uint4*)o;
  }
}

// ---------------- 256^2-tile GEMM, each-frag-once / counted-vmcnt pipeline ----------------
// MODE 1: f32 C row-major; MODE 2: bf16 + fused RoPE + relayout to Q[b][h][s][d].
// All 4 stages of T+1 issue at p1-start (full-tile lead). In-order-retirement
// vmcnt ledger: enter tile with 2 outstanding (A1(T)); +8 -> vmcnt(8) before
// p2's LDA (retires A1(T)); vmcnt(2) before tile-end barrier (retires
// A0,B0,B1 of T+1; A1(T+1) stays in flight). NO vmcnt(0) in the main loop.
#define MFMAQ(QI, AF, BF)                                                                \
  do {                                                                                   \
    __builtin_amdgcn_s_setprio(1);                                                       \
    _Pragma("unroll") for (int mf = 0; mf < 4; ++mf)                                     \
      _Pragma("unroll") for (int nf = 0; nf < 2; ++nf)                                   \
        _Pragma("unroll") for (int kk = 0; kk < 2; ++kk)                                 \
          acc[QI][mf][nf] = __builtin_amdgcn_mfma_f32_16x16x32_bf16(                     \
              AF[mf][kk], BF[nf][kk], acc[QI][mf][nf], 0, 0, 0);                         \
    __builtin_amdgcn_s_setprio(0);                                                       \
  } while (0)

template <int MODE>
__global__ __launch_bounds__(512, 2) void gemm256(const u16* __restrict__ A, const u16* __restrict__ BT,
                                                  void* __restrict__ Cv, const float* __restrict__ tbl,
                                                  int M, int N, int K) {
  extern __shared__ char smem[];   // 131072 B
  const int t = threadIdx.x, l = t & 63, w = t >> 6;
  const int ln15 = l & 15, lh = l >> 4;
  const int NT = K >> 6;

  int id = blockIdx.x;
  int nwg = gridDim.x;
  int swz = ((nwg & 7) == 0) ? ((id & 7) * (nwg >> 3) + (id >> 3)) : id;
  const int nbn = N >> 8;
  const int bm = swz / nbn, bn = swz % nbn;

  const u16* Ag = A + (size_t)bm * 256 * K;
  const u16* Bg = BT + (size_t)bn * 256 * K;

  f32x4 acc[4][4][2];
  #pragma unroll
  for (int q = 0; q < 4; ++q)
    #pragma unroll
    for (int mf = 0; mf < 4; ++mf)
      #pragma unroll
      for (int nf = 0; nf < 2; ++nf) acc[q][mf][nf] = f32x4{0.f, 0.f, 0.f, 0.f};
  short8_t af[4][2], af2[4][2], bfB0[2][2], bfB1[2][2];

  const int srow = (l >> 3);
  const int sck  = (l & 7) ^ srow;
  auto stageA = [&](char* bufbase, int h, int tt) {
    char* lb = bufbase + h * 16384 + w * 1024;
    const u16* g = Ag + (size_t)(h * 128 + w * 8 + srow) * K + tt * 64 + (sck << 3);
    gload_lds16(g, lb);
    gload_lds16(g + (size_t)64 * K, lb + 8192);
  };
  auto stageB = [&](char* bufbase, int h, int tt) {
    char* lb = bufbase + 32768 + h * 16384 + w * 1024;
    const u16* g = Bg + (size_t)(h * 128 + w * 8 + srow) * K + tt * 64 + (sck << 3);
    gload_lds16(g, lb);
    gload_lds16(g + (size_t)64 * K, lb + 8192);
  };
  const int arow = (w >> 2) * 64 + ln15;
  const int brow = (w & 3) * 32 + ln15;
  const int rsw = ln15 & 7;
  auto LDA = [&](const char* cb, int qm, short8_t (&dst)[4][2]) {
    #pragma unroll
    for (int mf = 0; mf < 4; ++mf)
      #pragma unroll
      for (int kk = 0; kk < 2; ++kk)
        dst[mf][kk] = *(const short8_t*)(cb + qm * 16384 + (arow + mf * 16) * 128 +
                                         (((kk * 4 + lh) ^ rsw) << 4));
  };
  auto LDB = [&](const char* cb, int qn, short8_t (&dst)[2][2]) {
    #pragma unroll
    for (int nf = 0; nf < 2; ++nf)
      #pragma unroll
      for (int kk = 0; kk < 2; ++kk)
        dst[nf][kk] = *(const short8_t*)(cb + 32768 + qn * 16384 + (brow + nf * 16) * 128 +
                                         (((kk * 4 + lh) ^ rsw) << 4));
  };

  // ---- prologue: stage tile 0 (A0,B0,B1,A1); retire all but A1 ----
  stageA(smem, 0, 0);
  stageB(smem, 0, 0);
  stageB(smem, 1, 0);
  stageA(smem, 1, 0);
  WAITVM(2);
  PBARRIER;

  for (int T = 0; T < NT; ++T) {
    char* cb = smem + (T & 1) * 65536;
    char* nb = smem + ((T & 1) ^ 1) * 65536;
    const bool s1 = (T + 1 < NT);
    // resident B for this tile (cb valid post-barrier except A1, handled below)
    LDB(cb, 0, bfB0);
    LDB(cb, 1, bfB1);
    // stage ALL of T+1 now (order A0,B0,B1,A1) -> full-tile latency lead
    if (s1) {
      stageA(nb, 0, T + 1);
      stageB(nb, 0, T + 1);
      stageB(nb, 1, T + 1);
      stageA(nb, 1, T + 1);
    }
    // p1: A0 phase
    LDA(cb, 0, af);
    MFMAQ(0, af, bfB0);     // Q00
    MFMAQ(3, af, bfB1);     // Q01
    // p2: A1 phase (A1(T) retired: it was issued one tile ago)
    if (s1) { WAITVM(8); } else { WAITVM(0); }
    LDA(cb, 1, af2);
    MFMAQ(1, af2, bfB0);    // Q10
    MFMAQ(2, af2, bfB1);    // Q11
    if (s1) { WAITVM(2); }  // retire A0,B0,B1 of T+1; keep A1(T+1) in flight
    PBARRIER;               // all waves done reading cb; nb (minus A1) valid
  }

  // ---- epilogue ----
  const int rw = (w >> 2) * 64, cw = (w & 3) * 32;
  #pragma unroll
  for (int qi = 0; qi < 4; ++qi) {
    const int qm = (qi == 1 || qi == 2) ? 1 : 0;
    const int qn = (qi >= 2) ? 1 : 0;
    #pragma unroll
    for (int mf = 0; mf < 4; ++mf)
      #pragma unroll
      for (int nf = 0; nf < 2; ++nf)
        #pragma unroll
        for (int e = 0; e < 4; ++e) {
          int row = bm * 256 + qm * 128 + rw + mf * 16 + lh * 4 + e;
          int col = bn * 256 + qn * 128 + cw + nf * 16 + ln15;
          float v = acc[qi][mf][nf][e];
          if (MODE == 2) {
            float pv = __shfl_xor(v, 1);        // partner holds col^1 (same row)
            int d = col & 127, hh = col >> 7;
            int s = row & (Sc - 1), bb = row >> 10;
            float2 cs = *(const float2*)(tbl + (size_t)(s * 64 + (d >> 1)) * 2);
            float o = (d & 1) ? (v * cs.x + pv * cs.y) : (v * cs.x - pv * cs.y);
            o *= 0.08838834764831845f;
            ((u16*)Cv)[(((size_t)(bb * Hc + hh) * Sc + s) << 7) + d] = f2bf(o);
          } else {
            size_t idx = (size_t)row * N + col;
            ((float*)Cv)[idx] = v;
          }
        }
  }
}

// ---------------- Fused K+V projection GEMM (each-frag-once, counted vmcnt) ----------------
#define MFMAKV(QM, AF)                                                                   \
  do {                                                                                   \
    __builtin_amdgcn_s_setprio(1);                                                       \
    _Pragma("unroll") for (int mf = 0; mf < 4; ++mf)                                     \
      _Pragma("unroll") for (int nf = 0; nf < 2; ++nf)                                   \
        _Pragma("unroll") for (int kk = 0; kk < 2; ++kk)                                 \
          acc[QM][mf][nf] = __builtin_amdgcn_mfma_f32_16x16x32_bf16(                     \
              AF[mf][kk], bf[nf][kk], acc[QM][mf][nf], 0, 0, 0);                         \
    __builtin_amdgcn_s_setprio(0);                                                       \
  } while (0)

__global__ __launch_bounds__(512, 1) void gemm_kv(const u16* __restrict__ A, const u16* __restrict__ BT,
                                                  u16* __restrict__ Krp, u16* __restrict__ Vtp,
                                                  const float* __restrict__ tbl) {
  extern __shared__ char smem[];   // A dbuf 2x32KB @0 | B dbuf 2x16KB @65536 = 98304 B
  const int t = threadIdx.x, l = t & 63, w = t >> 6;
  const int ln15 = l & 15, lh = l >> 4;
  const int K = 4096, NT = 64;

  int id = blockIdx.x;
  int swz = (id & 7) * 32 + (id >> 3);      // 256 blocks, XCD-bijective
  const int bm = swz >> 4, bn = swz & 15;

  const u16* Ag = A + (size_t)bm * 256 * K;
  const u16* Bg = BT + (size_t)bn * 128 * K;

  f32x4 acc[2][4][2];
  #pragma unroll
  for (int q = 0; q < 2; ++q)
    #pragma unroll
    for (int mf = 0; mf < 4; ++mf)
      #pragma unroll
      for (int nf = 0; nf < 2; ++nf) acc[q][mf][nf] = f32x4{0.f, 0.f, 0.f, 0.f};
  short8_t af[4][2], af2[4][2], bf[2][2];

  const int srow = (l >> 3);
  const int sck  = (l & 7) ^ srow;
  auto stageA = [&](int buf, int h, int tt) {   // one A half = 128 rows x 64 K = 16KB
    char* lb = smem + buf * 32768 + h * 16384 + w * 2048;
    const u16* g = Ag + (size_t)(h * 128 + w * 16 + srow) * K + tt * 64 + (sck << 3);
    gload_lds16(g, lb);
    gload_lds16(g + (size_t)8 * K, lb + 1024);
  };
  auto stageB = [&](int buf, int tt) {          // B tile = 128 rows x 64 K = 16KB
    char* lb = smem + 65536 + buf * 16384 + w * 2048;
    const u16* g = Bg + (size_t)(w * 16 + srow) * K + tt * 64 + (sck << 3);
    gload_lds16(g, lb);
    gload_lds16(g + (size_t)8 * K, lb + 1024);
  };
  const int arow = (w >> 2) * 64 + ln15;        // within A half
  const int brow = (w & 3) * 32 + ln15;         // within B tile (128 rows)
  const int rsw = ln15 & 7;
  auto LDA = [&](int buf, int qm, short8_t (&dst)[4][2]) {
    #pragma unroll
    for (int mf = 0; mf < 4; ++mf)
      #pragma unroll
      for (int kk = 0; kk < 2; ++kk)
        dst[mf][kk] = *(const short8_t*)(smem + buf * 32768 + qm * 16384 + (arow + mf * 16) * 128 +
                                         (((kk * 4 + lh) ^ rsw) << 4));
  };
  auto LDB = [&](int buf) {
    #pragma unroll
    for (int nf = 0; nf < 2; ++nf)
      #pragma unroll
      for (int kk = 0; kk < 2; ++kk)
        bf[nf][kk] = *(const short8_t*)(smem + 65536 + buf * 16384 + (brow + nf * 16) * 128 +
                                        (((kk * 4 + lh) ^ rsw) << 4));
  };

  // prologue: stage tile 0 (A0,B,A1); retire all but A1
  stageA(0, 0, 0);
  stageB(0, 0);
  stageA(0, 1, 0);
  WAITVM(2);
  PBARRIER;

  for (int T = 0; T < NT; ++T) {
    const int cb = T & 1, nb = cb ^ 1;
    const bool st = (T + 1 < NT);
    LDB(cb);
    if (st) { stageA(nb, 0, T + 1); stageB(nb, T + 1); stageA(nb, 1, T + 1); }
    // p1: A0 phase
    LDA(cb, 0, af);
    MFMAKV(0, af);
    // p2: A1 phase
    if (st) { WAITVM(6); } else { WAITVM(0); }   // retire A1(T)
    LDA(cb, 1, af2);
    MFMAKV(1, af2);
    if (st) { WAITVM(2); }                       // retire A0,B of T+1
    PBARRIER;
  }

  // epilogue
  #pragma unroll
  for (int qm = 0; qm < 2; ++qm)
    #pragma unroll
    for (int mf = 0; mf < 4; ++mf)
      #pragma unroll
      for (int nf = 0; nf < 2; ++nf)
        #pragma unroll
        for (int e = 0; e < 4; ++e) {
          int row = bm * 256 + qm * 128 + (w >> 2) * 64 + mf * 16 + lh * 4 + e;
          int col = bn * 128 + (w & 3) * 32 + nf * 16 + ln15;
          float v = acc[qm][mf][nf][e];
          float pv = __shfl_xor(v, 1);
          int s = row & (Sc - 1), bb = row >> 10;
          if (col < 1024) {          // K + RoPE
            int hkv = col >> 7, d = col & 127;
            float2 cs = *(const float2*)(tbl + (size_t)(s * 64 + (d >> 1)) * 2);
            float o = (d & 1) ? (v * cs.x + pv * cs.y) : (v * cs.x - pv * cs.y);
            Krp[(((size_t)(bb * HKVc + hkv) * Sc + s) << 7) + d] = f2bf(o);
          } else {                   // V, sigma-permuted transpose
            int vc = col - 1024;
            int hkv = vc >> 7, d = vc & 127;
            int sl = s & 63;
            int sg = (sl & 32) | (((sl >> 2) & 3) << 3) | (((sl >> 4) & 1) << 2) | (sl & 3);
            Vtp[((size_t)(bb * HKVc + hkv) * Dc + d) * Sc + (s & ~63) + sg] = f2bf(v);
          }
        }
}

// ---------------- Flash attention (causal, GQA), swapped-QK^T, P in registers ----------------
__global__ __launch_bounds__(512, 4) void attn_k(const u16* __restrict__ Q, const u16* __restrict__ Kr,
                                                 const u16* __restrict__ Vt, u16* __restrict__ AO) {
  extern __shared__ char smem[];
  const int t = threadIdx.x, l = t & 63, w = t >> 6;
  const int qb = (int)gridDim.x - 1 - (int)blockIdx.x;   // big causal tiles dispatched first
  const int h = blockIdx.y, b = blockIdx.z;
  const int hkv = h >> 2;
  const int ln15 = l & 15, lh = l >> 4;
  const int NT = 2 * qb + 2;

  const u16* Kg0 = Kr + (size_t)(b * HKVc + hkv) * Sc * Dc;
  const u16* Vg0 = Vt + (size_t)(b * HKVc + hkv) * Dc * Sc;

  auto stageK = [&](int buf, int tt) {
    char* base = smem + buf * 16384 + w * 2048;
    #pragma unroll
    for (int i = 0; i < 2; ++i) {
      int row = w * 8 + i * 4 + (l >> 4);
      int c = l & 15;
      gload_lds16(Kg0 + (size_t)(tt * 64 + row) * Dc + ((c ^ (row & 7)) << 3), base + i * 1024);
    }
  };
  auto stageV = [&](int buf, int tt) {
    char* base = smem + 32768 + buf * 16384 + w * 2048;
    #pragma unroll
    for (int i = 0; i < 2; ++i) {
      int d = w * 16 + i * 8 + (l >> 3);
      int c = l & 7;
      gload_lds16(Vg0 + (size_t)d * Sc + tt * 64 + ((c ^ (d & 7)) << 3), base + i * 1024);
    }
  };

  short8_t qf[4];
  {
    int q = qb * 128 + w * 16 + ln15;
    const u16* qp = Q + ((size_t)(b * Hc + h) * Sc + q) * Dc + lh * 8;
    #pragma unroll
    for (int ks = 0; ks < 4; ++ks) qf[ks] = *(const short8_t*)(qp + ks * 32);
  }
  SBAR;   // qf loads issued before staging (vmcnt ordering)

  f32x4 oacc[8];
  #pragma unroll
  for (int i = 0; i < 8; ++i) oacc[i] = f32x4{0.f, 0.f, 0.f, 0.f};
  float mrun = -1e30f, lrun = 0.f;

  stageK(0, 0); stageV(0, 0);
  stageK(1, 1); stageV(1, 1);

  const int qmaxw = qb * 128 + w * 16 + 15;
  const int qlane = qb * 128 + w * 16 + ln15;

  for (int T = 0; T < NT; ++T) {
    if (T < NT - 1) { WAITVM(4); } else { WAITVM(0); }
    PBARRIER;
    const char* Kb = smem + (T & 1) * 16384;
    const char* Vb = smem + 32768 + (T & 1) * 16384;

    if (T * 64 <= qmaxw) {
      f32x4 sf[4];
      #pragma unroll
      for (int fc = 0; fc < 4; ++fc) {
        sf[fc] = f32x4{0.f, 0.f, 0.f, 0.f};
        int kvr = fc * 16 + ln15;
        #pragma unroll
        for (int ks = 0; ks < 4; ++ks) {
          int chunk = ks * 4 + lh;
          short8_t kf = *(const short8_t*)(Kb + kvr * 256 + ((chunk ^ (kvr & 7)) << 4));
          sf[fc] = __builtin_amdgcn_mfma_f32_16x16x32_bf16(kf, qf[ks], sf[fc], 0, 0, 0);
        }
      }
      if (T * 64 + 63 > qb * 128 + w * 16) {
        #pragma unroll
        for (int fc = 0; fc < 4; ++fc)
          #pragma unroll
          for (int j = 0; j < 4; ++j) {
            int kvg = T * 64 + fc * 16 + lh * 4 + j;
            if (kvg > qlane) sf[fc][j] = -1e30f;
          }
      }
      float mx = sf[0][0];
      #pragma unroll
      for (int fc = 0; fc < 4; ++fc)
        #pragma unroll
        for (int j = 0; j < 4; ++j) mx = fmaxf(mx, sf[fc][j]);
      mx = fmaxf(mx, __shfl_xor(mx, 16));
      mx = fmaxf(mx, __shfl_xor(mx, 32));
      float mnew = fmaxf(mrun, mx);
      float alpha = __expf(mrun - mnew);
      mrun = mnew;
      float rs = 0.f;
      #pragma unroll
      for (int fc = 0; fc < 4; ++fc)
        #pragma unroll
        for (int j = 0; j < 4; ++j) {
          float p = __expf(sf[fc][j] - mnew);
          sf[fc][j] = p;
          rs += p;
        }
      rs += __shfl_xor(rs, 16);
      rs += __shfl_xor(rs, 32);
      lrun = lrun * alpha + rs;
      float arow[4];
      #pragma unroll
      for (int j = 0; j < 4; ++j) arow[j] = __shfl(alpha, (l & 48) | (lh * 4 + j));
      #pragma unroll
      for (int fd = 0; fd < 8; ++fd)
        #pragma unroll
        for (int j = 0; j < 4; ++j) oacc[fd][j] *= arow[j];
      short8_t pa[2];
      #pragma unroll
      for (int ks = 0; ks < 2; ++ks)
        #pragma unroll
        for (int b2 = 0; b2 < 2; ++b2)
          #pragma unroll
          for (int j = 0; j < 4; ++j) pa[ks][b2 * 4 + j] = (short)f2bf(sf[ks * 2 + b2][j]);
      #pragma unroll
      for (int fd = 0; fd < 8; ++fd) {
        int dcol = fd * 16 + ln15;
        #pragma unroll
        for (int ks = 0; ks < 2; ++ks) {
          int chunk = ks * 4 + lh;
          short8_t vf = *(const short8_t*)(Vb + dcol * 128 + ((chunk ^ (dcol & 7)) << 4));
          oacc[fd] = __builtin_amdgcn_mfma_f32_16x16x32_bf16(pa[ks], vf, oacc[fd], 0, 0, 0);
        }
      }
    }
    PBARRIER;
    if (T + 2 < NT) { stageK(T & 1, T + 2); stageV(T & 1, T + 2); }
  }

  float linv[4];
  #pragma unroll
  for (int j = 0; j < 4; ++j) linv[j] = 1.f / __shfl(lrun, (l & 48) | (lh * 4 + j));
  #pragma unroll
  for (int j = 0; j < 4; ++j) {
    int q = qb * 128 + w * 16 + lh * 4 + j;
    u16* op = AO + (size_t)(b * Sc + q) * DIMc + h * Dc + ln15;
    #pragma unroll
    for (int fd = 0; fd < 8; ++fd) op[fd * 16] = f2bf(oacc[fd][j] * linv[j]);
  }
}

extern "C" void kernel_launch(void* const* d_in, const int* in_sizes, int n_in,
                              void* d_out, int out_size, void* d_ws, size_t ws_size,
                              hipStream_t stream) {
  const float* x  = (const float*)d_in[0];
  const float* wq = (const float*)d_in[1];
  const float* wk = (const float*)d_in[2];
  const float* wv = (const float*)d_in[3];
  const float* wo = (const float*)d_in[4];
  float* out = (float*)d_out;

  char* ws = (char*)d_ws;
  size_t off = 0;
  auto alloc = [&](size_t bytes) -> char* {
    char* p = ws + off;
    off += (bytes + 255) & ~(size_t)255;
    return p;
  };
  float* tbl  = (float*)alloc((size_t)Sc * 64 * 2 * 4);
  u16* xb    = (u16*)alloc((size_t)BS * DIMc * 2);     // x bf16; later reused as AO
  u16* wqT   = (u16*)alloc((size_t)4096 * 4096 * 2);   // wqT; later woT
  u16* wkvT  = (u16*)alloc((size_t)2048 * 4096 * 2);   // [wkT ; wvT]
  u16* Qb    = (u16*)alloc((size_t)BS * 4096 * 2);     // roped Q in [b][h][s][d]
  u16* Krp   = (u16*)alloc((size_t)BS * 1024 * 2);     // roped K in [b][hkv][s][d]
  u16* Vtp   = (u16*)alloc((size_t)BS * 1024 * 2);     // V in [b][hkv][d][sigma(s)]
  u16* AO = xb;    // alias: xb dead after K/V GEMM
  u16* woT = wqT;  // alias: wqT dead after Q GEMM

  rope_table_k<<<(Sc * 64) / 256, 256, 0, stream>>>(tbl);
  f32_to_bf16_k<<<(BS * DIMc / 4) / 256, 256, 0, stream>>>(x, xb, BS * DIMc / 4);

  transpose_w_k<<<dim3(64, 64), 256, 0, stream>>>(wq, wqT, 4096, 4096);
  gemm256<2><<<256, 512, 131072, stream>>>(xb, wqT, Qb, tbl, 4096, 4096, 4096);  // Q + RoPE + relayout

  transpose_w_k<<<dim3(16, 64), 256, 0, stream>>>(wk, wkvT, 4096, 1024);
  transpose_w_k<<<dim3(16, 64), 256, 0, stream>>>(wv, wkvT + (size_t)1024 * 4096, 4096, 1024);
  gemm_kv<<<256, 512, 98304, stream>>>(xb, wkvT, Krp, Vtp, tbl);                 // K+RoPE, V+sigma-transpose

  attn_k<<<dim3(8, Hc, Bc), 512, 65536, stream>>>(Qb, Krp, Vtp, AO);

  transpose_w_k<<<dim3(64, 64), 256, 0, stream>>>(wo, woT, 4096, 4096);
  gemm256<1><<<256, 512, 131072, stream>>>(AO, woT, out, tbl, 4096, 4096, 4096);
}